// Round 1
// baseline (1305.816 us; speedup 1.0000x reference)
//
#include <hip/hip_runtime.h>

#define NN 100000
#define NE 1600000

__device__ __forceinline__ void fma4(float4& a, float s, const float4 w) {
  a.x = fmaf(s, w.x, a.x);
  a.y = fmaf(s, w.y, a.y);
  a.z = fmaf(s, w.z, a.z);
  a.w = fmaf(s, w.w, a.w);
}

// ---------------------------------------------------------------------------
// Edge kernel: msg = relu(x[src] + edge_attr @ We + be); atomic scatter to agg
// D = feature dim (32 for layer0, 128 for layer1). We column held in VGPRs.
// ---------------------------------------------------------------------------
template<int D>
__global__ __launch_bounds__(256) void edge_kernel(
    const int* __restrict__ ei, const float* __restrict__ ea,
    const float* __restrict__ x, const float* __restrict__ We,
    const float* __restrict__ be, float* __restrict__ agg)
{
  constexpr int EPB = 256 / D;
  const int j = threadIdx.x % D;
  const int g = threadIdx.x / D;
  float wc[16];
#pragma unroll
  for (int k = 0; k < 16; ++k) wc[k] = We[k * D + j];
  const float bj = be[j];

  for (int e0 = blockIdx.x * EPB; e0 < NE; e0 += gridDim.x * EPB) {
    const int e = e0 + g;
    if (e < NE) {
      const int src = ei[e];
      const int dst = ei[NE + e];
      const float4* eap = (const float4*)(ea + e * 16);
      const float4 a0 = eap[0], a1 = eap[1], a2 = eap[2], a3 = eap[3];
      float d = x[src * D + j] + bj;
      d = fmaf(wc[0],  a0.x, d); d = fmaf(wc[1],  a0.y, d);
      d = fmaf(wc[2],  a0.z, d); d = fmaf(wc[3],  a0.w, d);
      d = fmaf(wc[4],  a1.x, d); d = fmaf(wc[5],  a1.y, d);
      d = fmaf(wc[6],  a1.z, d); d = fmaf(wc[7],  a1.w, d);
      d = fmaf(wc[8],  a2.x, d); d = fmaf(wc[9],  a2.y, d);
      d = fmaf(wc[10], a2.z, d); d = fmaf(wc[11], a2.w, d);
      d = fmaf(wc[12], a3.x, d); d = fmaf(wc[13], a3.y, d);
      d = fmaf(wc[14], a3.z, d); d = fmaf(wc[15], a3.w, d);
      d = fmaxf(d, 0.f);
      atomicAdd(&agg[dst * D + j], d);
    }
  }
}

// ---------------------------------------------------------------------------
// Node MLP: hpre = relu((a+b) @ W1 + b1) @ W2 + b2, plus BN sum/sumsq stats.
// Block: 256 thr = 32 channel-quads x 8 node-groups; 64 nodes per chunk.
// Activations staged in LDS; weights streamed from L1/L2 as float4.
// ---------------------------------------------------------------------------
template<int DIN>
__global__ __launch_bounds__(256) void mlp_kernel(
    const float* __restrict__ a, const float* __restrict__ b,
    const float* __restrict__ W1, const float* __restrict__ b1,
    const float* __restrict__ W2, const float* __restrict__ b2,
    float* __restrict__ out, float* __restrict__ stats, int nChunks)
{
  __shared__ float hin[64 * DIN];
  __shared__ float tls[64 * 128];
  const int tid = threadIdx.x;
  const int cj  = tid & 31;
  const int gg  = tid >> 5;
  const float4 b1q = *(const float4*)&b1[4 * cj];
  const float4 b2q = *(const float4*)&b2[4 * cj];
  float4 lsum = make_float4(0.f, 0.f, 0.f, 0.f);
  float4 lsq  = make_float4(0.f, 0.f, 0.f, 0.f);

  for (int chunk = blockIdx.x; chunk < nChunks; chunk += gridDim.x) {
    const int base = chunk * 64;
    // stage hin = a + b for 64 nodes
    for (int idx = tid; idx < 16 * DIN; idx += 256) {
      const int n = idx / (DIN / 4);
      const int r = idx % (DIN / 4);
      const int node = base + n;
      float4 v = make_float4(0.f, 0.f, 0.f, 0.f);
      if (node < NN) {
        const float4 va = *(const float4*)&a[node * DIN + r * 4];
        const float4 vb = *(const float4*)&b[node * DIN + r * 4];
        v.x = va.x + vb.x; v.y = va.y + vb.y;
        v.z = va.z + vb.z; v.w = va.w + vb.w;
      }
      *(float4*)&hin[n * DIN + r * 4] = v;
    }
    __syncthreads();

    // phase 1: t = relu(hin @ W1 + b1)
    float4 acc[8];
#pragma unroll
    for (int s = 0; s < 8; ++s) acc[s] = b1q;
    for (int k = 0; k < DIN; k += 4) {
      const float4 w0 = *(const float4*)&W1[(k + 0) * 128 + 4 * cj];
      const float4 w1 = *(const float4*)&W1[(k + 1) * 128 + 4 * cj];
      const float4 w2 = *(const float4*)&W1[(k + 2) * 128 + 4 * cj];
      const float4 w3 = *(const float4*)&W1[(k + 3) * 128 + 4 * cj];
#pragma unroll
      for (int s = 0; s < 8; ++s) {
        const float4 hv = *(const float4*)&hin[(gg * 8 + s) * DIN + k];
        fma4(acc[s], hv.x, w0); fma4(acc[s], hv.y, w1);
        fma4(acc[s], hv.z, w2); fma4(acc[s], hv.w, w3);
      }
    }
#pragma unroll
    for (int s = 0; s < 8; ++s) {
      float4 t;
      t.x = fmaxf(acc[s].x, 0.f); t.y = fmaxf(acc[s].y, 0.f);
      t.z = fmaxf(acc[s].z, 0.f); t.w = fmaxf(acc[s].w, 0.f);
      *(float4*)&tls[(gg * 8 + s) * 128 + 4 * cj] = t;
    }
    __syncthreads();

    // phase 2: hpre = t @ W2 + b2
    float4 acc2[8];
#pragma unroll
    for (int s = 0; s < 8; ++s) acc2[s] = b2q;
    for (int k = 0; k < 128; k += 4) {
      const float4 w0 = *(const float4*)&W2[(k + 0) * 128 + 4 * cj];
      const float4 w1 = *(const float4*)&W2[(k + 1) * 128 + 4 * cj];
      const float4 w2 = *(const float4*)&W2[(k + 2) * 128 + 4 * cj];
      const float4 w3 = *(const float4*)&W2[(k + 3) * 128 + 4 * cj];
#pragma unroll
      for (int s = 0; s < 8; ++s) {
        const float4 tv = *(const float4*)&tls[(gg * 8 + s) * 128 + k];
        fma4(acc2[s], tv.x, w0); fma4(acc2[s], tv.y, w1);
        fma4(acc2[s], tv.z, w2); fma4(acc2[s], tv.w, w3);
      }
    }
#pragma unroll
    for (int s = 0; s < 8; ++s) {
      const int node = base + gg * 8 + s;
      if (node < NN) {
        *(float4*)&out[node * 128 + 4 * cj] = acc2[s];
        lsum.x += acc2[s].x; lsum.y += acc2[s].y;
        lsum.z += acc2[s].z; lsum.w += acc2[s].w;
        lsq.x  += acc2[s].x * acc2[s].x; lsq.y += acc2[s].y * acc2[s].y;
        lsq.z  += acc2[s].z * acc2[s].z; lsq.w += acc2[s].w * acc2[s].w;
      }
    }
    __syncthreads();
  }

  // block-level BN-stat reduction across the 8 node-groups (reuse hin LDS)
  *(float4*)&hin[gg * 128 + 4 * cj] = lsum;
  *(float4*)&hin[1024 + gg * 128 + 4 * cj] = lsq;
  __syncthreads();
  if (gg == 0) {
    float4 s = make_float4(0.f, 0.f, 0.f, 0.f);
    float4 q = make_float4(0.f, 0.f, 0.f, 0.f);
#pragma unroll
    for (int g2 = 0; g2 < 8; ++g2) {
      const float4 vs = *(const float4*)&hin[g2 * 128 + 4 * cj];
      const float4 vq = *(const float4*)&hin[1024 + g2 * 128 + 4 * cj];
      s.x += vs.x; s.y += vs.y; s.z += vs.z; s.w += vs.w;
      q.x += vq.x; q.y += vq.y; q.z += vq.z; q.w += vq.w;
    }
    atomicAdd(&stats[4 * cj + 0], s.x);
    atomicAdd(&stats[4 * cj + 1], s.y);
    atomicAdd(&stats[4 * cj + 2], s.z);
    atomicAdd(&stats[4 * cj + 3], s.w);
    atomicAdd(&stats[128 + 4 * cj + 0], q.x);
    atomicAdd(&stats[128 + 4 * cj + 1], q.y);
    atomicAdd(&stats[128 + 4 * cj + 2], q.z);
    atomicAdd(&stats[128 + 4 * cj + 3], q.w);
  }
}

// stats: [0:128) sum, [128:256) sumsq -> write [256:384) scale, [384:512) shift
__global__ void bn_finalize(float* __restrict__ stats,
                            const float* __restrict__ gamma,
                            const float* __restrict__ beta)
{
  const int c = threadIdx.x;
  const float inv_n = 1.0f / (float)NN;
  const float mu  = stats[c] * inv_n;
  float var = stats[128 + c] * inv_n - mu * mu;
  var = fmaxf(var, 0.f);
  const float rs = rsqrtf(var + 1e-5f);
  const float sc = rs * gamma[c];
  stats[256 + c] = sc;
  stats[384 + c] = beta[c] - mu * sc;
}

// h = relu(h * scale + shift), in place. Grid covers exactly NN*32 float4s.
__global__ __launch_bounds__(256) void bn_apply(float* __restrict__ h,
                                                const float* __restrict__ stats)
{
  const int idx = blockIdx.x * 256 + threadIdx.x;   // over NN*32 float4s
  const int c4 = (idx & 31) * 4;
  const float4 sc = *(const float4*)&stats[256 + c4];
  const float4 sh = *(const float4*)&stats[384 + c4];
  float4 v = ((const float4*)h)[idx];
  v.x = fmaxf(fmaf(v.x, sc.x, sh.x), 0.f);
  v.y = fmaxf(fmaf(v.y, sc.y, sh.y), 0.f);
  v.z = fmaxf(fmaf(v.z, sc.z, sh.z), 0.f);
  v.w = fmaxf(fmaf(v.w, sc.w, sh.w), 0.f);
  ((float4*)h)[idx] = v;
}

// head: out = sigmoid(relu(h @ W1 + b1) @ w2 + b2)
__global__ __launch_bounds__(256) void head_kernel(
    const float* __restrict__ h, const float* __restrict__ W1,
    const float* __restrict__ b1, const float* __restrict__ w2,
    const float* __restrict__ b2, float* __restrict__ out, int nChunks)
{
  __shared__ float hin[64 * 128];
  __shared__ float tls[64 * 128];
  __shared__ float w2s[128];
  const int tid = threadIdx.x;
  if (tid < 32) *(float4*)&w2s[tid * 4] = *(const float4*)&w2[tid * 4];
  const int cj = tid & 31;
  const int gg = tid >> 5;
  const float4 b1q = *(const float4*)&b1[4 * cj];
  const float b2v = b2[0];

  for (int chunk = blockIdx.x; chunk < nChunks; chunk += gridDim.x) {
    const int base = chunk * 64;
    for (int idx = tid; idx < 2048; idx += 256) {
      const int n = idx >> 5;
      const int r = idx & 31;
      const int node = base + n;
      float4 v = make_float4(0.f, 0.f, 0.f, 0.f);
      if (node < NN) v = *(const float4*)&h[node * 128 + r * 4];
      *(float4*)&hin[n * 128 + r * 4] = v;
    }
    __syncthreads();

    float4 acc[8];
#pragma unroll
    for (int s = 0; s < 8; ++s) acc[s] = b1q;
    for (int k = 0; k < 128; k += 4) {
      const float4 w0 = *(const float4*)&W1[(k + 0) * 128 + 4 * cj];
      const float4 w1 = *(const float4*)&W1[(k + 1) * 128 + 4 * cj];
      const float4 w2q = *(const float4*)&W1[(k + 2) * 128 + 4 * cj];
      const float4 w3 = *(const float4*)&W1[(k + 3) * 128 + 4 * cj];
#pragma unroll
      for (int s = 0; s < 8; ++s) {
        const float4 hv = *(const float4*)&hin[(gg * 8 + s) * 128 + k];
        fma4(acc[s], hv.x, w0); fma4(acc[s], hv.y, w1);
        fma4(acc[s], hv.z, w2q); fma4(acc[s], hv.w, w3);
      }
    }
#pragma unroll
    for (int s = 0; s < 8; ++s) {
      float4 t;
      t.x = fmaxf(acc[s].x, 0.f); t.y = fmaxf(acc[s].y, 0.f);
      t.z = fmaxf(acc[s].z, 0.f); t.w = fmaxf(acc[s].w, 0.f);
      *(float4*)&tls[(gg * 8 + s) * 128 + 4 * cj] = t;
    }
    __syncthreads();

    const int nl = tid >> 2;
    const int q  = tid & 3;
    float p = 0.f;
#pragma unroll
    for (int kk = 0; kk < 32; kk += 4) {
      const int k = q * 32 + kk;
      const float4 tv = *(const float4*)&tls[nl * 128 + k];
      const float4 wv = *(const float4*)&w2s[k];
      p = fmaf(tv.x, wv.x, p); p = fmaf(tv.y, wv.y, p);
      p = fmaf(tv.z, wv.z, p); p = fmaf(tv.w, wv.w, p);
    }
    p += __shfl_xor(p, 1);
    p += __shfl_xor(p, 2);
    const int node = base + nl;
    if (q == 0 && node < NN) out[node] = 1.f / (1.f + expf(-(p + b2v)));
    __syncthreads();
  }
}

extern "C" void kernel_launch(void* const* d_in, const int* in_sizes, int n_in,
                              void* d_out, int out_size, void* d_ws, size_t ws_size,
                              hipStream_t stream)
{
  const float* x    = (const float*)d_in[0];
  const int*   ei   = (const int*)  d_in[1];
  const float* ea   = (const float*)d_in[2];
  const float* l0We = (const float*)d_in[3];
  const float* l0be = (const float*)d_in[4];
  const float* l0W1 = (const float*)d_in[5];
  const float* l0b1 = (const float*)d_in[6];
  const float* l0W2 = (const float*)d_in[7];
  const float* l0b2 = (const float*)d_in[8];
  const float* l0g  = (const float*)d_in[9];
  const float* l0bt = (const float*)d_in[10];
  const float* l1We = (const float*)d_in[11];
  const float* l1be = (const float*)d_in[12];
  const float* l1W1 = (const float*)d_in[13];
  const float* l1b1 = (const float*)d_in[14];
  const float* l1W2 = (const float*)d_in[15];
  const float* l1b2 = (const float*)d_in[16];
  const float* l1g  = (const float*)d_in[17];
  const float* l1bt = (const float*)d_in[18];
  const float* hW1  = (const float*)d_in[19];
  const float* hb1  = (const float*)d_in[20];
  const float* hW2  = (const float*)d_in[21];
  const float* hb2  = (const float*)d_in[22];
  float* out = (float*)d_out;

  float* A    = (float*)d_ws;                  // hpre0 / h0  [NN*128]
  float* B    = A + (size_t)NN * 128;          // hpre1 / h1  [NN*128]
  float* agg0 = B + (size_t)NN * 128;          // [NN*32]
  float* agg1 = agg0 + (size_t)NN * 32;        // [NN*128]
  float* st0  = agg1 + (size_t)NN * 128;       // [512]
  float* st1  = st0 + 512;                     // [512]

  const size_t needed = ((size_t)NN * 128 * 3 + (size_t)NN * 32 + 1024) * sizeof(float);
  if (ws_size < needed) return;  // fail visibly (wrong output) rather than corrupt

  // zero accumulators + stats (agg0, agg1, st0, st1 are contiguous)
  hipMemsetAsync(agg0, 0,
                 ((size_t)NN * 32 + (size_t)NN * 128 + 1024) * sizeof(float),
                 stream);

  const int nChunks = (NN + 63) / 64;

  edge_kernel<32><<<8192, 256, 0, stream>>>(ei, ea, x, l0We, l0be, agg0);
  mlp_kernel<32><<<782, 256, 0, stream>>>(x, agg0, l0W1, l0b1, l0W2, l0b2, A, st0, nChunks);
  bn_finalize<<<1, 128, 0, stream>>>(st0, l0g, l0bt);
  bn_apply<<<(NN * 32) / 256, 256, 0, stream>>>(A, st0);

  edge_kernel<128><<<8192, 256, 0, stream>>>(ei, ea, A, l1We, l1be, agg1);
  mlp_kernel<128><<<782, 256, 0, stream>>>(A, agg1, l1W1, l1b1, l1W2, l1b2, B, st1, nChunks);
  bn_finalize<<<1, 128, 0, stream>>>(st1, l1g, l1bt);
  bn_apply<<<(NN * 32) / 256, 256, 0, stream>>>(B, st1);

  head_kernel<<<782, 256, 0, stream>>>(B, hW1, hb1, hW2, hb2, out, nChunks);
}

// Round 2
// 1108.687 us; speedup vs baseline: 1.1778x; 1.1778x over previous
//
#include <hip/hip_runtime.h>

#define NN 100000
#define NE 1600000

typedef unsigned int uint32;

__device__ __forceinline__ void fma4(float4& a, float s, const float4 w) {
  a.x = fmaf(s, w.x, a.x);
  a.y = fmaf(s, w.y, a.y);
  a.z = fmaf(s, w.z, a.z);
  a.w = fmaf(s, w.w, a.w);
}

// ---------------------------------------------------------------------------
// CSR build: histogram -> block-scanned offsets -> slot fill
// ---------------------------------------------------------------------------
__global__ __launch_bounds__(256) void hist_kernel(
    const int* __restrict__ ei, uint32* __restrict__ deg)
{
  const int e = blockIdx.x * 256 + threadIdx.x;
  if (e < NE) atomicAdd(&deg[ei[NE + e]], 1u);
}

__global__ __launch_bounds__(256) void offsets_kernel(
    const uint32* __restrict__ deg, uint32* __restrict__ off,
    uint32* __restrict__ cur, uint32* __restrict__ counter)
{
  __shared__ uint32 s[256];
  __shared__ uint32 base;
  const int tid = threadIdx.x;
  const int n = blockIdx.x * 256 + tid;
  const uint32 d = (n < NN) ? deg[n] : 0u;
  s[tid] = d;
  __syncthreads();
#pragma unroll
  for (int st = 1; st < 256; st <<= 1) {
    uint32 v = (tid >= st) ? s[tid - st] : 0u;
    __syncthreads();
    s[tid] += v;
    __syncthreads();
  }
  if (tid == 255) base = atomicAdd(counter, s[255]);
  __syncthreads();
  const uint32 excl = s[tid] - d;
  if (n < NN) {
    off[n] = base + excl;
    cur[n] = base + excl;
  }
}

__global__ __launch_bounds__(256) void fill_kernel(
    const int* __restrict__ ei, uint32* __restrict__ cur,
    uint32* __restrict__ eid)
{
  const int e = blockIdx.x * 256 + threadIdx.x;
  if (e < NE) {
    const int dst = ei[NE + e];
    const uint32 slot = atomicAdd(&cur[dst], 1u);
    eid[slot] = (uint32)e;
  }
}

// ---------------------------------------------------------------------------
// Gather-aggregate: agg[n] = sum_{e: dst=n} relu(x[src_e] + ea[e]@We + be)
// One wave per node; We column in VGPRs; single non-atomic row write.
// ---------------------------------------------------------------------------
__global__ __launch_bounds__(256) void agg_kernel128(
    const uint32* __restrict__ off, const uint32* __restrict__ deg,
    const uint32* __restrict__ eid, const int* __restrict__ ei,
    const float* __restrict__ ea, const float* __restrict__ x,
    const float* __restrict__ We, const float* __restrict__ be,
    float* __restrict__ agg)
{
  const int lane = threadIdx.x & 63;
  const int n = blockIdx.x * 4 + (threadIdx.x >> 6);
  float w0[16], w1[16];
#pragma unroll
  for (int k = 0; k < 16; ++k) {
    w0[k] = We[k * 128 + lane];
    w1[k] = We[k * 128 + 64 + lane];
  }
  const float be0 = be[lane];
  const float be1 = be[64 + lane];

  const uint32 o = off[n];
  const uint32 dn = deg[n];
  float a0 = 0.f, a1 = 0.f;
  for (uint32 i = 0; i < dn; ++i) {
    const int e = (int)eid[o + i];
    const int src = ei[e];
    const float4* er = (const float4*)(ea + (size_t)e * 16);
    const float4 q0 = er[0], q1 = er[1], q2 = er[2], q3 = er[3];
    float m0 = be0, m1 = be1;
    m0 = fmaf(q0.x, w0[0],  m0); m1 = fmaf(q0.x, w1[0],  m1);
    m0 = fmaf(q0.y, w0[1],  m0); m1 = fmaf(q0.y, w1[1],  m1);
    m0 = fmaf(q0.z, w0[2],  m0); m1 = fmaf(q0.z, w1[2],  m1);
    m0 = fmaf(q0.w, w0[3],  m0); m1 = fmaf(q0.w, w1[3],  m1);
    m0 = fmaf(q1.x, w0[4],  m0); m1 = fmaf(q1.x, w1[4],  m1);
    m0 = fmaf(q1.y, w0[5],  m0); m1 = fmaf(q1.y, w1[5],  m1);
    m0 = fmaf(q1.z, w0[6],  m0); m1 = fmaf(q1.z, w1[6],  m1);
    m0 = fmaf(q1.w, w0[7],  m0); m1 = fmaf(q1.w, w1[7],  m1);
    m0 = fmaf(q2.x, w0[8],  m0); m1 = fmaf(q2.x, w1[8],  m1);
    m0 = fmaf(q2.y, w0[9],  m0); m1 = fmaf(q2.y, w1[9],  m1);
    m0 = fmaf(q2.z, w0[10], m0); m1 = fmaf(q2.z, w1[10], m1);
    m0 = fmaf(q2.w, w0[11], m0); m1 = fmaf(q2.w, w1[11], m1);
    m0 = fmaf(q3.x, w0[12], m0); m1 = fmaf(q3.x, w1[12], m1);
    m0 = fmaf(q3.y, w0[13], m0); m1 = fmaf(q3.y, w1[13], m1);
    m0 = fmaf(q3.z, w0[14], m0); m1 = fmaf(q3.z, w1[14], m1);
    m0 = fmaf(q3.w, w0[15], m0); m1 = fmaf(q3.w, w1[15], m1);
    m0 += x[(size_t)src * 128 + lane];
    m1 += x[(size_t)src * 128 + 64 + lane];
    a0 += fmaxf(m0, 0.f);
    a1 += fmaxf(m1, 0.f);
  }
  agg[(size_t)n * 128 + lane] = a0;
  agg[(size_t)n * 128 + 64 + lane] = a1;
}

__global__ __launch_bounds__(256) void agg_kernel32(
    const uint32* __restrict__ off, const uint32* __restrict__ deg,
    const uint32* __restrict__ eid, const int* __restrict__ ei,
    const float* __restrict__ ea, const float* __restrict__ x,
    const float* __restrict__ We, const float* __restrict__ be,
    float* __restrict__ agg)
{
  const int lane = threadIdx.x & 63;
  const int c = lane & 31;
  const int h = lane >> 5;
  const int n = blockIdx.x * 4 + (threadIdx.x >> 6);
  float wc[16];
#pragma unroll
  for (int k = 0; k < 16; ++k) wc[k] = We[k * 32 + c];
  const float bec = be[c];

  const uint32 o = off[n];
  const uint32 dn = deg[n];
  float a = 0.f;
  for (uint32 i = (uint32)h; i < dn; i += 2) {
    const int e = (int)eid[o + i];
    const int src = ei[e];
    const float4* er = (const float4*)(ea + (size_t)e * 16);
    const float4 q0 = er[0], q1 = er[1], q2 = er[2], q3 = er[3];
    float m = bec;
    m = fmaf(q0.x, wc[0],  m); m = fmaf(q0.y, wc[1],  m);
    m = fmaf(q0.z, wc[2],  m); m = fmaf(q0.w, wc[3],  m);
    m = fmaf(q1.x, wc[4],  m); m = fmaf(q1.y, wc[5],  m);
    m = fmaf(q1.z, wc[6],  m); m = fmaf(q1.w, wc[7],  m);
    m = fmaf(q2.x, wc[8],  m); m = fmaf(q2.y, wc[9],  m);
    m = fmaf(q2.z, wc[10], m); m = fmaf(q2.w, wc[11], m);
    m = fmaf(q3.x, wc[12], m); m = fmaf(q3.y, wc[13], m);
    m = fmaf(q3.z, wc[14], m); m = fmaf(q3.w, wc[15], m);
    m += x[(size_t)src * 32 + c];
    a += fmaxf(m, 0.f);
  }
  a += __shfl_xor(a, 32);
  if (h == 0) agg[(size_t)n * 32 + c] = a;
}

// ---------------------------------------------------------------------------
// Node MLP: hpre = relu((a+b) @ W1 + b1) @ W2 + b2, plus BN sum/sumsq stats.
// ---------------------------------------------------------------------------
template<int DIN>
__global__ __launch_bounds__(256) void mlp_kernel(
    const float* __restrict__ a, const float* __restrict__ b,
    const float* __restrict__ W1, const float* __restrict__ b1,
    const float* __restrict__ W2, const float* __restrict__ b2,
    float* __restrict__ out, float* __restrict__ stats, int nChunks)
{
  __shared__ float hin[64 * DIN];
  __shared__ float tls[64 * 128];
  const int tid = threadIdx.x;
  const int cj  = tid & 31;
  const int gg  = tid >> 5;
  const float4 b1q = *(const float4*)&b1[4 * cj];
  const float4 b2q = *(const float4*)&b2[4 * cj];
  float4 lsum = make_float4(0.f, 0.f, 0.f, 0.f);
  float4 lsq  = make_float4(0.f, 0.f, 0.f, 0.f);

  for (int chunk = blockIdx.x; chunk < nChunks; chunk += gridDim.x) {
    const int base = chunk * 64;
    for (int idx = tid; idx < 16 * DIN; idx += 256) {
      const int n = idx / (DIN / 4);
      const int r = idx % (DIN / 4);
      const int node = base + n;
      float4 v = make_float4(0.f, 0.f, 0.f, 0.f);
      if (node < NN) {
        const float4 va = *(const float4*)&a[node * DIN + r * 4];
        const float4 vb = *(const float4*)&b[node * DIN + r * 4];
        v.x = va.x + vb.x; v.y = va.y + vb.y;
        v.z = va.z + vb.z; v.w = va.w + vb.w;
      }
      *(float4*)&hin[n * DIN + r * 4] = v;
    }
    __syncthreads();

    float4 acc[8];
#pragma unroll
    for (int s = 0; s < 8; ++s) acc[s] = b1q;
    for (int k = 0; k < DIN; k += 4) {
      const float4 w0 = *(const float4*)&W1[(k + 0) * 128 + 4 * cj];
      const float4 w1 = *(const float4*)&W1[(k + 1) * 128 + 4 * cj];
      const float4 w2 = *(const float4*)&W1[(k + 2) * 128 + 4 * cj];
      const float4 w3 = *(const float4*)&W1[(k + 3) * 128 + 4 * cj];
#pragma unroll
      for (int s = 0; s < 8; ++s) {
        const float4 hv = *(const float4*)&hin[(gg * 8 + s) * DIN + k];
        fma4(acc[s], hv.x, w0); fma4(acc[s], hv.y, w1);
        fma4(acc[s], hv.z, w2); fma4(acc[s], hv.w, w3);
      }
    }
#pragma unroll
    for (int s = 0; s < 8; ++s) {
      float4 t;
      t.x = fmaxf(acc[s].x, 0.f); t.y = fmaxf(acc[s].y, 0.f);
      t.z = fmaxf(acc[s].z, 0.f); t.w = fmaxf(acc[s].w, 0.f);
      *(float4*)&tls[(gg * 8 + s) * 128 + 4 * cj] = t;
    }
    __syncthreads();

    float4 acc2[8];
#pragma unroll
    for (int s = 0; s < 8; ++s) acc2[s] = b2q;
    for (int k = 0; k < 128; k += 4) {
      const float4 w0 = *(const float4*)&W2[(k + 0) * 128 + 4 * cj];
      const float4 w1 = *(const float4*)&W2[(k + 1) * 128 + 4 * cj];
      const float4 w2 = *(const float4*)&W2[(k + 2) * 128 + 4 * cj];
      const float4 w3 = *(const float4*)&W2[(k + 3) * 128 + 4 * cj];
#pragma unroll
      for (int s = 0; s < 8; ++s) {
        const float4 tv = *(const float4*)&tls[(gg * 8 + s) * 128 + k];
        fma4(acc2[s], tv.x, w0); fma4(acc2[s], tv.y, w1);
        fma4(acc2[s], tv.z, w2); fma4(acc2[s], tv.w, w3);
      }
    }
#pragma unroll
    for (int s = 0; s < 8; ++s) {
      const int node = base + gg * 8 + s;
      if (node < NN) {
        *(float4*)&out[node * 128 + 4 * cj] = acc2[s];
        lsum.x += acc2[s].x; lsum.y += acc2[s].y;
        lsum.z += acc2[s].z; lsum.w += acc2[s].w;
        lsq.x  += acc2[s].x * acc2[s].x; lsq.y += acc2[s].y * acc2[s].y;
        lsq.z  += acc2[s].z * acc2[s].z; lsq.w += acc2[s].w * acc2[s].w;
      }
    }
    __syncthreads();
  }

  *(float4*)&hin[gg * 128 + 4 * cj] = lsum;
  *(float4*)&hin[1024 + gg * 128 + 4 * cj] = lsq;
  __syncthreads();
  if (gg == 0) {
    float4 s = make_float4(0.f, 0.f, 0.f, 0.f);
    float4 q = make_float4(0.f, 0.f, 0.f, 0.f);
#pragma unroll
    for (int g2 = 0; g2 < 8; ++g2) {
      const float4 vs = *(const float4*)&hin[g2 * 128 + 4 * cj];
      const float4 vq = *(const float4*)&hin[1024 + g2 * 128 + 4 * cj];
      s.x += vs.x; s.y += vs.y; s.z += vs.z; s.w += vs.w;
      q.x += vq.x; q.y += vq.y; q.z += vq.z; q.w += vq.w;
    }
    atomicAdd(&stats[4 * cj + 0], s.x);
    atomicAdd(&stats[4 * cj + 1], s.y);
    atomicAdd(&stats[4 * cj + 2], s.z);
    atomicAdd(&stats[4 * cj + 3], s.w);
    atomicAdd(&stats[128 + 4 * cj + 0], q.x);
    atomicAdd(&stats[128 + 4 * cj + 1], q.y);
    atomicAdd(&stats[128 + 4 * cj + 2], q.z);
    atomicAdd(&stats[128 + 4 * cj + 3], q.w);
  }
}

__global__ void bn_finalize(float* __restrict__ stats,
                            const float* __restrict__ gamma,
                            const float* __restrict__ beta)
{
  const int c = threadIdx.x;
  const float inv_n = 1.0f / (float)NN;
  const float mu  = stats[c] * inv_n;
  float var = stats[128 + c] * inv_n - mu * mu;
  var = fmaxf(var, 0.f);
  const float rs = rsqrtf(var + 1e-5f);
  const float sc = rs * gamma[c];
  stats[256 + c] = sc;
  stats[384 + c] = beta[c] - mu * sc;
}

__global__ __launch_bounds__(256) void bn_apply(float* __restrict__ h,
                                                const float* __restrict__ stats)
{
  const int idx = blockIdx.x * 256 + threadIdx.x;
  const int c4 = (idx & 31) * 4;
  const float4 sc = *(const float4*)&stats[256 + c4];
  const float4 sh = *(const float4*)&stats[384 + c4];
  float4 v = ((const float4*)h)[idx];
  v.x = fmaxf(fmaf(v.x, sc.x, sh.x), 0.f);
  v.y = fmaxf(fmaf(v.y, sc.y, sh.y), 0.f);
  v.z = fmaxf(fmaf(v.z, sc.z, sh.z), 0.f);
  v.w = fmaxf(fmaf(v.w, sc.w, sh.w), 0.f);
  ((float4*)h)[idx] = v;
}

__global__ __launch_bounds__(256) void head_kernel(
    const float* __restrict__ h, const float* __restrict__ W1,
    const float* __restrict__ b1, const float* __restrict__ w2,
    const float* __restrict__ b2, float* __restrict__ out, int nChunks)
{
  __shared__ float hin[64 * 128];
  __shared__ float tls[64 * 128];
  __shared__ float w2s[128];
  const int tid = threadIdx.x;
  if (tid < 32) *(float4*)&w2s[tid * 4] = *(const float4*)&w2[tid * 4];
  const int cj = tid & 31;
  const int gg = tid >> 5;
  const float4 b1q = *(const float4*)&b1[4 * cj];
  const float b2v = b2[0];

  for (int chunk = blockIdx.x; chunk < nChunks; chunk += gridDim.x) {
    const int base = chunk * 64;
    for (int idx = tid; idx < 2048; idx += 256) {
      const int n = idx >> 5;
      const int r = idx & 31;
      const int node = base + n;
      float4 v = make_float4(0.f, 0.f, 0.f, 0.f);
      if (node < NN) v = *(const float4*)&h[node * 128 + r * 4];
      *(float4*)&hin[n * 128 + r * 4] = v;
    }
    __syncthreads();

    float4 acc[8];
#pragma unroll
    for (int s = 0; s < 8; ++s) acc[s] = b1q;
    for (int k = 0; k < 128; k += 4) {
      const float4 w0 = *(const float4*)&W1[(k + 0) * 128 + 4 * cj];
      const float4 w1 = *(const float4*)&W1[(k + 1) * 128 + 4 * cj];
      const float4 w2q = *(const float4*)&W1[(k + 2) * 128 + 4 * cj];
      const float4 w3 = *(const float4*)&W1[(k + 3) * 128 + 4 * cj];
#pragma unroll
      for (int s = 0; s < 8; ++s) {
        const float4 hv = *(const float4*)&hin[(gg * 8 + s) * 128 + k];
        fma4(acc[s], hv.x, w0); fma4(acc[s], hv.y, w1);
        fma4(acc[s], hv.z, w2q); fma4(acc[s], hv.w, w3);
      }
    }
#pragma unroll
    for (int s = 0; s < 8; ++s) {
      float4 t;
      t.x = fmaxf(acc[s].x, 0.f); t.y = fmaxf(acc[s].y, 0.f);
      t.z = fmaxf(acc[s].z, 0.f); t.w = fmaxf(acc[s].w, 0.f);
      *(float4*)&tls[(gg * 8 + s) * 128 + 4 * cj] = t;
    }
    __syncthreads();

    const int nl = tid >> 2;
    const int q  = tid & 3;
    float p = 0.f;
#pragma unroll
    for (int kk = 0; kk < 32; kk += 4) {
      const int k = q * 32 + kk;
      const float4 tv = *(const float4*)&tls[nl * 128 + k];
      const float4 wv = *(const float4*)&w2s[k];
      p = fmaf(tv.x, wv.x, p); p = fmaf(tv.y, wv.y, p);
      p = fmaf(tv.z, wv.z, p); p = fmaf(tv.w, wv.w, p);
    }
    p += __shfl_xor(p, 1);
    p += __shfl_xor(p, 2);
    const int node = base + nl;
    if (q == 0 && node < NN) out[node] = 1.f / (1.f + expf(-(p + b2v)));
    __syncthreads();
  }
}

extern "C" void kernel_launch(void* const* d_in, const int* in_sizes, int n_in,
                              void* d_out, int out_size, void* d_ws, size_t ws_size,
                              hipStream_t stream)
{
  const float* x    = (const float*)d_in[0];
  const int*   ei   = (const int*)  d_in[1];
  const float* ea   = (const float*)d_in[2];
  const float* l0We = (const float*)d_in[3];
  const float* l0be = (const float*)d_in[4];
  const float* l0W1 = (const float*)d_in[5];
  const float* l0b1 = (const float*)d_in[6];
  const float* l0W2 = (const float*)d_in[7];
  const float* l0b2 = (const float*)d_in[8];
  const float* l0g  = (const float*)d_in[9];
  const float* l0bt = (const float*)d_in[10];
  const float* l1We = (const float*)d_in[11];
  const float* l1be = (const float*)d_in[12];
  const float* l1W1 = (const float*)d_in[13];
  const float* l1b1 = (const float*)d_in[14];
  const float* l1W2 = (const float*)d_in[15];
  const float* l1b2 = (const float*)d_in[16];
  const float* l1g  = (const float*)d_in[17];
  const float* l1bt = (const float*)d_in[18];
  const float* hW1  = (const float*)d_in[19];
  const float* hb1  = (const float*)d_in[20];
  const float* hW2  = (const float*)d_in[21];
  const float* hb2  = (const float*)d_in[22];
  float* out = (float*)d_out;

  // workspace layout (~161.2 MB; previous 166.4 MB requirement passed)
  float*  A       = (float*)d_ws;               // NN*128
  float*  B       = A + (size_t)NN * 128;       // NN*128
  float*  AGG     = B + (size_t)NN * 128;       // NN*128 (agg0 uses first NN*32)
  uint32* deg     = (uint32*)(AGG + (size_t)NN * 128);  // NN
  uint32* off     = deg + NN;                   // NN
  uint32* cur     = off + NN;                   // NN
  uint32* counter = cur + NN;                   // 4 (padded)
  uint32* eid     = counter + 4;                // NE
  float*  st0     = (float*)(eid + NE);         // 512
  float*  st1     = st0 + 512;                  // 512

  const size_t needed = ((size_t)NN * 128 * 3 + 3 * NN + 4 + NE + 1024) * 4;
  if (ws_size < needed) return;

  // zero: deg + counter (contiguous would need off/cur in between; do 2 memsets)
  hipMemsetAsync(deg, 0, (size_t)NN * 4, stream);
  hipMemsetAsync(counter, 0, 4 * 4, stream);
  hipMemsetAsync(st0, 0, 1024 * 4, stream);

  const int nChunks = (NN + 63) / 64;
  const int eBlocks = (NE + 255) / 256;         // 6250
  const int nBlocks = (NN + 255) / 256;         // 391
  const int aBlocks = NN / 4;                   // 25000 (one wave per node)

  // CSR build (shared by both layers)
  hist_kernel<<<eBlocks, 256, 0, stream>>>(ei, deg);
  offsets_kernel<<<nBlocks, 256, 0, stream>>>(deg, off, cur, counter);
  fill_kernel<<<eBlocks, 256, 0, stream>>>(ei, cur, eid);

  // layer 0
  agg_kernel32<<<aBlocks, 256, 0, stream>>>(off, deg, eid, ei, ea, x, l0We, l0be, AGG);
  mlp_kernel<32><<<782, 256, 0, stream>>>(x, AGG, l0W1, l0b1, l0W2, l0b2, A, st0, nChunks);
  bn_finalize<<<1, 128, 0, stream>>>(st0, l0g, l0bt);
  bn_apply<<<(NN * 32) / 256, 256, 0, stream>>>(A, st0);

  // layer 1
  agg_kernel128<<<aBlocks, 256, 0, stream>>>(off, deg, eid, ei, ea, A, l1We, l1be, AGG);
  mlp_kernel<128><<<782, 256, 0, stream>>>(A, AGG, l1W1, l1b1, l1W2, l1b2, B, st1, nChunks);
  bn_finalize<<<1, 128, 0, stream>>>(st1, l1g, l1bt);
  bn_apply<<<(NN * 32) / 256, 256, 0, stream>>>(B, st1);

  // head
  head_kernel<<<782, 256, 0, stream>>>(B, hW1, hb1, hW2, hb2, out, nChunks);
}

// Round 3
// 830.104 us; speedup vs baseline: 1.5731x; 1.3356x over previous
//
#include <hip/hip_runtime.h>

#define NN 100000
#define NE 1600000

typedef unsigned int uint32;
typedef __attribute__((ext_vector_type(8))) short bf16x8;
typedef __attribute__((ext_vector_type(4))) float f32x4;

__device__ __forceinline__ unsigned short f2bf(float f) {
  unsigned int u = __float_as_uint(f);
  unsigned int r = (u + 0x7fffu + ((u >> 16) & 1u)) >> 16;  // RNE
  return (unsigned short)r;
}
__device__ __forceinline__ float bf2f(unsigned short u) {
  return __uint_as_float(((unsigned int)u) << 16);
}
__device__ __forceinline__ unsigned int pack2(float a, float b) {
  return (unsigned int)f2bf(a) | ((unsigned int)f2bf(b) << 16);
}

// ---------------------------------------------------------------------------
// Weight convert: dst[n*K + k] = bf16(src[k*N + n])   (transpose to N-major)
// ---------------------------------------------------------------------------
__global__ __launch_bounds__(256) void wconv(const float* __restrict__ src,
    unsigned short* __restrict__ dst, int K, int N)
{
  const int i = blockIdx.x * 256 + threadIdx.x;
  if (i < K * N) {
    const int n = i / K, k = i - n * K;
    dst[i] = f2bf(src[k * N + n]);
  }
}

__global__ __launch_bounds__(256) void xconv(const float* __restrict__ x,
    unsigned short* __restrict__ xb)
{
  const int i = blockIdx.x * 256 + threadIdx.x;   // per 8 elems
  if (i * 8 < NN * 32) {
    const float4 a = ((const float4*)x)[i * 2];
    const float4 b = ((const float4*)x)[i * 2 + 1];
    uint4 o;
    o.x = pack2(a.x, a.y); o.y = pack2(a.z, a.w);
    o.z = pack2(b.x, b.y); o.w = pack2(b.z, b.w);
    ((uint4*)xb)[i] = o;
  }
}

// ---------------------------------------------------------------------------
// CSR build
// ---------------------------------------------------------------------------
__global__ __launch_bounds__(256) void hist_kernel(
    const int* __restrict__ ei, uint32* __restrict__ deg)
{
  const int e = blockIdx.x * 256 + threadIdx.x;
  if (e < NE) atomicAdd(&deg[ei[NE + e]], 1u);
}

__global__ __launch_bounds__(256) void offsets_kernel(
    const uint32* __restrict__ deg, uint32* __restrict__ off,
    uint32* __restrict__ cur, uint32* __restrict__ counter)
{
  __shared__ uint32 s[256];
  __shared__ uint32 base;
  const int tid = threadIdx.x;
  const int n = blockIdx.x * 256 + tid;
  const uint32 d = (n < NN) ? deg[n] : 0u;
  s[tid] = d;
  __syncthreads();
#pragma unroll
  for (int st = 1; st < 256; st <<= 1) {
    uint32 v = (tid >= st) ? s[tid - st] : 0u;
    __syncthreads();
    s[tid] += v;
    __syncthreads();
  }
  if (tid == 255) base = atomicAdd(counter, s[255]);
  __syncthreads();
  const uint32 excl = s[tid] - d;
  if (n < NN) { off[n] = base + excl; cur[n] = base + excl; }
}

__global__ __launch_bounds__(256) void fill_kernel(
    const int* __restrict__ ei, uint32* __restrict__ cur,
    uint32* __restrict__ eid)
{
  const int e = blockIdx.x * 256 + threadIdx.x;
  if (e < NE) {
    const uint32 slot = atomicAdd(&cur[ei[NE + e]], 1u);
    eid[slot] = (uint32)e;
  }
}

// ---------------------------------------------------------------------------
// agg32: quarter-wave per edge, 2 ch/lane, bf16 x gather
// ---------------------------------------------------------------------------
__global__ __launch_bounds__(256) void agg32(
    const uint32* __restrict__ off, const uint32* __restrict__ deg,
    const uint32* __restrict__ eid, const int* __restrict__ ei,
    const float* __restrict__ ea, const unsigned short* __restrict__ xb,
    const float* __restrict__ We, const float* __restrict__ be,
    float* __restrict__ agg)
{
  const int lane = threadIdx.x & 63;
  const int qw = lane >> 4;
  const int c = lane & 15;
  const int n = blockIdx.x * 4 + (threadIdx.x >> 6);
  float w0[16], w1[16];
#pragma unroll
  for (int k = 0; k < 16; ++k) {
    w0[k] = We[k * 32 + 2 * c];
    w1[k] = We[k * 32 + 2 * c + 1];
  }
  const float b0 = be[2 * c], b1v = be[2 * c + 1];
  const uint32 o = off[n], dn = deg[n];
  float a0 = 0.f, a1 = 0.f;
  for (uint32 i = (uint32)qw; i < dn; i += 4) {
    const int e = (int)eid[o + i];
    const int src = ei[e];
    const unsigned int hx = *(const unsigned int*)&xb[src * 32 + 2 * c];
    const float4* er = (const float4*)(ea + (size_t)e * 16);
    const float4 q0 = er[0], q1 = er[1], q2 = er[2], q3 = er[3];
    float m0 = b0 + bf2f((unsigned short)(hx & 0xffffu));
    float m1 = b1v + bf2f((unsigned short)(hx >> 16));
    m0 = fmaf(q0.x, w0[0],  m0); m1 = fmaf(q0.x, w1[0],  m1);
    m0 = fmaf(q0.y, w0[1],  m0); m1 = fmaf(q0.y, w1[1],  m1);
    m0 = fmaf(q0.z, w0[2],  m0); m1 = fmaf(q0.z, w1[2],  m1);
    m0 = fmaf(q0.w, w0[3],  m0); m1 = fmaf(q0.w, w1[3],  m1);
    m0 = fmaf(q1.x, w0[4],  m0); m1 = fmaf(q1.x, w1[4],  m1);
    m0 = fmaf(q1.y, w0[5],  m0); m1 = fmaf(q1.y, w1[5],  m1);
    m0 = fmaf(q1.z, w0[6],  m0); m1 = fmaf(q1.z, w1[6],  m1);
    m0 = fmaf(q1.w, w0[7],  m0); m1 = fmaf(q1.w, w1[7],  m1);
    m0 = fmaf(q2.x, w0[8],  m0); m1 = fmaf(q2.x, w1[8],  m1);
    m0 = fmaf(q2.y, w0[9],  m0); m1 = fmaf(q2.y, w1[9],  m1);
    m0 = fmaf(q2.z, w0[10], m0); m1 = fmaf(q2.z, w1[10], m1);
    m0 = fmaf(q2.w, w0[11], m0); m1 = fmaf(q2.w, w1[11], m1);
    m0 = fmaf(q3.x, w0[12], m0); m1 = fmaf(q3.x, w1[12], m1);
    m0 = fmaf(q3.y, w0[13], m0); m1 = fmaf(q3.y, w1[13], m1);
    m0 = fmaf(q3.z, w0[14], m0); m1 = fmaf(q3.z, w1[14], m1);
    m0 = fmaf(q3.w, w0[15], m0); m1 = fmaf(q3.w, w1[15], m1);
    a0 += fmaxf(m0, 0.f);
    a1 += fmaxf(m1, 0.f);
  }
  a0 += __shfl_xor(a0, 16); a0 += __shfl_xor(a0, 32);
  a1 += __shfl_xor(a1, 16); a1 += __shfl_xor(a1, 32);
  if (qw == 0) *(float2*)&agg[n * 32 + 2 * c] = make_float2(a0, a1);
}

// ---------------------------------------------------------------------------
// agg128: half-wave per edge, 4 ch/lane, bf16 h gather, 2-ahead prefetch
// ---------------------------------------------------------------------------
__global__ __launch_bounds__(256) void agg128(
    const uint32* __restrict__ off, const uint32* __restrict__ deg,
    const uint32* __restrict__ eid, const int* __restrict__ ei,
    const float* __restrict__ ea, const unsigned short* __restrict__ hb,
    const float* __restrict__ We, const float* __restrict__ be,
    float* __restrict__ agg)
{
  const int lane = threadIdx.x & 63;
  const int hw = lane >> 5;
  const int c = lane & 31;     // ch quad = 4c..4c+3
  const int n = blockIdx.x * 4 + (threadIdx.x >> 6);
  float w[16][4];
#pragma unroll
  for (int k = 0; k < 16; ++k)
#pragma unroll
    for (int q = 0; q < 4; ++q) w[k][q] = We[k * 128 + 4 * c + q];
  float bev[4];
#pragma unroll
  for (int q = 0; q < 4; ++q) bev[q] = be[4 * c + q];

  const uint32 o = off[n], dn = deg[n];
  float a0 = 0.f, a1 = 0.f, a2 = 0.f, a3 = 0.f;

  uint32 i = (uint32)hw;
  int e0 = 0, s0 = 0;
  bool have = i < dn;
  if (have) { e0 = (int)eid[o + i]; s0 = ei[e0]; }
  while (have) {
    const uint32 in = i + 2;
    const bool hn = in < dn;
    int e1 = 0, s1 = 0;
    if (hn) { e1 = (int)eid[o + in]; s1 = ei[e1]; }   // prefetch next
    const uint2 hx = *(const uint2*)&hb[s0 * 128 + 4 * c];
    const float4* er = (const float4*)(ea + (size_t)e0 * 16);
    const float4 q0 = er[0], q1 = er[1], q2 = er[2], q3 = er[3];
    float m0 = bev[0] + bf2f((unsigned short)(hx.x & 0xffffu));
    float m1 = bev[1] + bf2f((unsigned short)(hx.x >> 16));
    float m2 = bev[2] + bf2f((unsigned short)(hx.y & 0xffffu));
    float m3 = bev[3] + bf2f((unsigned short)(hx.y >> 16));
#define EK(kv, sv) \
    m0 = fmaf(sv, w[kv][0], m0); m1 = fmaf(sv, w[kv][1], m1); \
    m2 = fmaf(sv, w[kv][2], m2); m3 = fmaf(sv, w[kv][3], m3);
    EK(0, q0.x) EK(1, q0.y) EK(2, q0.z) EK(3, q0.w)
    EK(4, q1.x) EK(5, q1.y) EK(6, q1.z) EK(7, q1.w)
    EK(8, q2.x) EK(9, q2.y) EK(10, q2.z) EK(11, q2.w)
    EK(12, q3.x) EK(13, q3.y) EK(14, q3.z) EK(15, q3.w)
#undef EK
    a0 += fmaxf(m0, 0.f); a1 += fmaxf(m1, 0.f);
    a2 += fmaxf(m2, 0.f); a3 += fmaxf(m3, 0.f);
    i = in; e0 = e1; s0 = s1; have = hn;
  }
  a0 += __shfl_xor(a0, 32); a1 += __shfl_xor(a1, 32);
  a2 += __shfl_xor(a2, 32); a3 += __shfl_xor(a3, 32);
  if (hw == 0) *(float4*)&agg[n * 128 + 4 * c] = make_float4(a0, a1, a2, a3);
}

// ---------------------------------------------------------------------------
// MFMA node MLP: out = relu((a+agg)@W1+b1)@W2+b2, + BN stats.
// 4 waves; wave w owns ch window [w*32, w*32+32); persistent B-frags in VGPR.
// ---------------------------------------------------------------------------
template<int DIN, bool ABF16>
__global__ __launch_bounds__(256) void mlp_mfma(
    const float* __restrict__ a32, const unsigned short* __restrict__ abf,
    const float* __restrict__ agg,
    const unsigned short* __restrict__ W1t, const float* __restrict__ b1,
    const unsigned short* __restrict__ W2t, const float* __restrict__ b2,
    float* __restrict__ outp, float* __restrict__ stats, int nChunks)
{
  constexpr int P1 = (DIN == 128) ? 136 : 40;   // padded pitch (bf16 elems)
  constexpr int KS1 = DIN / 32;
  __shared__ __align__(16) unsigned short hin[64 * P1];
  __shared__ __align__(16) unsigned short tls[64 * 136];
  const int tid = threadIdx.x;
  const int w = tid >> 6;
  const int lane = tid & 63;
  const int c = lane & 15, g = lane >> 4;
  const int cw = w * 32;

  bf16x8 B1[2][KS1], B2[2][4];
#pragma unroll
  for (int ct = 0; ct < 2; ++ct)
#pragma unroll
    for (int kk = 0; kk < KS1; ++kk)
      B1[ct][kk] = *(const bf16x8*)&W1t[(cw + ct * 16 + c) * DIN + kk * 32 + g * 8];
#pragma unroll
  for (int ct = 0; ct < 2; ++ct)
#pragma unroll
    for (int kk = 0; kk < 4; ++kk)
      B2[ct][kk] = *(const bf16x8*)&W2t[(cw + ct * 16 + c) * 128 + kk * 32 + g * 8];
  const float b1c0 = b1[cw + c], b1c1 = b1[cw + 16 + c];
  const float b2c0 = b2[cw + c], b2c1 = b2[cw + 16 + c];
  float lsum0 = 0.f, lsum1 = 0.f, lsq0 = 0.f, lsq1 = 0.f;

  for (int chunk = blockIdx.x; chunk < nChunks; chunk += gridDim.x) {
    const int base = chunk * 64;
    // ---- stage hin = bf16(a + agg), zero OOB rows ----
    if constexpr (DIN == 128) {
#pragma unroll
      for (int p = 0; p < 4; ++p) {
        const int idx = tid + 256 * p;
        const int n = idx >> 4, k8 = idx & 15;
        const int node = base + n;
        uint4 ov = make_uint4(0u, 0u, 0u, 0u);
        if (node < NN) {
          const float4 g0 = *(const float4*)&agg[node * 128 + k8 * 8];
          const float4 g1 = *(const float4*)&agg[node * 128 + k8 * 8 + 4];
          const uint4 hv = *(const uint4*)&abf[node * 128 + k8 * 8];
          ov.x = pack2(bf2f((unsigned short)(hv.x & 0xffffu)) + g0.x,
                       bf2f((unsigned short)(hv.x >> 16)) + g0.y);
          ov.y = pack2(bf2f((unsigned short)(hv.y & 0xffffu)) + g0.z,
                       bf2f((unsigned short)(hv.y >> 16)) + g0.w);
          ov.z = pack2(bf2f((unsigned short)(hv.z & 0xffffu)) + g1.x,
                       bf2f((unsigned short)(hv.z >> 16)) + g1.y);
          ov.w = pack2(bf2f((unsigned short)(hv.w & 0xffffu)) + g1.z,
                       bf2f((unsigned short)(hv.w >> 16)) + g1.w);
        }
        *(uint4*)&hin[n * P1 + k8 * 8] = ov;
      }
    } else {
      const int n = tid >> 2, k8 = tid & 3;
      const int node = base + n;
      uint4 ov = make_uint4(0u, 0u, 0u, 0u);
      if (node < NN) {
        const float4 x0 = *(const float4*)&a32[node * 32 + k8 * 8];
        const float4 x1 = *(const float4*)&a32[node * 32 + k8 * 8 + 4];
        const float4 g0 = *(const float4*)&agg[node * 32 + k8 * 8];
        const float4 g1 = *(const float4*)&agg[node * 32 + k8 * 8 + 4];
        ov.x = pack2(x0.x + g0.x, x0.y + g0.y);
        ov.y = pack2(x0.z + g0.z, x0.w + g0.w);
        ov.z = pack2(x1.x + g1.x, x1.y + g1.y);
        ov.w = pack2(x1.z + g1.z, x1.w + g1.w);
      }
      *(uint4*)&hin[n * P1 + k8 * 8] = ov;
    }
    __syncthreads();
    // ---- phase 1: t = relu(hin@W1 + b1) -> tls (this wave's ch window) ----
#pragma unroll
    for (int nt = 0; nt < 4; ++nt) {
      bf16x8 af[KS1];
#pragma unroll
      for (int kk = 0; kk < KS1; ++kk)
        af[kk] = *(const bf16x8*)&hin[(nt * 16 + c) * P1 + kk * 32 + g * 8];
      f32x4 acc0 = {0.f, 0.f, 0.f, 0.f}, acc1 = {0.f, 0.f, 0.f, 0.f};
#pragma unroll
      for (int kk = 0; kk < KS1; ++kk) {
        acc0 = __builtin_amdgcn_mfma_f32_16x16x32_bf16(af[kk], B1[0][kk], acc0, 0, 0, 0);
        acc1 = __builtin_amdgcn_mfma_f32_16x16x32_bf16(af[kk], B1[1][kk], acc1, 0, 0, 0);
      }
#pragma unroll
      for (int j = 0; j < 4; ++j) {
        const int row = nt * 16 + g * 4 + j;
        tls[row * 136 + cw + c]      = f2bf(fmaxf(acc0[j] + b1c0, 0.f));
        tls[row * 136 + cw + 16 + c] = f2bf(fmaxf(acc1[j] + b1c1, 0.f));
      }
    }
    __syncthreads();
    // ---- phase 2: out = t@W2 + b2, write + stats ----
#pragma unroll
    for (int nt = 0; nt < 4; ++nt) {
      bf16x8 af[4];
#pragma unroll
      for (int kk = 0; kk < 4; ++kk)
        af[kk] = *(const bf16x8*)&tls[(nt * 16 + c) * 136 + kk * 32 + g * 8];
      f32x4 acc0 = {0.f, 0.f, 0.f, 0.f}, acc1 = {0.f, 0.f, 0.f, 0.f};
#pragma unroll
      for (int kk = 0; kk < 4; ++kk) {
        acc0 = __builtin_amdgcn_mfma_f32_16x16x32_bf16(af[kk], B2[0][kk], acc0, 0, 0, 0);
        acc1 = __builtin_amdgcn_mfma_f32_16x16x32_bf16(af[kk], B2[1][kk], acc1, 0, 0, 0);
      }
#pragma unroll
      for (int j = 0; j < 4; ++j) {
        const int node = base + nt * 16 + g * 4 + j;
        if (node < NN) {
          const float v0 = acc0[j] + b2c0;
          const float v1 = acc1[j] + b2c1;
          outp[node * 128 + cw + c] = v0;
          outp[node * 128 + cw + 16 + c] = v1;
          lsum0 += v0; lsq0 += v0 * v0;
          lsum1 += v1; lsq1 += v1 * v1;
        }
      }
    }
  }
  lsum0 += __shfl_xor(lsum0, 16); lsum0 += __shfl_xor(lsum0, 32);
  lsum1 += __shfl_xor(lsum1, 16); lsum1 += __shfl_xor(lsum1, 32);
  lsq0  += __shfl_xor(lsq0, 16);  lsq0  += __shfl_xor(lsq0, 32);
  lsq1  += __shfl_xor(lsq1, 16);  lsq1  += __shfl_xor(lsq1, 32);
  if (lane < 16) {
    atomicAdd(&stats[cw + lane], lsum0);
    atomicAdd(&stats[cw + 16 + lane], lsum1);
    atomicAdd(&stats[128 + cw + lane], lsq0);
    atomicAdd(&stats[128 + cw + 16 + lane], lsq1);
  }
}

// stats: [0:128) sum, [128:256) sumsq -> [256:384) scale, [384:512) shift
__global__ void bn_finalize(float* __restrict__ stats,
                            const float* __restrict__ gamma,
                            const float* __restrict__ beta)
{
  const int cc = threadIdx.x;
  const float inv_n = 1.0f / (float)NN;
  const float mu = stats[cc] * inv_n;
  float var = stats[128 + cc] * inv_n - mu * mu;
  var = fmaxf(var, 0.f);
  const float rs = rsqrtf(var + 1e-5f);
  const float sc = rs * gamma[cc];
  stats[256 + cc] = sc;
  stats[384 + cc] = beta[cc] - mu * sc;
}

// h_bf16 = bf16(relu(hpre*scale + shift))
__global__ __launch_bounds__(256) void bn_apply_bf16(
    const float* __restrict__ h, const float* __restrict__ stats,
    unsigned short* __restrict__ hb)
{
  const int idx = blockIdx.x * 256 + threadIdx.x;   // over NN*32 float4s
  const int c4 = (idx & 31) * 4;
  const float4 sc = *(const float4*)&stats[256 + c4];
  const float4 sh = *(const float4*)&stats[384 + c4];
  const float4 v = ((const float4*)h)[idx];
  const float r0 = fmaxf(fmaf(v.x, sc.x, sh.x), 0.f);
  const float r1 = fmaxf(fmaf(v.y, sc.y, sh.y), 0.f);
  const float r2 = fmaxf(fmaf(v.z, sc.z, sh.z), 0.f);
  const float r3 = fmaxf(fmaf(v.w, sc.w, sh.w), 0.f);
  uint2 o;
  o.x = pack2(r0, r1);
  o.y = pack2(r2, r3);
  ((uint2*)hb)[idx] = o;
}

// ---------------------------------------------------------------------------
// Head: out = sigmoid(relu(h@W1+b1)@w2 + b2); phase1 MFMA (A direct from hb)
// ---------------------------------------------------------------------------
__global__ __launch_bounds__(256) void head_mfma(
    const unsigned short* __restrict__ hb, const unsigned short* __restrict__ W1t,
    const float* __restrict__ b1, const float* __restrict__ w2,
    const float* __restrict__ b2, float* __restrict__ out, int nChunks)
{
  __shared__ float pl[4][64];
  const int tid = threadIdx.x;
  const int w = tid >> 6;
  const int lane = tid & 63;
  const int c = lane & 15, g = lane >> 4;
  const int cw = w * 32;

  bf16x8 B1[2][4];
#pragma unroll
  for (int ct = 0; ct < 2; ++ct)
#pragma unroll
    for (int kk = 0; kk < 4; ++kk)
      B1[ct][kk] = *(const bf16x8*)&W1t[(cw + ct * 16 + c) * 128 + kk * 32 + g * 8];
  const float b1c0 = b1[cw + c], b1c1 = b1[cw + 16 + c];
  const float w2c0 = w2[cw + c], w2c1 = w2[cw + 16 + c];
  const float b2v = b2[0];

  for (int chunk = blockIdx.x; chunk < nChunks; chunk += gridDim.x) {
    const int base = chunk * 64;
    float p[4][4];
#pragma unroll
    for (int nt = 0; nt < 4; ++nt) {
      bf16x8 af[4];
#pragma unroll
      for (int kk = 0; kk < 4; ++kk)
        af[kk] = *(const bf16x8*)&hb[(size_t)(base + nt * 16 + c) * 128 + kk * 32 + g * 8];
      f32x4 acc0 = {0.f, 0.f, 0.f, 0.f}, acc1 = {0.f, 0.f, 0.f, 0.f};
#pragma unroll
      for (int kk = 0; kk < 4; ++kk) {
        acc0 = __builtin_amdgcn_mfma_f32_16x16x32_bf16(af[kk], B1[0][kk], acc0, 0, 0, 0);
        acc1 = __builtin_amdgcn_mfma_f32_16x16x32_bf16(af[kk], B1[1][kk], acc1, 0, 0, 0);
      }
#pragma unroll
      for (int j = 0; j < 4; ++j)
        p[nt][j] = fmaxf(acc0[j] + b1c0, 0.f) * w2c0 +
                   fmaxf(acc1[j] + b1c1, 0.f) * w2c1;
    }
#pragma unroll
    for (int d = 1; d <= 8; d <<= 1)
#pragma unroll
      for (int nt = 0; nt < 4; ++nt)
#pragma unroll
        for (int j = 0; j < 4; ++j)
          p[nt][j] += __shfl_xor(p[nt][j], d);
    if (c == 0) {
#pragma unroll
      for (int nt = 0; nt < 4; ++nt)
#pragma unroll
        for (int j = 0; j < 4; ++j)
          pl[w][nt * 16 + g * 4 + j] = p[nt][j];
    }
    __syncthreads();
    if (tid < 64) {
      const int node = base + tid;
      if (node < NN) {
        const float s = pl[0][tid] + pl[1][tid] + pl[2][tid] + pl[3][tid] + b2v;
        out[node] = 1.f / (1.f + expf(-s));
      }
    }
    __syncthreads();
  }
}

extern "C" void kernel_launch(void* const* d_in, const int* in_sizes, int n_in,
                              void* d_out, int out_size, void* d_ws, size_t ws_size,
                              hipStream_t stream)
{
  const float* x    = (const float*)d_in[0];
  const int*   ei   = (const int*)  d_in[1];
  const float* ea   = (const float*)d_in[2];
  const float* l0We = (const float*)d_in[3];
  const float* l0be = (const float*)d_in[4];
  const float* l0W1 = (const float*)d_in[5];
  const float* l0b1 = (const float*)d_in[6];
  const float* l0W2 = (const float*)d_in[7];
  const float* l0b2 = (const float*)d_in[8];
  const float* l0g  = (const float*)d_in[9];
  const float* l0bt = (const float*)d_in[10];
  const float* l1We = (const float*)d_in[11];
  const float* l1be = (const float*)d_in[12];
  const float* l1W1 = (const float*)d_in[13];
  const float* l1b1 = (const float*)d_in[14];
  const float* l1W2 = (const float*)d_in[15];
  const float* l1b2 = (const float*)d_in[16];
  const float* l1g  = (const float*)d_in[17];
  const float* l1bt = (const float*)d_in[18];
  const float* hW1  = (const float*)d_in[19];
  const float* hb1  = (const float*)d_in[20];
  const float* hW2  = (const float*)d_in[21];
  const float* hb2  = (const float*)d_in[22];
  float* out = (float*)d_out;

  // workspace (~142.2 MB)
  float*  A    = (float*)d_ws;                         // NN*128 f32 (hpre)
  float*  AGG  = A + (size_t)NN * 128;                 // NN*128 f32
  unsigned short* hb = (unsigned short*)(AGG + (size_t)NN * 128);  // NN*128 bf16
  unsigned short* xb = hb + (size_t)NN * 128;          // NN*32 bf16
  uint32* deg     = (uint32*)(xb + (size_t)NN * 32);   // NN
  uint32* off     = deg + NN;                          // NN
  uint32* cur     = off + NN;                          // NN
  uint32* counter = cur + NN;                          // 4
  uint32* eid     = counter + 4;                       // NE
  float*  st0     = (float*)(eid + NE);                // 512
  float*  st1     = st0 + 512;                         // 512
  unsigned short* W1t0 = (unsigned short*)(st1 + 512); // 128*32
  unsigned short* W2t0 = W1t0 + 4096;                  // 128*128
  unsigned short* W1t1 = W2t0 + 16384;
  unsigned short* W2t1 = W1t1 + 16384;
  unsigned short* hW1t = W2t1 + 16384;

  const size_t needed = (size_t)NN * 128 * 4 * 2 + (size_t)NN * 128 * 2 +
                        (size_t)NN * 32 * 2 + ((size_t)3 * NN + 4) * 4 +
                        (size_t)NE * 4 + 4096 + (size_t)69632 * 2;
  if (ws_size < needed) return;

  hipMemsetAsync(deg, 0, (size_t)NN * 4, stream);
  hipMemsetAsync(counter, 0, 16, stream);
  hipMemsetAsync(st0, 0, 4096, stream);   // st0 + st1

  const int nChunks = (NN + 63) / 64;     // 1563

  // weight/activation converts
  wconv<<<16, 256, 0, stream>>>(l0W1, W1t0, 32, 128);
  wconv<<<64, 256, 0, stream>>>(l0W2, W2t0, 128, 128);
  wconv<<<64, 256, 0, stream>>>(l1W1, W1t1, 128, 128);
  wconv<<<64, 256, 0, stream>>>(l1W2, W2t1, 128, 128);
  wconv<<<64, 256, 0, stream>>>(hW1, hW1t, 128, 128);
  xconv<<<1563, 256, 0, stream>>>(x, xb);

  // CSR build (shared by both layers)
  hist_kernel<<<(NE + 255) / 256, 256, 0, stream>>>(ei, deg);
  offsets_kernel<<<(NN + 255) / 256, 256, 0, stream>>>(deg, off, cur, counter);
  fill_kernel<<<(NE + 255) / 256, 256, 0, stream>>>(ei, cur, eid);

  // layer 0
  agg32<<<NN / 4, 256, 0, stream>>>(off, deg, eid, ei, ea, xb, l0We, l0be, AGG);
  mlp_mfma<32, false><<<782, 256, 0, stream>>>(x, (const unsigned short*)nullptr,
      AGG, W1t0, l0b1, W2t0, l0b2, A, st0, nChunks);
  bn_finalize<<<1, 128, 0, stream>>>(st0, l0g, l0bt);
  bn_apply_bf16<<<(NN * 32) / 256, 256, 0, stream>>>(A, st0, hb);

  // layer 1
  agg128<<<NN / 4, 256, 0, stream>>>(off, deg, eid, ei, ea, hb, l1We, l1be, AGG);
  mlp_mfma<128, true><<<782, 256, 0, stream>>>((const float*)nullptr, hb,
      AGG, W1t1, l1b1, W2t1, l1b2, A, st1, nChunks);
  bn_finalize<<<1, 128, 0, stream>>>(st1, l1g, l1bt);
  bn_apply_bf16<<<(NN * 32) / 256, 256, 0, stream>>>(A, st1, hb);

  // head
  head_mfma<<<782, 256, 0, stream>>>(hb, hW1t, hb1, hW2, hb2, out, nChunks);
}

// Round 4
// 808.896 us; speedup vs baseline: 1.6143x; 1.0262x over previous
//
#include <hip/hip_runtime.h>

#define NN 100000
#define NE 1600000

typedef unsigned int uint32;
typedef __attribute__((ext_vector_type(8))) short bf16x8;
typedef __attribute__((ext_vector_type(4))) float f32x4;

__device__ __forceinline__ unsigned short f2bf(float f) {
  unsigned int u = __float_as_uint(f);
  unsigned int r = (u + 0x7fffu + ((u >> 16) & 1u)) >> 16;  // RNE
  return (unsigned short)r;
}
__device__ __forceinline__ float bf2f(unsigned short u) {
  return __uint_as_float(((unsigned int)u) << 16);
}
__device__ __forceinline__ unsigned int pack2(float a, float b) {
  return (unsigned int)f2bf(a) | ((unsigned int)f2bf(b) << 16);
}

// ---------------------------------------------------------------------------
// Weight convert: dst[n*K + k] = bf16(src[k*N + n])   (transpose to N-major)
// ---------------------------------------------------------------------------
__global__ __launch_bounds__(256) void wconv(const float* __restrict__ src,
    unsigned short* __restrict__ dst, int K, int N)
{
  const int i = blockIdx.x * 256 + threadIdx.x;
  if (i < K * N) {
    const int n = i / K, k = i - n * K;
    dst[i] = f2bf(src[k * N + n]);
  }
}

__global__ __launch_bounds__(256) void xconv(const float* __restrict__ x,
    unsigned short* __restrict__ xb)
{
  const int i = blockIdx.x * 256 + threadIdx.x;   // per 8 elems
  if (i * 8 < NN * 32) {
    const float4 a = ((const float4*)x)[i * 2];
    const float4 b = ((const float4*)x)[i * 2 + 1];
    uint4 o;
    o.x = pack2(a.x, a.y); o.y = pack2(a.z, a.w);
    o.z = pack2(b.x, b.y); o.w = pack2(b.z, b.w);
    ((uint4*)xb)[i] = o;
  }
}

// ---------------------------------------------------------------------------
// CSR build
// ---------------------------------------------------------------------------
__global__ __launch_bounds__(256) void hist_kernel(
    const int* __restrict__ ei, uint32* __restrict__ deg)
{
  const int e = blockIdx.x * 256 + threadIdx.x;
  if (e < NE) atomicAdd(&deg[ei[NE + e]], 1u);
}

__global__ __launch_bounds__(256) void offsets_kernel(
    const uint32* __restrict__ deg, uint32* __restrict__ off,
    uint32* __restrict__ cur, uint32* __restrict__ counter)
{
  __shared__ uint32 s[256];
  __shared__ uint32 base;
  const int tid = threadIdx.x;
  const int n = blockIdx.x * 256 + tid;
  const uint32 d = (n < NN) ? deg[n] : 0u;
  s[tid] = d;
  __syncthreads();
#pragma unroll
  for (int st = 1; st < 256; st <<= 1) {
    uint32 v = (tid >= st) ? s[tid - st] : 0u;
    __syncthreads();
    s[tid] += v;
    __syncthreads();
  }
  if (tid == 255) base = atomicAdd(counter, s[255]);
  __syncthreads();
  const uint32 excl = s[tid] - d;
  if (n < NN) { off[n] = base + excl; cur[n] = base + excl; }
}

__global__ __launch_bounds__(256) void fill_kernel(
    const int* __restrict__ ei, uint32* __restrict__ cur,
    uint2* __restrict__ esrc)
{
  const int e = blockIdx.x * 256 + threadIdx.x;
  if (e < NE) {
    const int dst = ei[NE + e];
    const uint32 slot = atomicAdd(&cur[dst], 1u);
    esrc[slot] = make_uint2((uint32)e, (uint32)ei[e]);
  }
}

// ---------------------------------------------------------------------------
// Fused edge transform + gather + segment-sum.
// One wave per node. Per 16-edge CSR tile:
//   pre[ch][edge] = MFMA(We^T (+be at k=16), ea_tile (+1.0 at k=16))
//   msg = relu(pre + h[src][ch]); acc += msg (masked); reduce over edges.
// Output lane(c,g),j: ch = ct*16+g*4+j, edge = c  (A-rows->rows, B-cols->cols)
// ---------------------------------------------------------------------------
template<int D>
__global__ __launch_bounds__(256) void fused_agg(
    const uint32* __restrict__ off, const uint32* __restrict__ deg,
    const uint2* __restrict__ esrc, const float* __restrict__ ea,
    const unsigned short* __restrict__ hsrc,   // bf16 [NN, D]
    const unsigned short* __restrict__ Wet,    // bf16 [D, 16] N-major
    const float* __restrict__ be,
    float* __restrict__ agg)                   // f32 [NN, D]
{
  constexpr int NCT = D / 16;
  __shared__ float red[4][D];
  const int tid = threadIdx.x;
  const int wid = tid >> 6;
  const int lane = tid & 63;
  const int c = lane & 15;
  const int g = lane >> 4;
  const int n = blockIdx.x * 4 + wid;

  // persistent W-fragments (A operand), bias folded at k=16
  bf16x8 wf[NCT];
#pragma unroll
  for (int ct = 0; ct < NCT; ++ct) {
    uint4 u = make_uint4(0u, 0u, 0u, 0u);
    if (g < 2) u = *(const uint4*)&Wet[(ct * 16 + c) * 16 + g * 8];
    else if (g == 2) u.x = (unsigned int)f2bf(be[ct * 16 + c]);
    union { uint4 u4; bf16x8 v; } cv; cv.u4 = u;
    wf[ct] = cv.v;
  }

  const uint32 o = off[n];
  const uint32 d = deg[n];
  const uint32 endp = o + d;
  f32x4 acc[NCT];
#pragma unroll
  for (int ct = 0; ct < NCT; ++ct) acc[ct] = (f32x4){0.f, 0.f, 0.f, 0.f};

  const int ntiles = (int)((d + 15u) >> 4);
  for (int t = 0; t < ntiles; ++t) {
    const uint32 s0 = o + (uint32)t * 16u;
    uint2 ld = make_uint2(0u, 0u);
    if (lane < 16 && (s0 + (uint32)lane) < endp) ld = esrc[s0 + lane];
    const int e  = __shfl((int)ld.x, c);
    const int sr = __shfl((int)ld.y, c);
    const bool valid = (s0 + (uint32)c) < endp;

    // B operand: ea rows for 16 edges, K padded to 32, 1.0 at k=16
    bf16x8 af;
    {
      uint4 u = make_uint4(0u, 0u, 0u, 0u);
      if (g < 2) {
        const float4 p0 = *(const float4*)&ea[(size_t)e * 16 + g * 8];
        const float4 p1 = *(const float4*)&ea[(size_t)e * 16 + g * 8 + 4];
        u.x = pack2(p0.x, p0.y); u.y = pack2(p0.z, p0.w);
        u.z = pack2(p1.x, p1.y); u.w = pack2(p1.z, p1.w);
      } else if (g == 2) {
        u.x = 0x3f80u;   // bf16(1.0) in k=16 slot
      }
      union { uint4 u4; bf16x8 v; } cv; cv.u4 = u;
      af = cv.v;
    }

#pragma unroll
    for (int ct = 0; ct < NCT; ++ct) {
      f32x4 pre = __builtin_amdgcn_mfma_f32_16x16x32_bf16(
          wf[ct], af, (f32x4){0.f, 0.f, 0.f, 0.f}, 0, 0, 0);
      const uint2 hx = *(const uint2*)&hsrc[(size_t)sr * D + ct * 16 + g * 4];
      const float m0 = fmaxf(pre[0] + bf2f((unsigned short)(hx.x & 0xffffu)), 0.f);
      const float m1 = fmaxf(pre[1] + bf2f((unsigned short)(hx.x >> 16)), 0.f);
      const float m2 = fmaxf(pre[2] + bf2f((unsigned short)(hx.y & 0xffffu)), 0.f);
      const float m3 = fmaxf(pre[3] + bf2f((unsigned short)(hx.y >> 16)), 0.f);
      if (valid) {
        acc[ct][0] += m0; acc[ct][1] += m1;
        acc[ct][2] += m2; acc[ct][3] += m3;
      }
    }
  }

  // reduce over edge lanes (c) and stage per-wave row
#pragma unroll
  for (int ct = 0; ct < NCT; ++ct) {
#pragma unroll
    for (int j = 0; j < 4; ++j) {
      float v = acc[ct][j];
      v += __shfl_xor(v, 1); v += __shfl_xor(v, 2);
      v += __shfl_xor(v, 4); v += __shfl_xor(v, 8);
      if (c == 0) red[wid][ct * 16 + g * 4 + j] = v;
    }
  }
  __syncthreads();
  if (D == 128) {
    const float2 v = *(const float2*)&red[wid][lane * 2];
    *(float2*)&agg[(size_t)n * D + lane * 2] = v;
  } else {
    if (lane < 16) {
      const float2 v = *(const float2*)&red[wid][lane * 2];
      *(float2*)&agg[(size_t)n * D + lane * 2] = v;
    }
  }
}

// ---------------------------------------------------------------------------
// MFMA node MLP: out = relu((a+agg)@W1+b1)@W2+b2, + BN stats.
// ---------------------------------------------------------------------------
template<int DIN, bool ABF16>
__global__ __launch_bounds__(256) void mlp_mfma(
    const float* __restrict__ a32, const unsigned short* __restrict__ abf,
    const float* __restrict__ agg,
    const unsigned short* __restrict__ W1t, const float* __restrict__ b1,
    const unsigned short* __restrict__ W2t, const float* __restrict__ b2,
    float* __restrict__ outp, float* __restrict__ stats, int nChunks)
{
  constexpr int P1 = (DIN == 128) ? 136 : 40;
  constexpr int KS1 = DIN / 32;
  __shared__ __align__(16) unsigned short hin[64 * P1];
  __shared__ __align__(16) unsigned short tls[64 * 136];
  const int tid = threadIdx.x;
  const int w = tid >> 6;
  const int lane = tid & 63;
  const int c = lane & 15, g = lane >> 4;
  const int cw = w * 32;

  bf16x8 B1[2][KS1], B2[2][4];
#pragma unroll
  for (int ct = 0; ct < 2; ++ct)
#pragma unroll
    for (int kk = 0; kk < KS1; ++kk)
      B1[ct][kk] = *(const bf16x8*)&W1t[(cw + ct * 16 + c) * DIN + kk * 32 + g * 8];
#pragma unroll
  for (int ct = 0; ct < 2; ++ct)
#pragma unroll
    for (int kk = 0; kk < 4; ++kk)
      B2[ct][kk] = *(const bf16x8*)&W2t[(cw + ct * 16 + c) * 128 + kk * 32 + g * 8];
  const float b1c0 = b1[cw + c], b1c1 = b1[cw + 16 + c];
  const float b2c0 = b2[cw + c], b2c1 = b2[cw + 16 + c];
  float lsum0 = 0.f, lsum1 = 0.f, lsq0 = 0.f, lsq1 = 0.f;

  for (int chunk = blockIdx.x; chunk < nChunks; chunk += gridDim.x) {
    const int base = chunk * 64;
    if constexpr (DIN == 128) {
#pragma unroll
      for (int p = 0; p < 4; ++p) {
        const int idx = tid + 256 * p;
        const int n = idx >> 4, k8 = idx & 15;
        const int node = base + n;
        uint4 ov = make_uint4(0u, 0u, 0u, 0u);
        if (node < NN) {
          const float4 g0 = *(const float4*)&agg[node * 128 + k8 * 8];
          const float4 g1 = *(const float4*)&agg[node * 128 + k8 * 8 + 4];
          const uint4 hv = *(const uint4*)&abf[node * 128 + k8 * 8];
          ov.x = pack2(bf2f((unsigned short)(hv.x & 0xffffu)) + g0.x,
                       bf2f((unsigned short)(hv.x >> 16)) + g0.y);
          ov.y = pack2(bf2f((unsigned short)(hv.y & 0xffffu)) + g0.z,
                       bf2f((unsigned short)(hv.y >> 16)) + g0.w);
          ov.z = pack2(bf2f((unsigned short)(hv.z & 0xffffu)) + g1.x,
                       bf2f((unsigned short)(hv.z >> 16)) + g1.y);
          ov.w = pack2(bf2f((unsigned short)(hv.w & 0xffffu)) + g1.z,
                       bf2f((unsigned short)(hv.w >> 16)) + g1.w);
        }
        *(uint4*)&hin[n * P1 + k8 * 8] = ov;
      }
    } else {
      const int n = tid >> 2, k8 = tid & 3;
      const int node = base + n;
      uint4 ov = make_uint4(0u, 0u, 0u, 0u);
      if (node < NN) {
        const float4 x0 = *(const float4*)&a32[node * 32 + k8 * 8];
        const float4 x1 = *(const float4*)&a32[node * 32 + k8 * 8 + 4];
        const float4 g0 = *(const float4*)&agg[node * 32 + k8 * 8];
        const float4 g1 = *(const float4*)&agg[node * 32 + k8 * 8 + 4];
        ov.x = pack2(x0.x + g0.x, x0.y + g0.y);
        ov.y = pack2(x0.z + g0.z, x0.w + g0.w);
        ov.z = pack2(x1.x + g1.x, x1.y + g1.y);
        ov.w = pack2(x1.z + g1.z, x1.w + g1.w);
      }
      *(uint4*)&hin[n * P1 + k8 * 8] = ov;
    }
    __syncthreads();
#pragma unroll
    for (int nt = 0; nt < 4; ++nt) {
      bf16x8 af[KS1];
#pragma unroll
      for (int kk = 0; kk < KS1; ++kk)
        af[kk] = *(const bf16x8*)&hin[(nt * 16 + c) * P1 + kk * 32 + g * 8];
      f32x4 acc0 = {0.f, 0.f, 0.f, 0.f}, acc1 = {0.f, 0.f, 0.f, 0.f};
#pragma unroll
      for (int kk = 0; kk < KS1; ++kk) {
        acc0 = __builtin_amdgcn_mfma_f32_16x16x32_bf16(af[kk], B1[0][kk], acc0, 0, 0, 0);
        acc1 = __builtin_amdgcn_mfma_f32_16x16x32_bf16(af[kk], B1[1][kk], acc1, 0, 0, 0);
      }
#pragma unroll
      for (int j = 0; j < 4; ++j) {
        const int row = nt * 16 + g * 4 + j;
        tls[row * 136 + cw + c]      = f2bf(fmaxf(acc0[j] + b1c0, 0.f));
        tls[row * 136 + cw + 16 + c] = f2bf(fmaxf(acc1[j] + b1c1, 0.f));
      }
    }
    __syncthreads();
#pragma unroll
    for (int nt = 0; nt < 4; ++nt) {
      bf16x8 af[4];
#pragma unroll
      for (int kk = 0; kk < 4; ++kk)
        af[kk] = *(const bf16x8*)&tls[(nt * 16 + c) * 136 + kk * 32 + g * 8];
      f32x4 acc0 = {0.f, 0.f, 0.f, 0.f}, acc1 = {0.f, 0.f, 0.f, 0.f};
#pragma unroll
      for (int kk = 0; kk < 4; ++kk) {
        acc0 = __builtin_amdgcn_mfma_f32_16x16x32_bf16(af[kk], B2[0][kk], acc0, 0, 0, 0);
        acc1 = __builtin_amdgcn_mfma_f32_16x16x32_bf16(af[kk], B2[1][kk], acc1, 0, 0, 0);
      }
#pragma unroll
      for (int j = 0; j < 4; ++j) {
        const int node = base + nt * 16 + g * 4 + j;
        if (node < NN) {
          const float v0 = acc0[j] + b2c0;
          const float v1 = acc1[j] + b2c1;
          outp[node * 128 + cw + c] = v0;
          outp[node * 128 + cw + 16 + c] = v1;
          lsum0 += v0; lsq0 += v0 * v0;
          lsum1 += v1; lsq1 += v1 * v1;
        }
      }
    }
  }
  lsum0 += __shfl_xor(lsum0, 16); lsum0 += __shfl_xor(lsum0, 32);
  lsum1 += __shfl_xor(lsum1, 16); lsum1 += __shfl_xor(lsum1, 32);
  lsq0  += __shfl_xor(lsq0, 16);  lsq0  += __shfl_xor(lsq0, 32);
  lsq1  += __shfl_xor(lsq1, 16);  lsq1  += __shfl_xor(lsq1, 32);
  if (lane < 16) {
    atomicAdd(&stats[cw + lane], lsum0);
    atomicAdd(&stats[cw + 16 + lane], lsum1);
    atomicAdd(&stats[128 + cw + lane], lsq0);
    atomicAdd(&stats[128 + cw + 16 + lane], lsq1);
  }
}

__global__ void bn_finalize(float* __restrict__ stats,
                            const float* __restrict__ gamma,
                            const float* __restrict__ beta)
{
  const int cc = threadIdx.x;
  const float inv_n = 1.0f / (float)NN;
  const float mu = stats[cc] * inv_n;
  float var = stats[128 + cc] * inv_n - mu * mu;
  var = fmaxf(var, 0.f);
  const float rs = rsqrtf(var + 1e-5f);
  const float sc = rs * gamma[cc];
  stats[256 + cc] = sc;
  stats[384 + cc] = beta[cc] - mu * sc;
}

__global__ __launch_bounds__(256) void bn_apply_bf16(
    const float* __restrict__ h, const float* __restrict__ stats,
    unsigned short* __restrict__ hb)
{
  const int idx = blockIdx.x * 256 + threadIdx.x;
  const int c4 = (idx & 31) * 4;
  const float4 sc = *(const float4*)&stats[256 + c4];
  const float4 sh = *(const float4*)&stats[384 + c4];
  const float4 v = ((const float4*)h)[idx];
  const float r0 = fmaxf(fmaf(v.x, sc.x, sh.x), 0.f);
  const float r1 = fmaxf(fmaf(v.y, sc.y, sh.y), 0.f);
  const float r2 = fmaxf(fmaf(v.z, sc.z, sh.z), 0.f);
  const float r3 = fmaxf(fmaf(v.w, sc.w, sh.w), 0.f);
  uint2 o;
  o.x = pack2(r0, r1);
  o.y = pack2(r2, r3);
  ((uint2*)hb)[idx] = o;
}

// ---------------------------------------------------------------------------
// Head: out = sigmoid(relu(h@W1+b1)@w2 + b2)
// ---------------------------------------------------------------------------
__global__ __launch_bounds__(256) void head_mfma(
    const unsigned short* __restrict__ hb, const unsigned short* __restrict__ W1t,
    const float* __restrict__ b1, const float* __restrict__ w2,
    const float* __restrict__ b2, float* __restrict__ out, int nChunks)
{
  __shared__ float pl[4][64];
  const int tid = threadIdx.x;
  const int w = tid >> 6;
  const int lane = tid & 63;
  const int c = lane & 15, g = lane >> 4;
  const int cw = w * 32;

  bf16x8 B1[2][4];
#pragma unroll
  for (int ct = 0; ct < 2; ++ct)
#pragma unroll
    for (int kk = 0; kk < 4; ++kk)
      B1[ct][kk] = *(const bf16x8*)&W1t[(cw + ct * 16 + c) * 128 + kk * 32 + g * 8];
  const float b1c0 = b1[cw + c], b1c1 = b1[cw + 16 + c];
  const float w2c0 = w2[cw + c], w2c1 = w2[cw + 16 + c];
  const float b2v = b2[0];

  for (int chunk = blockIdx.x; chunk < nChunks; chunk += gridDim.x) {
    const int base = chunk * 64;
    float p[4][4];
#pragma unroll
    for (int nt = 0; nt < 4; ++nt) {
      bf16x8 af[4];
#pragma unroll
      for (int kk = 0; kk < 4; ++kk)
        af[kk] = *(const bf16x8*)&hb[(size_t)(base + nt * 16 + c) * 128 + kk * 32 + g * 8];
      f32x4 acc0 = {0.f, 0.f, 0.f, 0.f}, acc1 = {0.f, 0.f, 0.f, 0.f};
#pragma unroll
      for (int kk = 0; kk < 4; ++kk) {
        acc0 = __builtin_amdgcn_mfma_f32_16x16x32_bf16(af[kk], B1[0][kk], acc0, 0, 0, 0);
        acc1 = __builtin_amdgcn_mfma_f32_16x16x32_bf16(af[kk], B1[1][kk], acc1, 0, 0, 0);
      }
#pragma unroll
      for (int j = 0; j < 4; ++j)
        p[nt][j] = fmaxf(acc0[j] + b1c0, 0.f) * w2c0 +
                   fmaxf(acc1[j] + b1c1, 0.f) * w2c1;
    }
#pragma unroll
    for (int dd = 1; dd <= 8; dd <<= 1)
#pragma unroll
      for (int nt = 0; nt < 4; ++nt)
#pragma unroll
        for (int j = 0; j < 4; ++j)
          p[nt][j] += __shfl_xor(p[nt][j], dd);
    if (c == 0) {
#pragma unroll
      for (int nt = 0; nt < 4; ++nt)
#pragma unroll
        for (int j = 0; j < 4; ++j)
          pl[w][nt * 16 + g * 4 + j] = p[nt][j];
    }
    __syncthreads();
    if (tid < 64) {
      const int node = base + tid;
      if (node < NN) {
        const float s = pl[0][tid] + pl[1][tid] + pl[2][tid] + pl[3][tid] + b2v;
        out[node] = 1.f / (1.f + expf(-s));
      }
    }
    __syncthreads();
  }
}

extern "C" void kernel_launch(void* const* d_in, const int* in_sizes, int n_in,
                              void* d_out, int out_size, void* d_ws, size_t ws_size,
                              hipStream_t stream)
{
  const float* x    = (const float*)d_in[0];
  const int*   ei   = (const int*)  d_in[1];
  const float* ea   = (const float*)d_in[2];
  const float* l0We = (const float*)d_in[3];
  const float* l0be = (const float*)d_in[4];
  const float* l0W1 = (const float*)d_in[5];
  const float* l0b1 = (const float*)d_in[6];
  const float* l0W2 = (const float*)d_in[7];
  const float* l0b2 = (const float*)d_in[8];
  const float* l0g  = (const float*)d_in[9];
  const float* l0bt = (const float*)d_in[10];
  const float* l1We = (const float*)d_in[11];
  const float* l1be = (const float*)d_in[12];
  const float* l1W1 = (const float*)d_in[13];
  const float* l1b1 = (const float*)d_in[14];
  const float* l1W2 = (const float*)d_in[15];
  const float* l1b2 = (const float*)d_in[16];
  const float* l1g  = (const float*)d_in[17];
  const float* l1bt = (const float*)d_in[18];
  const float* hW1  = (const float*)d_in[19];
  const float* hb1  = (const float*)d_in[20];
  const float* hW2  = (const float*)d_in[21];
  const float* hb2  = (const float*)d_in[22];
  float* out = (float*)d_out;

  // workspace (~149 MB)
  float*  A    = (float*)d_ws;                         // NN*128 f32 (hpre)
  float*  AGG  = A + (size_t)NN * 128;                 // NN*128 f32
  unsigned short* hb = (unsigned short*)(AGG + (size_t)NN * 128);  // NN*128 bf16
  unsigned short* xb = hb + (size_t)NN * 128;          // NN*32 bf16
  uint32* deg     = (uint32*)(xb + (size_t)NN * 32);   // NN
  uint32* off     = deg + NN;                          // NN
  uint32* cur     = off + NN;                          // NN
  uint32* counter = cur + NN;                          // 4
  uint2*  esrc    = (uint2*)(counter + 4);             // NE (8 B each)
  float*  st0     = (float*)(esrc + NE);               // 512
  float*  st1     = st0 + 512;                         // 512
  unsigned short* W1t0 = (unsigned short*)(st1 + 512); // 128*32
  unsigned short* W2t0 = W1t0 + 4096;                  // 128*128
  unsigned short* W1t1 = W2t0 + 16384;
  unsigned short* W2t1 = W1t1 + 16384;
  unsigned short* hW1t = W2t1 + 16384;
  unsigned short* Wet0 = hW1t + 16384;                 // 32*16
  unsigned short* Wet1 = Wet0 + 512;                   // 128*16

  const size_t needed = (size_t)NN * 128 * 4 * 2 + (size_t)NN * 128 * 2 +
                        (size_t)NN * 32 * 2 + ((size_t)3 * NN + 4) * 4 +
                        (size_t)NE * 8 + 4096 + (size_t)(69632 + 2560) * 2;
  if (ws_size < needed) return;

  hipMemsetAsync(deg, 0, (size_t)NN * 4, stream);
  hipMemsetAsync(counter, 0, 16, stream);
  hipMemsetAsync(st0, 0, 4096, stream);   // st0 + st1

  const int nChunks = (NN + 63) / 64;     // 1563

  // weight/activation converts
  wconv<<<16, 256, 0, stream>>>(l0W1, W1t0, 32, 128);
  wconv<<<64, 256, 0, stream>>>(l0W2, W2t0, 128, 128);
  wconv<<<64, 256, 0, stream>>>(l1W1, W1t1, 128, 128);
  wconv<<<64, 256, 0, stream>>>(l1W2, W2t1, 128, 128);
  wconv<<<64, 256, 0, stream>>>(hW1, hW1t, 128, 128);
  wconv<<<2, 256, 0, stream>>>(l0We, Wet0, 16, 32);
  wconv<<<8, 256, 0, stream>>>(l1We, Wet1, 16, 128);
  xconv<<<1563, 256, 0, stream>>>(x, xb);

  // CSR build
  hist_kernel<<<(NE + 255) / 256, 256, 0, stream>>>(ei, deg);
  offsets_kernel<<<(NN + 255) / 256, 256, 0, stream>>>(deg, off, cur, counter);
  fill_kernel<<<(NE + 255) / 256, 256, 0, stream>>>(ei, cur, esrc);

  // layer 0
  fused_agg<32><<<NN / 4, 256, 0, stream>>>(off, deg, esrc, ea, xb, Wet0, l0be, AGG);
  mlp_mfma<32, false><<<782, 256, 0, stream>>>(x, (const unsigned short*)nullptr,
      AGG, W1t0, l0b1, W2t0, l0b2, A, st0, nChunks);
  bn_finalize<<<1, 128, 0, stream>>>(st0, l0g, l0bt);
  bn_apply_bf16<<<(NN * 32) / 256, 256, 0, stream>>>(A, st0, hb);

  // layer 1
  fused_agg<128><<<NN / 4, 256, 0, stream>>>(off, deg, esrc, ea, hb, Wet1, l1be, AGG);
  mlp_mfma<128, true><<<782, 256, 0, stream>>>((const float*)nullptr, hb,
      AGG, W1t1, l1b1, W2t1, l1b2, A, st1, nChunks);
  bn_finalize<<<1, 128, 0, stream>>>(st1, l1g, l1bt);
  bn_apply_bf16<<<(NN * 32) / 256, 256, 0, stream>>>(A, st1, hb);

  // head
  head_mfma<<<782, 256, 0, stream>>>(hb, hW1t, hb1, hW2, hb2, out, nChunks);
}

// Round 5
// 698.735 us; speedup vs baseline: 1.8688x; 1.1577x over previous
//
#include <hip/hip_runtime.h>

#define NN 100000
#define NE 1600000

typedef unsigned int uint32;
typedef __attribute__((ext_vector_type(8))) short bf16x8;
typedef __attribute__((ext_vector_type(4))) float f32x4;

__device__ __forceinline__ unsigned short f2bf(float f) {
  unsigned int u = __float_as_uint(f);
  unsigned int r = (u + 0x7fffu + ((u >> 16) & 1u)) >> 16;  // RNE
  return (unsigned short)r;
}
__device__ __forceinline__ float bf2f(unsigned short u) {
  return __uint_as_float(((unsigned int)u) << 16);
}
__device__ __forceinline__ unsigned int pack2(float a, float b) {
  return (unsigned int)f2bf(a) | ((unsigned int)f2bf(b) << 16);
}

// ---------------------------------------------------------------------------
// Weight convert: dst[n*K + k] = bf16(src[k*N + n])   (transpose to N-major)
// ---------------------------------------------------------------------------
__global__ __launch_bounds__(256) void wconv(const float* __restrict__ src,
    unsigned short* __restrict__ dst, int K, int N)
{
  const int i = blockIdx.x * 256 + threadIdx.x;
  if (i < K * N) {
    const int n = i / K, k = i - n * K;
    dst[i] = f2bf(src[k * N + n]);
  }
}

__global__ __launch_bounds__(256) void xconv(const float* __restrict__ x,
    unsigned short* __restrict__ xb)
{
  const int i = blockIdx.x * 256 + threadIdx.x;   // per 8 elems
  if (i * 8 < NN * 32) {
    const float4 a = ((const float4*)x)[i * 2];
    const float4 b = ((const float4*)x)[i * 2 + 1];
    uint4 o;
    o.x = pack2(a.x, a.y); o.y = pack2(a.z, a.w);
    o.z = pack2(b.x, b.y); o.w = pack2(b.z, b.w);
    ((uint4*)xb)[i] = o;
  }
}

// ---------------------------------------------------------------------------
// CSR build
// ---------------------------------------------------------------------------
__global__ __launch_bounds__(256) void hist_kernel(
    const int* __restrict__ ei, uint32* __restrict__ deg)
{
  const int e = blockIdx.x * 256 + threadIdx.x;
  if (e < NE) atomicAdd(&deg[ei[NE + e]], 1u);
}

__global__ __launch_bounds__(256) void offsets_kernel(
    const uint32* __restrict__ deg, uint32* __restrict__ off,
    uint32* __restrict__ cur, uint32* __restrict__ counter)
{
  __shared__ uint32 s[256];
  __shared__ uint32 base;
  const int tid = threadIdx.x;
  const int n = blockIdx.x * 256 + tid;
  const uint32 d = (n < NN) ? deg[n] : 0u;
  s[tid] = d;
  __syncthreads();
#pragma unroll
  for (int st = 1; st < 256; st <<= 1) {
    uint32 v = (tid >= st) ? s[tid - st] : 0u;
    __syncthreads();
    s[tid] += v;
    __syncthreads();
  }
  if (tid == 255) base = atomicAdd(counter, s[255]);
  __syncthreads();
  const uint32 excl = s[tid] - d;
  if (n < NN) { off[n] = base + excl; cur[n] = base + excl; }
}

__global__ __launch_bounds__(256) void fill_kernel(
    const int* __restrict__ ei, uint32* __restrict__ cur,
    uint4* __restrict__ esrc4)
{
  const int e = blockIdx.x * 256 + threadIdx.x;
  if (e < NE) {
    const int dst = ei[NE + e];
    const uint32 slot = atomicAdd(&cur[dst], 1u);
    esrc4[slot] = make_uint4((uint32)e, (uint32)ei[e], (uint32)dst, 0u);
  }
}

// ---------------------------------------------------------------------------
// Flat edge-tile aggregate. NE = 100000 tiles of 16 edges; a wave owns 8
// consecutive tiles (128 CSR slots). D=128 is split across 2 half-waves
// (NCT=4 channel-tiles each); D=32 is one wave (NCT=2).
// Per tile: pre[ch][edge] = MFMA(We^T+be, ea+1.0); msg = relu(pre+h[src]);
// segmented sum over the 16 edge lanes via head-ballot + open-node register
// accumulator; interior nodes flush as one coalesced float4 row store,
// boundary nodes as scalar f32 atomicAdds (agg pre-zeroed).
// ---------------------------------------------------------------------------
template<int D, int NCT>
__global__ __launch_bounds__(256) void flat_agg(
    const uint32* __restrict__ off, const uint4* __restrict__ esrc4,
    const float* __restrict__ ea, const unsigned short* __restrict__ hsrc,
    const unsigned short* __restrict__ Wet, const float* __restrict__ be,
    float* __restrict__ agg)
{
  const int tid = threadIdx.x;
  const int wid = tid >> 6;
  const int lane = tid & 63;
  const int c = lane & 15;
  const int g = lane >> 4;
  constexpr bool HALF = (NCT * 16 != D);
  int range, ch0;
  if (HALF) { range = blockIdx.x * 2 + (wid >> 1); ch0 = (wid & 1) * (NCT * 16); }
  else      { range = blockIdx.x * 4 + wid;        ch0 = 0; }

  // persistent W fragments (A operand), bias folded at k=16
  bf16x8 wf[NCT];
#pragma unroll
  for (int ct = 0; ct < NCT; ++ct) {
    uint4 u = make_uint4(0u, 0u, 0u, 0u);
    const int ch = ch0 + ct * 16 + c;
    if (g < 2) u = *(const uint4*)&Wet[ch * 16 + g * 8];
    else if (g == 2) u.x = (uint32)f2bf(be[ch]);
    union { uint4 u4; bf16x8 v; } cv; cv.u4 = u;
    wf[ct] = cv.v;
  }

  const uint32 sbase = (uint32)range * 128u;
  uint4 ldA = esrc4[sbase + (uint32)c];          // tile 0 (4-way dup across g)
  uint4 ldB = esrc4[sbase + 16u + (uint32)c];    // tile 1

  float openAcc[NCT][4];
#pragma unroll
  for (int ct = 0; ct < NCT; ++ct) {
    openAcc[ct][0] = 0.f; openAcc[ct][1] = 0.f;
    openAcc[ct][2] = 0.f; openAcc[ct][3] = 0.f;
  }
  int openNode = __shfl((int)ldA.z, 0);
  bool openAtomic = (off[(uint32)openNode] != sbase);

  // double-buffered A-stage (loads issued one tile ahead)
  float4 eaA0, eaA1, eaB0, eaB1;
  uint2 hxA[NCT], hxB[NCT];
  int mA = 0, mB = 0;

  auto issueA = [&](const uint4 l) {
    mA = (int)l.z;
    const int e = (int)l.x, sr = (int)l.y;
    if (g < 2) {
      eaA0 = *(const float4*)&ea[(size_t)e * 16 + g * 8];
      eaA1 = *(const float4*)&ea[(size_t)e * 16 + g * 8 + 4];
    }
#pragma unroll
    for (int ct = 0; ct < NCT; ++ct)
      hxA[ct] = *(const uint2*)&hsrc[(size_t)sr * D + ch0 + ct * 16 + g * 4];
  };
  auto issueB = [&](const uint4 l) {
    mB = (int)l.z;
    const int e = (int)l.x, sr = (int)l.y;
    if (g < 2) {
      eaB0 = *(const float4*)&ea[(size_t)e * 16 + g * 8];
      eaB1 = *(const float4*)&ea[(size_t)e * 16 + g * 8 + 4];
    }
#pragma unroll
    for (int ct = 0; ct < NCT; ++ct)
      hxB[ct] = *(const uint2*)&hsrc[(size_t)sr * D + ch0 + ct * 16 + g * 4];
  };

  auto flushOpen = [&]() {
#pragma unroll
    for (int d = 1; d <= 8; d <<= 1)
#pragma unroll
      for (int ct = 0; ct < NCT; ++ct) {
        openAcc[ct][0] += __shfl_xor(openAcc[ct][0], d);
        openAcc[ct][1] += __shfl_xor(openAcc[ct][1], d);
        openAcc[ct][2] += __shfl_xor(openAcc[ct][2], d);
        openAcc[ct][3] += __shfl_xor(openAcc[ct][3], d);
      }
    float4 sv = make_float4(0.f, 0.f, 0.f, 0.f);
#pragma unroll
    for (int ct = 0; ct < NCT; ++ct)
      if (c == ct)
        sv = make_float4(openAcc[ct][0], openAcc[ct][1],
                         openAcc[ct][2], openAcc[ct][3]);
    if (c < NCT) {
      float* p = &agg[(size_t)openNode * D + ch0 + c * 16 + g * 4];
      if (!openAtomic) {
        *(float4*)p = sv;
      } else {
        atomicAdd(p + 0, sv.x); atomicAdd(p + 1, sv.y);
        atomicAdd(p + 2, sv.z); atomicAdd(p + 3, sv.w);
      }
    }
  };

  auto compute = [&](const float4 e0, const float4 e1, const uint2* hx,
                     const int m) {
    bf16x8 afv;
    {
      uint4 u = make_uint4(0u, 0u, 0u, 0u);
      if (g < 2) {
        u.x = pack2(e0.x, e0.y); u.y = pack2(e0.z, e0.w);
        u.z = pack2(e1.x, e1.y); u.w = pack2(e1.z, e1.w);
      } else if (g == 2) {
        u.x = 0x3f80u;   // bf16(1.0) at k=16
      }
      union { uint4 u4; bf16x8 v; } cv; cv.u4 = u; afv = cv.v;
    }
    float msg[NCT][4];
#pragma unroll
    for (int ct = 0; ct < NCT; ++ct) {
      f32x4 pre = __builtin_amdgcn_mfma_f32_16x16x32_bf16(
          wf[ct], afv, (f32x4){0.f, 0.f, 0.f, 0.f}, 0, 0, 0);
      msg[ct][0] = fmaxf(pre[0] + bf2f((unsigned short)(hx[ct].x & 0xffffu)), 0.f);
      msg[ct][1] = fmaxf(pre[1] + bf2f((unsigned short)(hx[ct].x >> 16)), 0.f);
      msg[ct][2] = fmaxf(pre[2] + bf2f((unsigned short)(hx[ct].y & 0xffffu)), 0.f);
      msg[ct][3] = fmaxf(pre[3] + bf2f((unsigned short)(hx[ct].y >> 16)), 0.f);
    }
    const int mprev = __shfl_up(m, 1);
    const bool head = (c == 0) || (m != mprev);
    const uint32 hm = (uint32)__ballot(head) & 0xffffu;
    if (hm == 1u) {                       // whole tile = one node
      const int fst = __shfl(m, 0);
      if (fst == openNode) {
#pragma unroll
        for (int ct = 0; ct < NCT; ++ct) {
          openAcc[ct][0] += msg[ct][0]; openAcc[ct][1] += msg[ct][1];
          openAcc[ct][2] += msg[ct][2]; openAcc[ct][3] += msg[ct][3];
        }
      } else {
        flushOpen();
#pragma unroll
        for (int ct = 0; ct < NCT; ++ct) {
          openAcc[ct][0] = msg[ct][0]; openAcc[ct][1] = msg[ct][1];
          openAcc[ct][2] = msg[ct][2]; openAcc[ct][3] = msg[ct][3];
        }
        openNode = fst; openAtomic = false;
      }
    } else {
      uint32 rem = hm;
      while (rem) {                       // wave-uniform segment loop
        const int b = __ffs(rem) - 1;
        rem &= rem - 1u;
        const int ee = rem ? (__ffs(rem) - 2) : 15;
        const int node = __shfl(m, b);
        const bool ins = (c >= b) && (c <= ee);
        if (node == openNode) {
#pragma unroll
          for (int ct = 0; ct < NCT; ++ct) {
            openAcc[ct][0] += ins ? msg[ct][0] : 0.f;
            openAcc[ct][1] += ins ? msg[ct][1] : 0.f;
            openAcc[ct][2] += ins ? msg[ct][2] : 0.f;
            openAcc[ct][3] += ins ? msg[ct][3] : 0.f;
          }
        } else {
          flushOpen();
#pragma unroll
          for (int ct = 0; ct < NCT; ++ct) {
            openAcc[ct][0] = ins ? msg[ct][0] : 0.f;
            openAcc[ct][1] = ins ? msg[ct][1] : 0.f;
            openAcc[ct][2] = ins ? msg[ct][2] : 0.f;
            openAcc[ct][3] = ins ? msg[ct][3] : 0.f;
          }
          openNode = node; openAtomic = false;
        }
      }
    }
  };

  issueA(ldA);                       // tile 0 into buffer A
#pragma unroll
  for (int t = 0; t < 8; ++t) {
    if ((t & 1) == 0) {
      if (t < 7) issueB(ldB);        // tile t+1
      if (t < 6) ldA = esrc4[sbase + (uint32)(t + 2) * 16u + (uint32)c];
      compute(eaA0, eaA1, hxA, mA);  // tile t
    } else {
      if (t < 7) issueA(ldA);
      if (t < 6) ldB = esrc4[sbase + (uint32)(t + 2) * 16u + (uint32)c];
      compute(eaB0, eaB1, hxB, mB);
    }
  }
  openAtomic = true;                 // final (possibly continuing) node
  flushOpen();
}

// ---------------------------------------------------------------------------
// MFMA node MLP: out = relu((a+agg)@W1+b1)@W2+b2, + BN stats.
// ---------------------------------------------------------------------------
template<int DIN, bool ABF16>
__global__ __launch_bounds__(256) void mlp_mfma(
    const float* __restrict__ a32, const unsigned short* __restrict__ abf,
    const float* __restrict__ agg,
    const unsigned short* __restrict__ W1t, const float* __restrict__ b1,
    const unsigned short* __restrict__ W2t, const float* __restrict__ b2,
    float* __restrict__ outp, float* __restrict__ stats, int nChunks)
{
  constexpr int P1 = (DIN == 128) ? 136 : 40;
  constexpr int KS1 = DIN / 32;
  __shared__ __align__(16) unsigned short hin[64 * P1];
  __shared__ __align__(16) unsigned short tls[64 * 136];
  const int tid = threadIdx.x;
  const int w = tid >> 6;
  const int lane = tid & 63;
  const int c = lane & 15, g = lane >> 4;
  const int cw = w * 32;

  bf16x8 B1[2][KS1], B2[2][4];
#pragma unroll
  for (int ct = 0; ct < 2; ++ct)
#pragma unroll
    for (int kk = 0; kk < KS1; ++kk)
      B1[ct][kk] = *(const bf16x8*)&W1t[(cw + ct * 16 + c) * DIN + kk * 32 + g * 8];
#pragma unroll
  for (int ct = 0; ct < 2; ++ct)
#pragma unroll
    for (int kk = 0; kk < 4; ++kk)
      B2[ct][kk] = *(const bf16x8*)&W2t[(cw + ct * 16 + c) * 128 + kk * 32 + g * 8];
  const float b1c0 = b1[cw + c], b1c1 = b1[cw + 16 + c];
  const float b2c0 = b2[cw + c], b2c1 = b2[cw + 16 + c];
  float lsum0 = 0.f, lsum1 = 0.f, lsq0 = 0.f, lsq1 = 0.f;

  for (int chunk = blockIdx.x; chunk < nChunks; chunk += gridDim.x) {
    const int base = chunk * 64;
    if constexpr (DIN == 128) {
#pragma unroll
      for (int p = 0; p < 4; ++p) {
        const int idx = tid + 256 * p;
        const int n = idx >> 4, k8 = idx & 15;
        const int node = base + n;
        uint4 ov = make_uint4(0u, 0u, 0u, 0u);
        if (node < NN) {
          const float4 g0 = *(const float4*)&agg[node * 128 + k8 * 8];
          const float4 g1 = *(const float4*)&agg[node * 128 + k8 * 8 + 4];
          const uint4 hv = *(const uint4*)&abf[node * 128 + k8 * 8];
          ov.x = pack2(bf2f((unsigned short)(hv.x & 0xffffu)) + g0.x,
                       bf2f((unsigned short)(hv.x >> 16)) + g0.y);
          ov.y = pack2(bf2f((unsigned short)(hv.y & 0xffffu)) + g0.z,
                       bf2f((unsigned short)(hv.y >> 16)) + g0.w);
          ov.z = pack2(bf2f((unsigned short)(hv.z & 0xffffu)) + g1.x,
                       bf2f((unsigned short)(hv.z >> 16)) + g1.y);
          ov.w = pack2(bf2f((unsigned short)(hv.w & 0xffffu)) + g1.z,
                       bf2f((unsigned short)(hv.w >> 16)) + g1.w);
        }
        *(uint4*)&hin[n * P1 + k8 * 8] = ov;
      }
    } else {
      const int n = tid >> 2, k8 = tid & 3;
      const int node = base + n;
      uint4 ov = make_uint4(0u, 0u, 0u, 0u);
      if (node < NN) {
        const float4 x0 = *(const float4*)&a32[node * 32 + k8 * 8];
        const float4 x1 = *(const float4*)&a32[node * 32 + k8 * 8 + 4];
        const float4 g0 = *(const float4*)&agg[node * 32 + k8 * 8];
        const float4 g1 = *(const float4*)&agg[node * 32 + k8 * 8 + 4];
        ov.x = pack2(x0.x + g0.x, x0.y + g0.y);
        ov.y = pack2(x0.z + g0.z, x0.w + g0.w);
        ov.z = pack2(x1.x + g1.x, x1.y + g1.y);
        ov.w = pack2(x1.z + g1.z, x1.w + g1.w);
      }
      *(uint4*)&hin[n * P1 + k8 * 8] = ov;
    }
    __syncthreads();
#pragma unroll
    for (int nt = 0; nt < 4; ++nt) {
      bf16x8 af[KS1];
#pragma unroll
      for (int kk = 0; kk < KS1; ++kk)
        af[kk] = *(const bf16x8*)&hin[(nt * 16 + c) * P1 + kk * 32 + g * 8];
      f32x4 acc0 = {0.f, 0.f, 0.f, 0.f}, acc1 = {0.f, 0.f, 0.f, 0.f};
#pragma unroll
      for (int kk = 0; kk < KS1; ++kk) {
        acc0 = __builtin_amdgcn_mfma_f32_16x16x32_bf16(af[kk], B1[0][kk], acc0, 0, 0, 0);
        acc1 = __builtin_amdgcn_mfma_f32_16x16x32_bf16(af[kk], B1[1][kk], acc1, 0, 0, 0);
      }
#pragma unroll
      for (int j = 0; j < 4; ++j) {
        const int row = nt * 16 + g * 4 + j;
        tls[row * 136 + cw + c]      = f2bf(fmaxf(acc0[j] + b1c0, 0.f));
        tls[row * 136 + cw + 16 + c] = f2bf(fmaxf(acc1[j] + b1c1, 0.f));
      }
    }
    __syncthreads();
#pragma unroll
    for (int nt = 0; nt < 4; ++nt) {
      bf16x8 af[4];
#pragma unroll
      for (int kk = 0; kk < 4; ++kk)
        af[kk] = *(const bf16x8*)&tls[(nt * 16 + c) * 136 + kk * 32 + g * 8];
      f32x4 acc0 = {0.f, 0.f, 0.f, 0.f}, acc1 = {0.f, 0.f, 0.f, 0.f};
#pragma unroll
      for (int kk = 0; kk < 4; ++kk) {
        acc0 = __builtin_amdgcn_mfma_f32_16x16x32_bf16(af[kk], B2[0][kk], acc0, 0, 0, 0);
        acc1 = __builtin_amdgcn_mfma_f32_16x16x32_bf16(af[kk], B2[1][kk], acc1, 0, 0, 0);
      }
#pragma unroll
      for (int j = 0; j < 4; ++j) {
        const int node = base + nt * 16 + g * 4 + j;
        if (node < NN) {
          const float v0 = acc0[j] + b2c0;
          const float v1 = acc1[j] + b2c1;
          outp[node * 128 + cw + c] = v0;
          outp[node * 128 + cw + 16 + c] = v1;
          lsum0 += v0; lsq0 += v0 * v0;
          lsum1 += v1; lsq1 += v1 * v1;
        }
      }
    }
  }
  lsum0 += __shfl_xor(lsum0, 16); lsum0 += __shfl_xor(lsum0, 32);
  lsum1 += __shfl_xor(lsum1, 16); lsum1 += __shfl_xor(lsum1, 32);
  lsq0  += __shfl_xor(lsq0, 16);  lsq0  += __shfl_xor(lsq0, 32);
  lsq1  += __shfl_xor(lsq1, 16);  lsq1  += __shfl_xor(lsq1, 32);
  if (lane < 16) {
    atomicAdd(&stats[cw + lane], lsum0);
    atomicAdd(&stats[cw + 16 + lane], lsum1);
    atomicAdd(&stats[128 + cw + lane], lsq0);
    atomicAdd(&stats[128 + cw + 16 + lane], lsq1);
  }
}

__global__ void bn_finalize(float* __restrict__ stats,
                            const float* __restrict__ gamma,
                            const float* __restrict__ beta)
{
  const int cc = threadIdx.x;
  const float inv_n = 1.0f / (float)NN;
  const float mu = stats[cc] * inv_n;
  float var = stats[128 + cc] * inv_n - mu * mu;
  var = fmaxf(var, 0.f);
  const float rs = rsqrtf(var + 1e-5f);
  const float sc = rs * gamma[cc];
  stats[256 + cc] = sc;
  stats[384 + cc] = beta[cc] - mu * sc;
}

__global__ __launch_bounds__(256) void bn_apply_bf16(
    const float* __restrict__ h, const float* __restrict__ stats,
    unsigned short* __restrict__ hb)
{
  const int idx = blockIdx.x * 256 + threadIdx.x;
  const int c4 = (idx & 31) * 4;
  const float4 sc = *(const float4*)&stats[256 + c4];
  const float4 sh = *(const float4*)&stats[384 + c4];
  const float4 v = ((const float4*)h)[idx];
  const float r0 = fmaxf(fmaf(v.x, sc.x, sh.x), 0.f);
  const float r1 = fmaxf(fmaf(v.y, sc.y, sh.y), 0.f);
  const float r2 = fmaxf(fmaf(v.z, sc.z, sh.z), 0.f);
  const float r3 = fmaxf(fmaf(v.w, sc.w, sh.w), 0.f);
  uint2 o;
  o.x = pack2(r0, r1);
  o.y = pack2(r2, r3);
  ((uint2*)hb)[idx] = o;
}

// ---------------------------------------------------------------------------
// Head: out = sigmoid(relu(h@W1+b1)@w2 + b2)
// ---------------------------------------------------------------------------
__global__ __launch_bounds__(256) void head_mfma(
    const unsigned short* __restrict__ hb, const unsigned short* __restrict__ W1t,
    const float* __restrict__ b1, const float* __restrict__ w2,
    const float* __restrict__ b2, float* __restrict__ out, int nChunks)
{
  __shared__ float pl[4][64];
  const int tid = threadIdx.x;
  const int w = tid >> 6;
  const int lane = tid & 63;
  const int c = lane & 15, g = lane >> 4;
  const int cw = w * 32;

  bf16x8 B1[2][4];
#pragma unroll
  for (int ct = 0; ct < 2; ++ct)
#pragma unroll
    for (int kk = 0; kk < 4; ++kk)
      B1[ct][kk] = *(const bf16x8*)&W1t[(cw + ct * 16 + c) * 128 + kk * 32 + g * 8];
  const float b1c0 = b1[cw + c], b1c1 = b1[cw + 16 + c];
  const float w2c0 = w2[cw + c], w2c1 = w2[cw + 16 + c];
  const float b2v = b2[0];

  for (int chunk = blockIdx.x; chunk < nChunks; chunk += gridDim.x) {
    const int base = chunk * 64;
    float p[4][4];
#pragma unroll
    for (int nt = 0; nt < 4; ++nt) {
      bf16x8 af[4];
#pragma unroll
      for (int kk = 0; kk < 4; ++kk)
        af[kk] = *(const bf16x8*)&hb[(size_t)(base + nt * 16 + c) * 128 + kk * 32 + g * 8];
      f32x4 acc0 = {0.f, 0.f, 0.f, 0.f}, acc1 = {0.f, 0.f, 0.f, 0.f};
#pragma unroll
      for (int kk = 0; kk < 4; ++kk) {
        acc0 = __builtin_amdgcn_mfma_f32_16x16x32_bf16(af[kk], B1[0][kk], acc0, 0, 0, 0);
        acc1 = __builtin_amdgcn_mfma_f32_16x16x32_bf16(af[kk], B1[1][kk], acc1, 0, 0, 0);
      }
#pragma unroll
      for (int j = 0; j < 4; ++j)
        p[nt][j] = fmaxf(acc0[j] + b1c0, 0.f) * w2c0 +
                   fmaxf(acc1[j] + b1c1, 0.f) * w2c1;
    }
#pragma unroll
    for (int dd = 1; dd <= 8; dd <<= 1)
#pragma unroll
      for (int nt = 0; nt < 4; ++nt)
#pragma unroll
        for (int j = 0; j < 4; ++j)
          p[nt][j] += __shfl_xor(p[nt][j], dd);
    if (c == 0) {
#pragma unroll
      for (int nt = 0; nt < 4; ++nt)
#pragma unroll
        for (int j = 0; j < 4; ++j)
          pl[w][nt * 16 + g * 4 + j] = p[nt][j];
    }
    __syncthreads();
    if (tid < 64) {
      const int node = base + tid;
      if (node < NN) {
        const float s = pl[0][tid] + pl[1][tid] + pl[2][tid] + pl[3][tid] + b2v;
        out[node] = 1.f / (1.f + expf(-s));
      }
    }
    __syncthreads();
  }
}

extern "C" void kernel_launch(void* const* d_in, const int* in_sizes, int n_in,
                              void* d_out, int out_size, void* d_ws, size_t ws_size,
                              hipStream_t stream)
{
  const float* x    = (const float*)d_in[0];
  const int*   ei   = (const int*)  d_in[1];
  const float* ea   = (const float*)d_in[2];
  const float* l0We = (const float*)d_in[3];
  const float* l0be = (const float*)d_in[4];
  const float* l0W1 = (const float*)d_in[5];
  const float* l0b1 = (const float*)d_in[6];
  const float* l0W2 = (const float*)d_in[7];
  const float* l0b2 = (const float*)d_in[8];
  const float* l0g  = (const float*)d_in[9];
  const float* l0bt = (const float*)d_in[10];
  const float* l1We = (const float*)d_in[11];
  const float* l1be = (const float*)d_in[12];
  const float* l1W1 = (const float*)d_in[13];
  const float* l1b1 = (const float*)d_in[14];
  const float* l1W2 = (const float*)d_in[15];
  const float* l1b2 = (const float*)d_in[16];
  const float* l1g  = (const float*)d_in[17];
  const float* l1bt = (const float*)d_in[18];
  const float* hW1  = (const float*)d_in[19];
  const float* hb1  = (const float*)d_in[20];
  const float* hW2  = (const float*)d_in[21];
  const float* hb2  = (const float*)d_in[22];
  float* out = (float*)d_out;

  // workspace (~161.3 MB)
  float*  A    = (float*)d_ws;                         // NN*128 f32 (hpre)
  float*  AGG  = A + (size_t)NN * 128;                 // NN*128 f32
  unsigned short* hb = (unsigned short*)(AGG + (size_t)NN * 128);  // NN*128 bf16
  unsigned short* xb = hb + (size_t)NN * 128;          // NN*32 bf16
  uint32* deg     = (uint32*)(xb + (size_t)NN * 32);   // NN
  uint32* off     = deg + NN;                          // NN
  uint32* cur     = off + NN;                          // NN
  uint32* counter = cur + NN;                          // 4
  uint4*  esrc4   = (uint4*)(counter + 4);             // NE (16 B each)
  float*  st0     = (float*)(esrc4 + NE);              // 512
  float*  st1     = st0 + 512;                         // 512
  unsigned short* W1t0 = (unsigned short*)(st1 + 512); // 128*32
  unsigned short* W2t0 = W1t0 + 4096;                  // 128*128
  unsigned short* W1t1 = W2t0 + 16384;
  unsigned short* W2t1 = W1t1 + 16384;
  unsigned short* hW1t = W2t1 + 16384;
  unsigned short* Wet0 = hW1t + 16384;                 // 32*16
  unsigned short* Wet1 = Wet0 + 512;                   // 128*16

  const size_t needed = (size_t)NN * 128 * 4 * 2 + (size_t)NN * 128 * 2 +
                        (size_t)NN * 32 * 2 + ((size_t)3 * NN + 4) * 4 +
                        (size_t)NE * 16 + 4096 +
                        (size_t)(4096 + 4 * 16384 + 512 + 2048) * 2;
  if (ws_size < needed) return;

  hipMemsetAsync(deg, 0, (size_t)NN * 4, stream);
  hipMemsetAsync(counter, 0, 16, stream);
  hipMemsetAsync(st0, 0, 4096, stream);            // st0 + st1
  hipMemsetAsync(AGG, 0, (size_t)NN * 32 * 4, stream);  // layer-0 agg region

  const int nChunks = (NN + 63) / 64;     // 1563

  // weight/activation converts
  wconv<<<16, 256, 0, stream>>>(l0W1, W1t0, 32, 128);
  wconv<<<64, 256, 0, stream>>>(l0W2, W2t0, 128, 128);
  wconv<<<64, 256, 0, stream>>>(l1W1, W1t1, 128, 128);
  wconv<<<64, 256, 0, stream>>>(l1W2, W2t1, 128, 128);
  wconv<<<64, 256, 0, stream>>>(hW1, hW1t, 128, 128);
  wconv<<<2, 256, 0, stream>>>(l0We, Wet0, 16, 32);
  wconv<<<8, 256, 0, stream>>>(l1We, Wet1, 16, 128);
  xconv<<<1563, 256, 0, stream>>>(x, xb);

  // CSR build
  hist_kernel<<<(NE + 255) / 256, 256, 0, stream>>>(ei, deg);
  offsets_kernel<<<(NN + 255) / 256, 256, 0, stream>>>(deg, off, cur, counter);
  fill_kernel<<<(NE + 255) / 256, 256, 0, stream>>>(ei, cur, esrc4);

  // layer 0  (12500 ranges of 8 tiles; 1 wave per range)
  flat_agg<32, 2><<<3125, 256, 0, stream>>>(off, esrc4, ea, xb, Wet0, l0be, AGG);
  mlp_mfma<32, false><<<782, 256, 0, stream>>>(x, (const unsigned short*)nullptr,
      AGG, W1t0, l0b1, W2t0, l0b2, A, st0, nChunks);
  // re-zero full AGG for layer 1 (ordered after mlp<32> consumed it)
  hipMemsetAsync(AGG, 0, (size_t)NN * 128 * 4, stream);
  bn_finalize<<<1, 128, 0, stream>>>(st0, l0g, l0bt);
  bn_apply_bf16<<<(NN * 32) / 256, 256, 0, stream>>>(A, st0, hb);

  // layer 1  (2 half-waves per range)
  flat_agg<128, 4><<<6250, 256, 0, stream>>>(off, esrc4, ea, hb, Wet1, l1be, AGG);
  mlp_mfma<128, true><<<782, 256, 0, stream>>>((const float*)nullptr, hb,
      AGG, W1t1, l1b1, W2t1, l1b2, A, st1, nChunks);
  bn_finalize<<<1, 128, 0, stream>>>(st1, l1g, l1bt);
  bn_apply_bf16<<<(NN * 32) / 256, 256, 0, stream>>>(A, st1, hb);

  // head
  head_mfma<<<782, 256, 0, stream>>>(hb, hW1t, hb1, hW2, hb2, out, nChunks);
}

// Round 6
// 686.785 us; speedup vs baseline: 1.9013x; 1.0174x over previous
//
#include <hip/hip_runtime.h>

#define NN 100000
#define NE 1600000
#define TMAX 193760           // 24220 ranges * 8 tiles; >= sum ceil(deg/16) max 193750
#define NRANGES 24220

typedef unsigned int uint32;
typedef __attribute__((ext_vector_type(8))) short bf16x8;
typedef __attribute__((ext_vector_type(4))) float f32x4;

__device__ __forceinline__ unsigned short f2bf(float f) {
  unsigned int u = __float_as_uint(f);
  unsigned int r = (u + 0x7fffu + ((u >> 16) & 1u)) >> 16;  // RNE
  return (unsigned short)r;
}
__device__ __forceinline__ float bf2f(unsigned short u) {
  return __uint_as_float(((unsigned int)u) << 16);
}
__device__ __forceinline__ unsigned int pack2(float a, float b) {
  return (unsigned int)f2bf(a) | ((unsigned int)f2bf(b) << 16);
}

// ---------------------------------------------------------------------------
// Weight convert: dst[n*K + k] = bf16(src[k*N + n])   (transpose to N-major)
// ---------------------------------------------------------------------------
__global__ __launch_bounds__(256) void wconv(const float* __restrict__ src,
    unsigned short* __restrict__ dst, int K, int N)
{
  const int i = blockIdx.x * 256 + threadIdx.x;
  if (i < K * N) {
    const int n = i / K, k = i - n * K;
    dst[i] = f2bf(src[k * N + n]);
  }
}

__global__ __launch_bounds__(256) void xconv(const float* __restrict__ x,
    unsigned short* __restrict__ xb)
{
  const int i = blockIdx.x * 256 + threadIdx.x;   // per 8 elems
  if (i * 8 < NN * 32) {
    const float4 a = ((const float4*)x)[i * 2];
    const float4 b = ((const float4*)x)[i * 2 + 1];
    uint4 o;
    o.x = pack2(a.x, a.y); o.y = pack2(a.z, a.w);
    o.z = pack2(b.x, b.y); o.w = pack2(b.z, b.w);
    ((uint4*)xb)[i] = o;
  }
}

// ---------------------------------------------------------------------------
// Padded-tile CSR build
// ---------------------------------------------------------------------------
__global__ __launch_bounds__(256) void hist_kernel(
    const int* __restrict__ ei, uint32* __restrict__ deg)
{
  const int e = blockIdx.x * 256 + threadIdx.x;
  if (e < NE) atomicAdd(&deg[ei[NE + e]], 1u);
}

// scan over tile counts ceil(deg/16) -> toff (tile units)
__global__ __launch_bounds__(256) void offsets_kernel(
    const uint32* __restrict__ deg, uint32* __restrict__ toff,
    uint32* __restrict__ counter)
{
  __shared__ uint32 s[256];
  __shared__ uint32 base;
  const int tid = threadIdx.x;
  const int n = blockIdx.x * 256 + tid;
  const uint32 tc = (n < NN) ? ((deg[n] + 15u) >> 4) : 0u;
  s[tid] = tc;
  __syncthreads();
#pragma unroll
  for (int st = 1; st < 256; st <<= 1) {
    uint32 v = (tid >= st) ? s[tid - st] : 0u;
    __syncthreads();
    s[tid] += v;
    __syncthreads();
  }
  if (tid == 255) base = atomicAdd(counter, s[255]);
  __syncthreads();
  if (n < NN) toff[n] = base + s[tid] - tc;
}

__global__ __launch_bounds__(256) void snode_fill(
    const uint32* __restrict__ toff, const uint32* __restrict__ deg,
    int* __restrict__ snode)
{
  const int n = blockIdx.x * 256 + threadIdx.x;
  if (n < NN) {
    const uint32 t0 = toff[n];
    const uint32 tc = (deg[n] + 15u) >> 4;
    for (uint32 i = 0; i < tc; ++i) snode[t0 + i] = n;
  }
}

__global__ __launch_bounds__(256) void fill_kernel(
    const int* __restrict__ ei, const uint32* __restrict__ toff,
    uint32* __restrict__ cnt, uint2* __restrict__ esrc2)
{
  const int e = blockIdx.x * 256 + threadIdx.x;
  if (e < NE) {
    const int dst = ei[NE + e];
    const uint32 slot = toff[dst] * 16u + atomicAdd(&cnt[dst], 1u);
    esrc2[slot] = make_uint2((uint32)e, (uint32)ei[e]);
  }
}

// ---------------------------------------------------------------------------
// Padded flat-tile aggregate. TMAX tiles of 16 slots; each tile belongs to
// exactly one node (snode). A wave owns 8 consecutive tiles; D=128 is split
// across 2 half-waves (NCT=4 x 16ch), D=32 one wave (NCT=2).
// Per tile: pre = MFMA(We^T+be, ea+1.0); msg = relu(pre + h[src]);
// acc += validf * msg; uniform node-change -> butterfly flush
// (float4 store for wave-contained nodes, atomics at range boundaries).
// ---------------------------------------------------------------------------
template<int D, int NCT>
__global__ __launch_bounds__(256) void flat_agg(
    const int* __restrict__ snode, const uint32* __restrict__ toff,
    const uint32* __restrict__ deg, const uint2* __restrict__ esrc2,
    const float* __restrict__ ea, const unsigned short* __restrict__ hsrc,
    const unsigned short* __restrict__ Wet, const float* __restrict__ be,
    float* __restrict__ agg)
{
  const int tid = threadIdx.x;
  const int wid = tid >> 6;
  const int lane = tid & 63;
  const int c = lane & 15;
  const int g = lane >> 4;
  constexpr bool HALF = (NCT * 16 != D);
  int range, ch0;
  if (HALF) { range = blockIdx.x * 2 + (wid >> 1); ch0 = (wid & 1) * (NCT * 16); }
  else      { range = blockIdx.x * 4 + wid;        ch0 = 0; }

  // persistent W fragments (A operand), bias folded at k=16
  bf16x8 wf[NCT];
#pragma unroll
  for (int ct = 0; ct < NCT; ++ct) {
    uint4 u = make_uint4(0u, 0u, 0u, 0u);
    const int ch = ch0 + ct * 16 + c;
    if (g < 2) u = *(const uint4*)&Wet[ch * 16 + g * 8];
    else if (g == 2) u.x = (uint32)f2bf(be[ch]);
    union { uint4 u4; bf16x8 v; } cv; cv.u4 = u;
    wf[ct] = cv.v;
  }

  const int tile0 = range * 8;
  // pre-gather per-tile metadata (8 tiles) on lanes 0..7
  int sn8 = -1; uint32 to8 = 0u, dg8 = 0u;
  if (lane < 8) {
    sn8 = snode[tile0 + lane];
    if (sn8 >= 0) { to8 = toff[sn8]; dg8 = deg[sn8]; }
  }

  float accv[NCT][4];
#pragma unroll
  for (int ct = 0; ct < NCT; ++ct) {
    accv[ct][0] = 0.f; accv[ct][1] = 0.f; accv[ct][2] = 0.f; accv[ct][3] = 0.f;
  }
  int openNode = -1; bool openFull = false; int openEnd = 0;

  float4 eaA0, eaA1, eaB0, eaB1;
  uint2 hxA[NCT], hxB[NCT];

  auto issue = [&](const uint2 l, float4& E0, float4& E1, uint2* hx) {
    const int e = (int)l.x, sr = (int)l.y;
    if (g < 2) {
      E0 = *(const float4*)&ea[(size_t)e * 16 + g * 8];
      E1 = *(const float4*)&ea[(size_t)e * 16 + g * 8 + 4];
    }
#pragma unroll
    for (int ct = 0; ct < NCT; ++ct)
      hx[ct] = *(const uint2*)&hsrc[(size_t)sr * D + ch0 + ct * 16 + g * 4];
  };

  auto flush = [&](bool storeOK) {
#pragma unroll
    for (int d = 1; d <= 8; d <<= 1)
#pragma unroll
      for (int ct = 0; ct < NCT; ++ct) {
        accv[ct][0] += __shfl_xor(accv[ct][0], d);
        accv[ct][1] += __shfl_xor(accv[ct][1], d);
        accv[ct][2] += __shfl_xor(accv[ct][2], d);
        accv[ct][3] += __shfl_xor(accv[ct][3], d);
      }
    float4 sv = make_float4(0.f, 0.f, 0.f, 0.f);
#pragma unroll
    for (int ct = 0; ct < NCT; ++ct)
      if (c == ct)
        sv = make_float4(accv[ct][0], accv[ct][1], accv[ct][2], accv[ct][3]);
    if (c < NCT) {
      float* p = &agg[(size_t)openNode * D + ch0 + c * 16 + g * 4];
      if (storeOK) {
        *(float4*)p = sv;
      } else {
        atomicAdd(p + 0, sv.x); atomicAdd(p + 1, sv.y);
        atomicAdd(p + 2, sv.z); atomicAdd(p + 3, sv.w);
      }
    }
  };

  auto compute = [&](const float4 E0, const float4 E1, const uint2* hx,
                     const int t) {
    const int n = __shfl(sn8, t);
    if (n < 0) return;
    const uint32 to = (uint32)__shfl((int)to8, t);
    const uint32 dg = (uint32)__shfl((int)dg8, t);
    if (n != openNode) {
      if (openNode >= 0) {
        flush(openFull);   // previous node's tiles all processed
#pragma unroll
        for (int ct = 0; ct < NCT; ++ct) {
          accv[ct][0] = 0.f; accv[ct][1] = 0.f;
          accv[ct][2] = 0.f; accv[ct][3] = 0.f;
        }
      }
      openNode = n;
      openFull = ((uint32)(tile0 + t) == to);
      openEnd = (int)(to + ((dg + 15u) >> 4));
    }
    const int rem = (int)dg - (tile0 + t - (int)to) * 16;
    const float validf = (c < rem) ? 1.0f : 0.0f;
    bf16x8 afv;
    {
      uint4 u = make_uint4(0u, 0u, 0u, 0u);
      if (g < 2) {
        u.x = pack2(E0.x, E0.y); u.y = pack2(E0.z, E0.w);
        u.z = pack2(E1.x, E1.y); u.w = pack2(E1.z, E1.w);
      } else if (g == 2) {
        u.x = 0x3f80u;   // bf16(1.0) at k=16
      }
      union { uint4 u4; bf16x8 v; } cv; cv.u4 = u; afv = cv.v;
    }
#pragma unroll
    for (int ct = 0; ct < NCT; ++ct) {
      f32x4 pre = __builtin_amdgcn_mfma_f32_16x16x32_bf16(
          wf[ct], afv, (f32x4){0.f, 0.f, 0.f, 0.f}, 0, 0, 0);
      const float m0 = fmaxf(pre[0] + bf2f((unsigned short)(hx[ct].x & 0xffffu)), 0.f);
      const float m1 = fmaxf(pre[1] + bf2f((unsigned short)(hx[ct].x >> 16)), 0.f);
      const float m2 = fmaxf(pre[2] + bf2f((unsigned short)(hx[ct].y & 0xffffu)), 0.f);
      const float m3 = fmaxf(pre[3] + bf2f((unsigned short)(hx[ct].y >> 16)), 0.f);
      accv[ct][0] = fmaf(validf, m0, accv[ct][0]);
      accv[ct][1] = fmaf(validf, m1, accv[ct][1]);
      accv[ct][2] = fmaf(validf, m2, accv[ct][2]);
      accv[ct][3] = fmaf(validf, m3, accv[ct][3]);
    }
  };

  uint2 ldA = esrc2[(size_t)tile0 * 16 + c];
  issue(ldA, eaA0, eaA1, hxA);
  uint2 ldB = esrc2[((size_t)tile0 + 1) * 16 + c];
#pragma unroll
  for (int t = 0; t < 8; ++t) {
    if ((t & 1) == 0) {
      if (t < 7) issue(ldB, eaB0, eaB1, hxB);
      if (t < 6) ldA = esrc2[((size_t)tile0 + t + 2) * 16 + c];
      compute(eaA0, eaA1, hxA, t);
    } else {
      if (t < 7) issue(ldA, eaA0, eaA1, hxA);
      if (t < 6) ldB = esrc2[((size_t)tile0 + t + 2) * 16 + c];
      compute(eaB0, eaB1, hxB, t);
    }
  }
  if (openNode >= 0) flush(openFull && (openEnd <= tile0 + 8));
}

// ---------------------------------------------------------------------------
// MFMA node MLP: out = relu((a+agg)@W1+b1)@W2+b2, + BN stats.
// ---------------------------------------------------------------------------
template<int DIN, bool ABF16>
__global__ __launch_bounds__(256) void mlp_mfma(
    const float* __restrict__ a32, const unsigned short* __restrict__ abf,
    const float* __restrict__ agg,
    const unsigned short* __restrict__ W1t, const float* __restrict__ b1,
    const unsigned short* __restrict__ W2t, const float* __restrict__ b2,
    float* __restrict__ outp, float* __restrict__ stats, int nChunks)
{
  constexpr int P1 = (DIN == 128) ? 136 : 40;
  constexpr int KS1 = DIN / 32;
  __shared__ __align__(16) unsigned short hin[64 * P1];
  __shared__ __align__(16) unsigned short tls[64 * 136];
  const int tid = threadIdx.x;
  const int w = tid >> 6;
  const int lane = tid & 63;
  const int c = lane & 15, g = lane >> 4;
  const int cw = w * 32;

  bf16x8 B1[2][KS1], B2[2][4];
#pragma unroll
  for (int ct = 0; ct < 2; ++ct)
#pragma unroll
    for (int kk = 0; kk < KS1; ++kk)
      B1[ct][kk] = *(const bf16x8*)&W1t[(cw + ct * 16 + c) * DIN + kk * 32 + g * 8];
#pragma unroll
  for (int ct = 0; ct < 2; ++ct)
#pragma unroll
    for (int kk = 0; kk < 4; ++kk)
      B2[ct][kk] = *(const bf16x8*)&W2t[(cw + ct * 16 + c) * 128 + kk * 32 + g * 8];
  const float b1c0 = b1[cw + c], b1c1 = b1[cw + 16 + c];
  const float b2c0 = b2[cw + c], b2c1 = b2[cw + 16 + c];
  float lsum0 = 0.f, lsum1 = 0.f, lsq0 = 0.f, lsq1 = 0.f;

  for (int chunk = blockIdx.x; chunk < nChunks; chunk += gridDim.x) {
    const int base = chunk * 64;
    if constexpr (DIN == 128) {
#pragma unroll
      for (int p = 0; p < 4; ++p) {
        const int idx = tid + 256 * p;
        const int n = idx >> 4, k8 = idx & 15;
        const int node = base + n;
        uint4 ov = make_uint4(0u, 0u, 0u, 0u);
        if (node < NN) {
          const float4 g0 = *(const float4*)&agg[node * 128 + k8 * 8];
          const float4 g1 = *(const float4*)&agg[node * 128 + k8 * 8 + 4];
          const uint4 hv = *(const uint4*)&abf[node * 128 + k8 * 8];
          ov.x = pack2(bf2f((unsigned short)(hv.x & 0xffffu)) + g0.x,
                       bf2f((unsigned short)(hv.x >> 16)) + g0.y);
          ov.y = pack2(bf2f((unsigned short)(hv.y & 0xffffu)) + g0.z,
                       bf2f((unsigned short)(hv.y >> 16)) + g0.w);
          ov.z = pack2(bf2f((unsigned short)(hv.z & 0xffffu)) + g1.x,
                       bf2f((unsigned short)(hv.z >> 16)) + g1.y);
          ov.w = pack2(bf2f((unsigned short)(hv.w & 0xffffu)) + g1.z,
                       bf2f((unsigned short)(hv.w >> 16)) + g1.w);
        }
        *(uint4*)&hin[n * P1 + k8 * 8] = ov;
      }
    } else {
      const int n = tid >> 2, k8 = tid & 3;
      const int node = base + n;
      uint4 ov = make_uint4(0u, 0u, 0u, 0u);
      if (node < NN) {
        const float4 x0 = *(const float4*)&a32[node * 32 + k8 * 8];
        const float4 x1 = *(const float4*)&a32[node * 32 + k8 * 8 + 4];
        const float4 g0 = *(const float4*)&agg[node * 32 + k8 * 8];
        const float4 g1 = *(const float4*)&agg[node * 32 + k8 * 8 + 4];
        ov.x = pack2(x0.x + g0.x, x0.y + g0.y);
        ov.y = pack2(x0.z + g0.z, x0.w + g0.w);
        ov.z = pack2(x1.x + g1.x, x1.y + g1.y);
        ov.w = pack2(x1.z + g1.z, x1.w + g1.w);
      }
      *(uint4*)&hin[n * P1 + k8 * 8] = ov;
    }
    __syncthreads();
#pragma unroll
    for (int nt = 0; nt < 4; ++nt) {
      bf16x8 af[KS1];
#pragma unroll
      for (int kk = 0; kk < KS1; ++kk)
        af[kk] = *(const bf16x8*)&hin[(nt * 16 + c) * P1 + kk * 32 + g * 8];
      f32x4 acc0 = {0.f, 0.f, 0.f, 0.f}, acc1 = {0.f, 0.f, 0.f, 0.f};
#pragma unroll
      for (int kk = 0; kk < KS1; ++kk) {
        acc0 = __builtin_amdgcn_mfma_f32_16x16x32_bf16(af[kk], B1[0][kk], acc0, 0, 0, 0);
        acc1 = __builtin_amdgcn_mfma_f32_16x16x32_bf16(af[kk], B1[1][kk], acc1, 0, 0, 0);
      }
#pragma unroll
      for (int j = 0; j < 4; ++j) {
        const int row = nt * 16 + g * 4 + j;
        tls[row * 136 + cw + c]      = f2bf(fmaxf(acc0[j] + b1c0, 0.f));
        tls[row * 136 + cw + 16 + c] = f2bf(fmaxf(acc1[j] + b1c1, 0.f));
      }
    }
    __syncthreads();
#pragma unroll
    for (int nt = 0; nt < 4; ++nt) {
      bf16x8 af[4];
#pragma unroll
      for (int kk = 0; kk < 4; ++kk)
        af[kk] = *(const bf16x8*)&tls[(nt * 16 + c) * 136 + kk * 32 + g * 8];
      f32x4 acc0 = {0.f, 0.f, 0.f, 0.f}, acc1 = {0.f, 0.f, 0.f, 0.f};
#pragma unroll
      for (int kk = 0; kk < 4; ++kk) {
        acc0 = __builtin_amdgcn_mfma_f32_16x16x32_bf16(af[kk], B2[0][kk], acc0, 0, 0, 0);
        acc1 = __builtin_amdgcn_mfma_f32_16x16x32_bf16(af[kk], B2[1][kk], acc1, 0, 0, 0);
      }
#pragma unroll
      for (int j = 0; j < 4; ++j) {
        const int node = base + nt * 16 + g * 4 + j;
        if (node < NN) {
          const float v0 = acc0[j] + b2c0;
          const float v1 = acc1[j] + b2c1;
          outp[node * 128 + cw + c] = v0;
          outp[node * 128 + cw + 16 + c] = v1;
          lsum0 += v0; lsq0 += v0 * v0;
          lsum1 += v1; lsq1 += v1 * v1;
        }
      }
    }
  }
  lsum0 += __shfl_xor(lsum0, 16); lsum0 += __shfl_xor(lsum0, 32);
  lsum1 += __shfl_xor(lsum1, 16); lsum1 += __shfl_xor(lsum1, 32);
  lsq0  += __shfl_xor(lsq0, 16);  lsq0  += __shfl_xor(lsq0, 32);
  lsq1  += __shfl_xor(lsq1, 16);  lsq1  += __shfl_xor(lsq1, 32);
  if (lane < 16) {
    atomicAdd(&stats[cw + lane], lsum0);
    atomicAdd(&stats[cw + 16 + lane], lsum1);
    atomicAdd(&stats[128 + cw + lane], lsq0);
    atomicAdd(&stats[128 + cw + 16 + lane], lsq1);
  }
}

__global__ void bn_finalize(float* __restrict__ stats,
                            const float* __restrict__ gamma,
                            const float* __restrict__ beta)
{
  const int cc = threadIdx.x;
  const float inv_n = 1.0f / (float)NN;
  const float mu = stats[cc] * inv_n;
  float var = stats[128 + cc] * inv_n - mu * mu;
  var = fmaxf(var, 0.f);
  const float rs = rsqrtf(var + 1e-5f);
  const float sc = rs * gamma[cc];
  stats[256 + cc] = sc;
  stats[384 + cc] = beta[cc] - mu * sc;
}

__global__ __launch_bounds__(256) void bn_apply_bf16(
    const float* __restrict__ h, const float* __restrict__ stats,
    unsigned short* __restrict__ hb)
{
  const int idx = blockIdx.x * 256 + threadIdx.x;
  const int c4 = (idx & 31) * 4;
  const float4 sc = *(const float4*)&stats[256 + c4];
  const float4 sh = *(const float4*)&stats[384 + c4];
  const float4 v = ((const float4*)h)[idx];
  const float r0 = fmaxf(fmaf(v.x, sc.x, sh.x), 0.f);
  const float r1 = fmaxf(fmaf(v.y, sc.y, sh.y), 0.f);
  const float r2 = fmaxf(fmaf(v.z, sc.z, sh.z), 0.f);
  const float r3 = fmaxf(fmaf(v.w, sc.w, sh.w), 0.f);
  uint2 o;
  o.x = pack2(r0, r1);
  o.y = pack2(r2, r3);
  ((uint2*)hb)[idx] = o;
}

// ---------------------------------------------------------------------------
// Fused BN-apply + head: out = sigmoid(relu(relu(hpre*sc+sh)@W1+b1)@w2 + b2)
// ---------------------------------------------------------------------------
__global__ __launch_bounds__(256) void head_bn(
    const float* __restrict__ hpre, const float* __restrict__ stats,
    const unsigned short* __restrict__ W1t, const float* __restrict__ b1,
    const float* __restrict__ w2, const float* __restrict__ b2,
    float* __restrict__ out, int nChunks)
{
  __shared__ float pl[4][64];
  const int tid = threadIdx.x;
  const int w = tid >> 6;
  const int lane = tid & 63;
  const int c = lane & 15, g = lane >> 4;
  const int cw = w * 32;

  bf16x8 B1[2][4];
#pragma unroll
  for (int ct = 0; ct < 2; ++ct)
#pragma unroll
    for (int kk = 0; kk < 4; ++kk)
      B1[ct][kk] = *(const bf16x8*)&W1t[(cw + ct * 16 + c) * 128 + kk * 32 + g * 8];
  const float b1c0 = b1[cw + c], b1c1 = b1[cw + 16 + c];
  const float w2c0 = w2[cw + c], w2c1 = w2[cw + 16 + c];
  const float b2v = b2[0];
  // per-lane scale/shift octets: channels kk*32 + g*8 + (0..7)
  float4 scq[4][2], shq[4][2];
#pragma unroll
  for (int kk = 0; kk < 4; ++kk) {
    const int cb = kk * 32 + g * 8;
    scq[kk][0] = *(const float4*)&stats[256 + cb];
    scq[kk][1] = *(const float4*)&stats[256 + cb + 4];
    shq[kk][0] = *(const float4*)&stats[384 + cb];
    shq[kk][1] = *(const float4*)&stats[384 + cb + 4];
  }

  for (int chunk = blockIdx.x; chunk < nChunks; chunk += gridDim.x) {
    const int base = chunk * 64;
    float p[4][4];
#pragma unroll
    for (int nt = 0; nt < 4; ++nt) {
      const int node = base + nt * 16 + c;
      bf16x8 af[4];
#pragma unroll
      for (int kk = 0; kk < 4; ++kk) {
        uint4 u = make_uint4(0u, 0u, 0u, 0u);
        if (node < NN) {
          const float4 v0 = *(const float4*)&hpre[(size_t)node * 128 + kk * 32 + g * 8];
          const float4 v1 = *(const float4*)&hpre[(size_t)node * 128 + kk * 32 + g * 8 + 4];
          const float4 s0 = scq[kk][0], s1 = scq[kk][1];
          const float4 h0 = shq[kk][0], h1 = shq[kk][1];
          u.x = pack2(fmaxf(fmaf(v0.x, s0.x, h0.x), 0.f),
                      fmaxf(fmaf(v0.y, s0.y, h0.y), 0.f));
          u.y = pack2(fmaxf(fmaf(v0.z, s0.z, h0.z), 0.f),
                      fmaxf(fmaf(v0.w, s0.w, h0.w), 0.f));
          u.z = pack2(fmaxf(fmaf(v1.x, s1.x, h1.x), 0.f),
                      fmaxf(fmaf(v1.y, s1.y, h1.y), 0.f));
          u.w = pack2(fmaxf(fmaf(v1.z, s1.z, h1.z), 0.f),
                      fmaxf(fmaf(v1.w, s1.w, h1.w), 0.f));
        }
        union { uint4 u4; bf16x8 v; } cv; cv.u4 = u;
        af[kk] = cv.v;
      }
      f32x4 acc0 = {0.f, 0.f, 0.f, 0.f}, acc1 = {0.f, 0.f, 0.f, 0.f};
#pragma unroll
      for (int kk = 0; kk < 4; ++kk) {
        acc0 = __builtin_amdgcn_mfma_f32_16x16x32_bf16(af[kk], B1[0][kk], acc0, 0, 0, 0);
        acc1 = __builtin_amdgcn_mfma_f32_16x16x32_bf16(af[kk], B1[1][kk], acc1, 0, 0, 0);
      }
#pragma unroll
      for (int j = 0; j < 4; ++j)
        p[nt][j] = fmaxf(acc0[j] + b1c0, 0.f) * w2c0 +
                   fmaxf(acc1[j] + b1c1, 0.f) * w2c1;
    }
#pragma unroll
    for (int dd = 1; dd <= 8; dd <<= 1)
#pragma unroll
      for (int nt = 0; nt < 4; ++nt)
#pragma unroll
        for (int j = 0; j < 4; ++j)
          p[nt][j] += __shfl_xor(p[nt][j], dd);
    if (c == 0) {
#pragma unroll
      for (int nt = 0; nt < 4; ++nt)
#pragma unroll
        for (int j = 0; j < 4; ++j)
          pl[w][nt * 16 + g * 4 + j] = p[nt][j];
    }
    __syncthreads();
    if (tid < 64) {
      const int node = base + tid;
      if (node < NN) {
        const float s = pl[0][tid] + pl[1][tid] + pl[2][tid] + pl[3][tid] + b2v;
        out[node] = 1.f / (1.f + expf(-s));
      }
    }
    __syncthreads();
  }
}

extern "C" void kernel_launch(void* const* d_in, const int* in_sizes, int n_in,
                              void* d_out, int out_size, void* d_ws, size_t ws_size,
                              hipStream_t stream)
{
  const float* x    = (const float*)d_in[0];
  const int*   ei   = (const int*)  d_in[1];
  const float* ea   = (const float*)d_in[2];
  const float* l0We = (const float*)d_in[3];
  const float* l0be = (const float*)d_in[4];
  const float* l0W1 = (const float*)d_in[5];
  const float* l0b1 = (const float*)d_in[6];
  const float* l0W2 = (const float*)d_in[7];
  const float* l0b2 = (const float*)d_in[8];
  const float* l0g  = (const float*)d_in[9];
  const float* l0bt = (const float*)d_in[10];
  const float* l1We = (const float*)d_in[11];
  const float* l1be = (const float*)d_in[12];
  const float* l1W1 = (const float*)d_in[13];
  const float* l1b1 = (const float*)d_in[14];
  const float* l1W2 = (const float*)d_in[15];
  const float* l1b2 = (const float*)d_in[16];
  const float* l1g  = (const float*)d_in[17];
  const float* l1bt = (const float*)d_in[18];
  const float* hW1  = (const float*)d_in[19];
  const float* hb1  = (const float*)d_in[20];
  const float* hW2  = (const float*)d_in[21];
  const float* hb2  = (const float*)d_in[22];
  float* out = (float*)d_out;

  // workspace (~161 MB)
  float*  A    = (float*)d_ws;                         // NN*128 f32 (hpre)
  float*  AGG  = A + (size_t)NN * 128;                 // NN*128 f32
  unsigned short* hb = (unsigned short*)(AGG + (size_t)NN * 128);  // NN*128 bf16
  unsigned short* xb = hb + (size_t)NN * 128;          // NN*32 bf16
  uint32* deg     = (uint32*)(xb + (size_t)NN * 32);   // NN
  uint32* cnt     = deg + NN;                          // NN
  uint32* counter = cnt + NN;                          // 4
  uint32* toff    = counter + 4;                       // NN
  int*    snode   = (int*)(toff + NN);                 // TMAX
  uint2*  esrc2   = (uint2*)(snode + TMAX);            // TMAX*16 (8 B each)
  float*  st0     = (float*)(esrc2 + (size_t)TMAX * 16);  // 512
  float*  st1     = st0 + 512;                         // 512
  unsigned short* W1t0 = (unsigned short*)(st1 + 512); // 128*32
  unsigned short* W2t0 = W1t0 + 4096;                  // 128*128
  unsigned short* W1t1 = W2t0 + 16384;
  unsigned short* W2t1 = W1t1 + 16384;
  unsigned short* hW1t = W2t1 + 16384;
  unsigned short* Wet0 = hW1t + 16384;                 // 32*16
  unsigned short* Wet1 = Wet0 + 512;                   // 128*16

  const size_t needed = (size_t)NN * 128 * 4 * 2 + (size_t)NN * 128 * 2 +
                        (size_t)NN * 32 * 2 + ((size_t)3 * NN + 4) * 4 +
                        (size_t)TMAX * 4 + (size_t)TMAX * 16 * 8 + 4096 +
                        (size_t)(4096 + 4 * 16384 + 512 + 2048) * 2;
  if (ws_size < needed) return;

  hipMemsetAsync(deg, 0, ((size_t)2 * NN + 4) * 4, stream);   // deg, cnt, counter
  hipMemsetAsync(snode, 0xFF, (size_t)TMAX * 4, stream);
  hipMemsetAsync(esrc2, 0, (size_t)TMAX * 16 * 8, stream);
  hipMemsetAsync(st0, 0, 4096, stream);                        // st0 + st1
  hipMemsetAsync(AGG, 0, (size_t)NN * 32 * 4, stream);         // layer-0 agg

  const int nChunks = (NN + 63) / 64;     // 1563

  // weight/activation converts
  wconv<<<16, 256, 0, stream>>>(l0W1, W1t0, 32, 128);
  wconv<<<64, 256, 0, stream>>>(l0W2, W2t0, 128, 128);
  wconv<<<64, 256, 0, stream>>>(l1W1, W1t1, 128, 128);
  wconv<<<64, 256, 0, stream>>>(l1W2, W2t1, 128, 128);
  wconv<<<64, 256, 0, stream>>>(hW1, hW1t, 128, 128);
  wconv<<<2, 256, 0, stream>>>(l0We, Wet0, 16, 32);
  wconv<<<8, 256, 0, stream>>>(l1We, Wet1, 16, 128);
  xconv<<<1563, 256, 0, stream>>>(x, xb);

  // padded-tile CSR build
  hist_kernel<<<(NE + 255) / 256, 256, 0, stream>>>(ei, deg);
  offsets_kernel<<<(NN + 255) / 256, 256, 0, stream>>>(deg, toff, counter);
  snode_fill<<<(NN + 255) / 256, 256, 0, stream>>>(toff, deg, snode);
  fill_kernel<<<(NE + 255) / 256, 256, 0, stream>>>(ei, toff, cnt, esrc2);

  // layer 0  (NRANGES ranges of 8 tiles; 1 wave per range)
  flat_agg<32, 2><<<NRANGES / 4, 256, 0, stream>>>(
      snode, toff, deg, esrc2, ea, xb, Wet0, l0be, AGG);
  mlp_mfma<32, false><<<782, 256, 0, stream>>>(x, (const unsigned short*)nullptr,
      AGG, W1t0, l0b1, W2t0, l0b2, A, st0, nChunks);
  // re-zero full AGG for layer 1 (ordered after mlp<32> consumed it)
  hipMemsetAsync(AGG, 0, (size_t)NN * 128 * 4, stream);
  bn_finalize<<<1, 128, 0, stream>>>(st0, l0g, l0bt);
  bn_apply_bf16<<<(NN * 32) / 256, 256, 0, stream>>>(A, st0, hb);

  // layer 1  (2 half-waves per range)
  flat_agg<128, 4><<<NRANGES / 2, 256, 0, stream>>>(
      snode, toff, deg, esrc2, ea, hb, Wet1, l1be, AGG);
  mlp_mfma<128, true><<<782, 256, 0, stream>>>((const float*)nullptr, hb,
      AGG, W1t1, l1b1, W2t1, l1b2, A, st1, nChunks);
  bn_finalize<<<1, 128, 0, stream>>>(st1, l1g, l1bt);

  // fused BN-apply + head
  head_bn<<<782, 256, 0, stream>>>(A, st1, hW1t, hb1, hW2, hb2, out, nChunks);
}

// Round 7
// 645.056 us; speedup vs baseline: 2.0243x; 1.0647x over previous
//
#include <hip/hip_runtime.h>

#define NN 100000
#define NE 1600000
#define TMAX 193760           // >= sum ceil(deg/16) worst case (193750)
#define NRANGES 24220         // TMAX / 8

typedef unsigned int uint32;
typedef unsigned long long ull;
typedef __attribute__((ext_vector_type(8))) short bf16x8;
typedef __attribute__((ext_vector_type(4))) float f32x4;

__device__ __forceinline__ unsigned short f2bf(float f) {
  unsigned int u = __float_as_uint(f);
  unsigned int r = (u + 0x7fffu + ((u >> 16) & 1u)) >> 16;  // RNE
  return (unsigned short)r;
}
__device__ __forceinline__ float bf2f(unsigned short u) {
  return __uint_as_float(((unsigned int)u) << 16);
}
__device__ __forceinline__ unsigned int pack2(float a, float b) {
  return (unsigned int)f2bf(a) | ((unsigned int)f2bf(b) << 16);
}

// ---------------------------------------------------------------------------
// Weight convert: dst[n*K + k] = bf16(src[k*N + n])   (transpose to N-major)
// ---------------------------------------------------------------------------
__global__ __launch_bounds__(256) void wconv(const float* __restrict__ src,
    unsigned short* __restrict__ dst, int K, int N)
{
  const int i = blockIdx.x * 256 + threadIdx.x;
  if (i < K * N) {
    const int n = i / K, k = i - n * K;
    dst[i] = f2bf(src[k * N + n]);
  }
}

__global__ __launch_bounds__(256) void xconv(const float* __restrict__ x,
    unsigned short* __restrict__ xb)
{
  const int i = blockIdx.x * 256 + threadIdx.x;   // per 8 elems
  if (i * 8 < NN * 32) {
    const float4 a = ((const float4*)x)[i * 2];
    const float4 b = ((const float4*)x)[i * 2 + 1];
    uint4 o;
    o.x = pack2(a.x, a.y); o.y = pack2(a.z, a.w);
    o.z = pack2(b.x, b.y); o.w = pack2(b.z, b.w);
    ((uint4*)xb)[i] = o;
  }
}

// ---------------------------------------------------------------------------
// CSR build: histogram -> dual prefix scan (tiles, edges) -> snode -> fill
// ---------------------------------------------------------------------------
__global__ __launch_bounds__(256) void hist_kernel(
    const int* __restrict__ ei, uint32* __restrict__ deg)
{
  const int e = blockIdx.x * 256 + threadIdx.x;
  if (e < NE) atomicAdd(&deg[ei[NE + e]], 1u);
}

__global__ __launch_bounds__(256) void offsets2_kernel(
    const uint32* __restrict__ deg, uint32* __restrict__ toff,
    uint32* __restrict__ eoff, ull* __restrict__ counter)
{
  __shared__ ull s[256];
  __shared__ ull base;
  const int tid = threadIdx.x;
  const int n = blockIdx.x * 256 + tid;
  const uint32 d = (n < NN) ? deg[n] : 0u;
  const uint32 tc = (d + 15u) >> 4;
  const ull v = ((ull)tc << 32) | (ull)d;
  s[tid] = v;
  __syncthreads();
#pragma unroll
  for (int st = 1; st < 256; st <<= 1) {
    ull w = (tid >= st) ? s[tid - st] : 0ull;
    __syncthreads();
    s[tid] += w;
    __syncthreads();
  }
  if (tid == 255) base = atomicAdd(counter, s[255]);
  __syncthreads();
  if (n < NN) {
    const ull t = base + (s[tid] - v);
    toff[n] = (uint32)(t >> 32);
    eoff[n] = (uint32)t;
  }
}

__global__ __launch_bounds__(256) void snode_fill(
    const uint32* __restrict__ toff, const uint32* __restrict__ deg,
    int* __restrict__ snode)
{
  const int n = blockIdx.x * 256 + threadIdx.x;
  if (n < NN) {
    const uint32 t0 = toff[n];
    const uint32 tc = (deg[n] + 15u) >> 4;
    for (uint32 i = 0; i < tc; ++i) snode[t0 + i] = n;
  }
}

template<bool EAB>
__global__ __launch_bounds__(256) void fill_kernel(
    const int* __restrict__ ei, const uint32* __restrict__ eoff,
    uint32* __restrict__ cnt, uint32* __restrict__ srcc,
    unsigned short* __restrict__ eabc, uint32* __restrict__ eidc,
    const float* __restrict__ ea)
{
  const int e = blockIdx.x * 256 + threadIdx.x;
  if (e < NE) {
    const int dst = ei[NE + e];
    const uint32 pos = eoff[dst] + atomicAdd(&cnt[dst], 1u);
    srcc[pos] = (uint32)ei[e];
    if constexpr (EAB) {
      const float4* er = (const float4*)(ea + (size_t)e * 16);
      const float4 p0 = er[0], p1 = er[1], p2 = er[2], p3 = er[3];
      uint4 lo, hi;
      lo.x = pack2(p0.x, p0.y); lo.y = pack2(p0.z, p0.w);
      lo.z = pack2(p1.x, p1.y); lo.w = pack2(p1.z, p1.w);
      hi.x = pack2(p2.x, p2.y); hi.y = pack2(p2.z, p2.w);
      hi.z = pack2(p3.x, p3.y); hi.w = pack2(p3.z, p3.w);
      *(uint4*)&eabc[(size_t)pos * 16]     = lo;
      *(uint4*)&eabc[(size_t)pos * 16 + 8] = hi;
    } else {
      eidc[pos] = (uint32)e;
    }
  }
}

// ---------------------------------------------------------------------------
// Padded-tile aggregate over dense slot storage. Tiles [0,total) are real
// (node-sorted); a wave owns 8 tiles; D=128 splits channels across 2
// half-waves (NCT=4), D=32 one wave (NCT=2). Slot data is UNPADDED (pos =
// eoff[n] + k*16 + c, tail lanes clamp to pos0 and mask via validf).
// Per tile: pre = MFMA(We^T+be, ea+1.0); msg = relu(pre + h[src]);
// acc += validf*msg; node change -> butterfly flush (float4 store when node
// fully inside the wave's range, else atomics onto pre-zeroed agg).
// ---------------------------------------------------------------------------
template<int D, int NCT, bool EAB>
__global__ __launch_bounds__(256) void flat_agg(
    const int* __restrict__ snode, const uint32* __restrict__ toff,
    const uint32* __restrict__ eoff, const uint32* __restrict__ deg,
    const uint32* __restrict__ srcc, const unsigned short* __restrict__ eabc,
    const uint32* __restrict__ eidc, const float* __restrict__ ea,
    const unsigned short* __restrict__ hsrc,
    const unsigned short* __restrict__ Wet, const float* __restrict__ be,
    const ull* __restrict__ tot, float* __restrict__ agg)
{
  const int tid = threadIdx.x;
  const int wid = tid >> 6;
  const int lane = tid & 63;
  const int c = lane & 15;
  const int g = lane >> 4;
  constexpr bool HALF = (NCT * 16 != D);
  int range, ch0;
  if (HALF) { range = blockIdx.x * 2 + (wid >> 1); ch0 = (wid & 1) * (NCT * 16); }
  else      { range = blockIdx.x * 4 + wid;        ch0 = 0; }
  const int tile0 = range * 8;
  const uint32 ntile = (uint32)((*tot) >> 32);
  if ((uint32)tile0 >= ntile) return;   // dead range

  // persistent W fragments (A operand), bias folded at k=16
  bf16x8 wf[NCT];
#pragma unroll
  for (int ct = 0; ct < NCT; ++ct) {
    uint4 u = make_uint4(0u, 0u, 0u, 0u);
    const int ch = ch0 + ct * 16 + c;
    if (g < 2) u = *(const uint4*)&Wet[ch * 16 + g * 8];
    else if (g == 2) u.x = (uint32)f2bf(be[ch]);
    union { uint4 u4; bf16x8 v; } cv; cv.u4 = u;
    wf[ct] = cv.v;
  }

  // per-tile metadata on lanes 0..7: node, pos0, rem, flags(first|last<<1)
  int sn8 = -1, ps8 = 0, rm8 = 0, fl8 = 0;
  if (lane < 8) {
    sn8 = snode[tile0 + lane];
    if (sn8 >= 0) {
      const uint32 to = toff[sn8], dg = deg[sn8], eo = eoff[sn8];
      const int k = tile0 + lane - (int)to;
      ps8 = (int)eo + k * 16;
      rm8 = (int)dg - k * 16;
      fl8 = (k == 0 ? 1 : 0) | ((k == (int)((dg + 15u) >> 4) - 1) ? 2 : 0);
    }
  }

  float accv[NCT][4];
#pragma unroll
  for (int ct = 0; ct < NCT; ++ct) {
    accv[ct][0] = 0.f; accv[ct][1] = 0.f; accv[ct][2] = 0.f; accv[ct][3] = 0.f;
  }
  int openNode = -1; bool openFull = false, openClosed = false;

  uint4 afA = make_uint4(0u,0u,0u,0u), afB = make_uint4(0u,0u,0u,0u);
  float4 eA0, eA1, eB0, eB1;
  uint2 hxA[NCT], hxB[NCT];
  int nA = -1, rA = 0, fA = 0, nB = -1, rB = 0, fB = 0;

  auto issue = [&](int t, uint4& af, float4& E0, float4& E1, uint2* hx,
                   int& n_, int& r_, int& f_) {
    n_ = __shfl(sn8, t);
    const int p0 = __shfl(ps8, t);
    r_ = __shfl(rm8, t);
    f_ = __shfl(fl8, t);
    const int idx = p0 + ((c < r_) ? c : 0);
    if constexpr (EAB) {
      if (g < 2) af = *(const uint4*)&eabc[(size_t)idx * 16 + g * 8];
    } else {
      const int e = (int)eidc[idx];
      if (g < 2) {
        E0 = *(const float4*)&ea[(size_t)e * 16 + g * 8];
        E1 = *(const float4*)&ea[(size_t)e * 16 + g * 8 + 4];
      }
    }
    const int sr = (int)srcc[idx];
#pragma unroll
    for (int ct = 0; ct < NCT; ++ct)
      hx[ct] = *(const uint2*)&hsrc[(size_t)sr * D + ch0 + ct * 16 + g * 4];
  };

  auto flushOpen = [&](bool storeOK) {
#pragma unroll
    for (int d = 1; d <= 8; d <<= 1)
#pragma unroll
      for (int ct = 0; ct < NCT; ++ct) {
        accv[ct][0] += __shfl_xor(accv[ct][0], d);
        accv[ct][1] += __shfl_xor(accv[ct][1], d);
        accv[ct][2] += __shfl_xor(accv[ct][2], d);
        accv[ct][3] += __shfl_xor(accv[ct][3], d);
      }
    float4 sv = make_float4(0.f, 0.f, 0.f, 0.f);
#pragma unroll
    for (int ct = 0; ct < NCT; ++ct)
      if (c == ct)
        sv = make_float4(accv[ct][0], accv[ct][1], accv[ct][2], accv[ct][3]);
    if (c < NCT) {
      float* p = &agg[(size_t)openNode * D + ch0 + c * 16 + g * 4];
      if (storeOK) {
        *(float4*)p = sv;
      } else {
        atomicAdd(p + 0, sv.x); atomicAdd(p + 1, sv.y);
        atomicAdd(p + 2, sv.z); atomicAdd(p + 3, sv.w);
      }
    }
  };

  auto compute = [&](const uint4 afu, const float4 E0, const float4 E1,
                     const uint2* hx, int n, int r_, int f_) {
    if (n < 0) return;
    if (n != openNode) {
      if (openNode >= 0) {
        flushOpen(openFull);
#pragma unroll
        for (int ct = 0; ct < NCT; ++ct) {
          accv[ct][0] = 0.f; accv[ct][1] = 0.f;
          accv[ct][2] = 0.f; accv[ct][3] = 0.f;
        }
      }
      openNode = n; openFull = (f_ & 1) != 0; openClosed = false;
    }
    if (f_ & 2) openClosed = true;
    const float validf = (c < r_) ? 1.0f : 0.0f;
    bf16x8 afv;
    {
      uint4 u = make_uint4(0u, 0u, 0u, 0u);
      if constexpr (EAB) {
        if (g < 2) u = afu;
        else if (g == 2) u.x = 0x3f80u;   // bf16(1.0) at k=16
      } else {
        if (g < 2) {
          u.x = pack2(E0.x, E0.y); u.y = pack2(E0.z, E0.w);
          u.z = pack2(E1.x, E1.y); u.w = pack2(E1.z, E1.w);
        } else if (g == 2) u.x = 0x3f80u;
      }
      union { uint4 u4; bf16x8 v; } cv; cv.u4 = u; afv = cv.v;
    }
#pragma unroll
    for (int ct = 0; ct < NCT; ++ct) {
      f32x4 pre = __builtin_amdgcn_mfma_f32_16x16x32_bf16(
          wf[ct], afv, (f32x4){0.f, 0.f, 0.f, 0.f}, 0, 0, 0);
      const float m0 = fmaxf(pre[0] + bf2f((unsigned short)(hx[ct].x & 0xffffu)), 0.f);
      const float m1 = fmaxf(pre[1] + bf2f((unsigned short)(hx[ct].x >> 16)), 0.f);
      const float m2 = fmaxf(pre[2] + bf2f((unsigned short)(hx[ct].y & 0xffffu)), 0.f);
      const float m3 = fmaxf(pre[3] + bf2f((unsigned short)(hx[ct].y >> 16)), 0.f);
      accv[ct][0] = fmaf(validf, m0, accv[ct][0]);
      accv[ct][1] = fmaf(validf, m1, accv[ct][1]);
      accv[ct][2] = fmaf(validf, m2, accv[ct][2]);
      accv[ct][3] = fmaf(validf, m3, accv[ct][3]);
    }
  };

  issue(0, afA, eA0, eA1, hxA, nA, rA, fA);
#pragma unroll
  for (int t = 0; t < 8; ++t) {
    if ((t & 1) == 0) {
      if (t < 7) issue(t + 1, afB, eB0, eB1, hxB, nB, rB, fB);
      compute(afA, eA0, eA1, hxA, nA, rA, fA);
    } else {
      if (t < 7) issue(t + 1, afA, eA0, eA1, hxA, nA, rA, fA);
      compute(afB, eB0, eB1, hxB, nB, rB, fB);
    }
  }
  if (openNode >= 0) flushOpen(openFull && openClosed);
}

// ---------------------------------------------------------------------------
// MFMA node MLP: out = relu((a+agg)@W1+b1)@W2+b2, + BN stats.
// ---------------------------------------------------------------------------
template<int DIN, bool ABF16>
__global__ __launch_bounds__(256) void mlp_mfma(
    const float* __restrict__ a32, const unsigned short* __restrict__ abf,
    const float* __restrict__ agg,
    const unsigned short* __restrict__ W1t, const float* __restrict__ b1,
    const unsigned short* __restrict__ W2t, const float* __restrict__ b2,
    float* __restrict__ outp, float* __restrict__ stats, int nChunks)
{
  constexpr int P1 = (DIN == 128) ? 136 : 40;
  constexpr int KS1 = DIN / 32;
  __shared__ __align__(16) unsigned short hin[64 * P1];
  __shared__ __align__(16) unsigned short tls[64 * 136];
  const int tid = threadIdx.x;
  const int w = tid >> 6;
  const int lane = tid & 63;
  const int c = lane & 15, g = lane >> 4;
  const int cw = w * 32;

  bf16x8 B1[2][KS1], B2[2][4];
#pragma unroll
  for (int ct = 0; ct < 2; ++ct)
#pragma unroll
    for (int kk = 0; kk < KS1; ++kk)
      B1[ct][kk] = *(const bf16x8*)&W1t[(cw + ct * 16 + c) * DIN + kk * 32 + g * 8];
#pragma unroll
  for (int ct = 0; ct < 2; ++ct)
#pragma unroll
    for (int kk = 0; kk < 4; ++kk)
      B2[ct][kk] = *(const bf16x8*)&W2t[(cw + ct * 16 + c) * 128 + kk * 32 + g * 8];
  const float b1c0 = b1[cw + c], b1c1 = b1[cw + 16 + c];
  const float b2c0 = b2[cw + c], b2c1 = b2[cw + 16 + c];
  float lsum0 = 0.f, lsum1 = 0.f, lsq0 = 0.f, lsq1 = 0.f;

  for (int chunk = blockIdx.x; chunk < nChunks; chunk += gridDim.x) {
    const int base = chunk * 64;
    if constexpr (DIN == 128) {
#pragma unroll
      for (int p = 0; p < 4; ++p) {
        const int idx = tid + 256 * p;
        const int n = idx >> 4, k8 = idx & 15;
        const int node = base + n;
        uint4 ov = make_uint4(0u, 0u, 0u, 0u);
        if (node < NN) {
          const float4 g0 = *(const float4*)&agg[node * 128 + k8 * 8];
          const float4 g1 = *(const float4*)&agg[node * 128 + k8 * 8 + 4];
          const uint4 hv = *(const uint4*)&abf[node * 128 + k8 * 8];
          ov.x = pack2(bf2f((unsigned short)(hv.x & 0xffffu)) + g0.x,
                       bf2f((unsigned short)(hv.x >> 16)) + g0.y);
          ov.y = pack2(bf2f((unsigned short)(hv.y & 0xffffu)) + g0.z,
                       bf2f((unsigned short)(hv.y >> 16)) + g0.w);
          ov.z = pack2(bf2f((unsigned short)(hv.z & 0xffffu)) + g1.x,
                       bf2f((unsigned short)(hv.z >> 16)) + g1.y);
          ov.w = pack2(bf2f((unsigned short)(hv.w & 0xffffu)) + g1.z,
                       bf2f((unsigned short)(hv.w >> 16)) + g1.w);
        }
        *(uint4*)&hin[n * P1 + k8 * 8] = ov;
      }
    } else {
      const int n = tid >> 2, k8 = tid & 3;
      const int node = base + n;
      uint4 ov = make_uint4(0u, 0u, 0u, 0u);
      if (node < NN) {
        const float4 x0 = *(const float4*)&a32[node * 32 + k8 * 8];
        const float4 x1 = *(const float4*)&a32[node * 32 + k8 * 8 + 4];
        const float4 g0 = *(const float4*)&agg[node * 32 + k8 * 8];
        const float4 g1 = *(const float4*)&agg[node * 32 + k8 * 8 + 4];
        ov.x = pack2(x0.x + g0.x, x0.y + g0.y);
        ov.y = pack2(x0.z + g0.z, x0.w + g0.w);
        ov.z = pack2(x1.x + g1.x, x1.y + g1.y);
        ov.w = pack2(x1.z + g1.z, x1.w + g1.w);
      }
      *(uint4*)&hin[n * P1 + k8 * 8] = ov;
    }
    __syncthreads();
#pragma unroll
    for (int nt = 0; nt < 4; ++nt) {
      bf16x8 af[KS1];
#pragma unroll
      for (int kk = 0; kk < KS1; ++kk)
        af[kk] = *(const bf16x8*)&hin[(nt * 16 + c) * P1 + kk * 32 + g * 8];
      f32x4 acc0 = {0.f, 0.f, 0.f, 0.f}, acc1 = {0.f, 0.f, 0.f, 0.f};
#pragma unroll
      for (int kk = 0; kk < KS1; ++kk) {
        acc0 = __builtin_amdgcn_mfma_f32_16x16x32_bf16(af[kk], B1[0][kk], acc0, 0, 0, 0);
        acc1 = __builtin_amdgcn_mfma_f32_16x16x32_bf16(af[kk], B1[1][kk], acc1, 0, 0, 0);
      }
#pragma unroll
      for (int j = 0; j < 4; ++j) {
        const int row = nt * 16 + g * 4 + j;
        tls[row * 136 + cw + c]      = f2bf(fmaxf(acc0[j] + b1c0, 0.f));
        tls[row * 136 + cw + 16 + c] = f2bf(fmaxf(acc1[j] + b1c1, 0.f));
      }
    }
    __syncthreads();
#pragma unroll
    for (int nt = 0; nt < 4; ++nt) {
      bf16x8 af[4];
#pragma unroll
      for (int kk = 0; kk < 4; ++kk)
        af[kk] = *(const bf16x8*)&tls[(nt * 16 + c) * 136 + kk * 32 + g * 8];
      f32x4 acc0 = {0.f, 0.f, 0.f, 0.f}, acc1 = {0.f, 0.f, 0.f, 0.f};
#pragma unroll
      for (int kk = 0; kk < 4; ++kk) {
        acc0 = __builtin_amdgcn_mfma_f32_16x16x32_bf16(af[kk], B2[0][kk], acc0, 0, 0, 0);
        acc1 = __builtin_amdgcn_mfma_f32_16x16x32_bf16(af[kk], B2[1][kk], acc1, 0, 0, 0);
      }
#pragma unroll
      for (int j = 0; j < 4; ++j) {
        const int node = base + nt * 16 + g * 4 + j;
        if (node < NN) {
          const float v0 = acc0[j] + b2c0;
          const float v1 = acc1[j] + b2c1;
          outp[node * 128 + cw + c] = v0;
          outp[node * 128 + cw + 16 + c] = v1;
          lsum0 += v0; lsq0 += v0 * v0;
          lsum1 += v1; lsq1 += v1 * v1;
        }
      }
    }
  }
  lsum0 += __shfl_xor(lsum0, 16); lsum0 += __shfl_xor(lsum0, 32);
  lsum1 += __shfl_xor(lsum1, 16); lsum1 += __shfl_xor(lsum1, 32);
  lsq0  += __shfl_xor(lsq0, 16);  lsq0  += __shfl_xor(lsq0, 32);
  lsq1  += __shfl_xor(lsq1, 16);  lsq1  += __shfl_xor(lsq1, 32);
  if (lane < 16) {
    atomicAdd(&stats[cw + lane], lsum0);
    atomicAdd(&stats[cw + 16 + lane], lsum1);
    atomicAdd(&stats[128 + cw + lane], lsq0);
    atomicAdd(&stats[128 + cw + 16 + lane], lsq1);
  }
}

__global__ void bn_finalize(float* __restrict__ stats,
                            const float* __restrict__ gamma,
                            const float* __restrict__ beta)
{
  const int cc = threadIdx.x;
  const float inv_n = 1.0f / (float)NN;
  const float mu = stats[cc] * inv_n;
  float var = stats[128 + cc] * inv_n - mu * mu;
  var = fmaxf(var, 0.f);
  const float rs = rsqrtf(var + 1e-5f);
  const float sc = rs * gamma[cc];
  stats[256 + cc] = sc;
  stats[384 + cc] = beta[cc] - mu * sc;
}

__global__ __launch_bounds__(256) void bn_apply_bf16(
    const float* __restrict__ h, const float* __restrict__ stats,
    unsigned short* __restrict__ hb)
{
  const int idx = blockIdx.x * 256 + threadIdx.x;
  const int c4 = (idx & 31) * 4;
  const float4 sc = *(const float4*)&stats[256 + c4];
  const float4 sh = *(const float4*)&stats[384 + c4];
  const float4 v = ((const float4*)h)[idx];
  const float r0 = fmaxf(fmaf(v.x, sc.x, sh.x), 0.f);
  const float r1 = fmaxf(fmaf(v.y, sc.y, sh.y), 0.f);
  const float r2 = fmaxf(fmaf(v.z, sc.z, sh.z), 0.f);
  const float r3 = fmaxf(fmaf(v.w, sc.w, sh.w), 0.f);
  uint2 o;
  o.x = pack2(r0, r1);
  o.y = pack2(r2, r3);
  ((uint2*)hb)[idx] = o;
}

// ---------------------------------------------------------------------------
// Fused BN-apply + head: out = sigmoid(relu(relu(hpre*sc+sh)@W1+b1)@w2 + b2)
// ---------------------------------------------------------------------------
__global__ __launch_bounds__(256) void head_bn(
    const float* __restrict__ hpre, const float* __restrict__ stats,
    const unsigned short* __restrict__ W1t, const float* __restrict__ b1,
    const float* __restrict__ w2, const float* __restrict__ b2,
    float* __restrict__ out, int nChunks)
{
  __shared__ float pl[4][64];
  const int tid = threadIdx.x;
  const int w = tid >> 6;
  const int lane = tid & 63;
  const int c = lane & 15, g = lane >> 4;
  const int cw = w * 32;

  bf16x8 B1[2][4];
#pragma unroll
  for (int ct = 0; ct < 2; ++ct)
#pragma unroll
    for (int kk = 0; kk < 4; ++kk)
      B1[ct][kk] = *(const bf16x8*)&W1t[(cw + ct * 16 + c) * 128 + kk * 32 + g * 8];
  const float b1c0 = b1[cw + c], b1c1 = b1[cw + 16 + c];
  const float w2c0 = w2[cw + c], w2c1 = w2[cw + 16 + c];
  const float b2v = b2[0];
  float4 scq[4][2], shq[4][2];
#pragma unroll
  for (int kk = 0; kk < 4; ++kk) {
    const int cb = kk * 32 + g * 8;
    scq[kk][0] = *(const float4*)&stats[256 + cb];
    scq[kk][1] = *(const float4*)&stats[256 + cb + 4];
    shq[kk][0] = *(const float4*)&stats[384 + cb];
    shq[kk][1] = *(const float4*)&stats[384 + cb + 4];
  }

  for (int chunk = blockIdx.x; chunk < nChunks; chunk += gridDim.x) {
    const int base = chunk * 64;
    float p[4][4];
#pragma unroll
    for (int nt = 0; nt < 4; ++nt) {
      const int node = base + nt * 16 + c;
      bf16x8 af[4];
#pragma unroll
      for (int kk = 0; kk < 4; ++kk) {
        uint4 u = make_uint4(0u, 0u, 0u, 0u);
        if (node < NN) {
          const float4 v0 = *(const float4*)&hpre[(size_t)node * 128 + kk * 32 + g * 8];
          const float4 v1 = *(const float4*)&hpre[(size_t)node * 128 + kk * 32 + g * 8 + 4];
          const float4 s0 = scq[kk][0], s1 = scq[kk][1];
          const float4 h0 = shq[kk][0], h1 = shq[kk][1];
          u.x = pack2(fmaxf(fmaf(v0.x, s0.x, h0.x), 0.f),
                      fmaxf(fmaf(v0.y, s0.y, h0.y), 0.f));
          u.y = pack2(fmaxf(fmaf(v0.z, s0.z, h0.z), 0.f),
                      fmaxf(fmaf(v0.w, s0.w, h0.w), 0.f));
          u.z = pack2(fmaxf(fmaf(v1.x, s1.x, h1.x), 0.f),
                      fmaxf(fmaf(v1.y, s1.y, h1.y), 0.f));
          u.w = pack2(fmaxf(fmaf(v1.z, s1.z, h1.z), 0.f),
                      fmaxf(fmaf(v1.w, s1.w, h1.w), 0.f));
        }
        union { uint4 u4; bf16x8 v; } cv; cv.u4 = u;
        af[kk] = cv.v;
      }
      f32x4 acc0 = {0.f, 0.f, 0.f, 0.f}, acc1 = {0.f, 0.f, 0.f, 0.f};
#pragma unroll
      for (int kk = 0; kk < 4; ++kk) {
        acc0 = __builtin_amdgcn_mfma_f32_16x16x32_bf16(af[kk], B1[0][kk], acc0, 0, 0, 0);
        acc1 = __builtin_amdgcn_mfma_f32_16x16x32_bf16(af[kk], B1[1][kk], acc1, 0, 0, 0);
      }
#pragma unroll
      for (int j = 0; j < 4; ++j)
        p[nt][j] = fmaxf(acc0[j] + b1c0, 0.f) * w2c0 +
                   fmaxf(acc1[j] + b1c1, 0.f) * w2c1;
    }
#pragma unroll
    for (int dd = 1; dd <= 8; dd <<= 1)
#pragma unroll
      for (int nt = 0; nt < 4; ++nt)
#pragma unroll
        for (int j = 0; j < 4; ++j)
          p[nt][j] += __shfl_xor(p[nt][j], dd);
    if (c == 0) {
#pragma unroll
      for (int nt = 0; nt < 4; ++nt)
#pragma unroll
        for (int j = 0; j < 4; ++j)
          pl[w][nt * 16 + g * 4 + j] = p[nt][j];
    }
    __syncthreads();
    if (tid < 64) {
      const int node = base + tid;
      if (node < NN) {
        const float s = pl[0][tid] + pl[1][tid] + pl[2][tid] + pl[3][tid] + b2v;
        out[node] = 1.f / (1.f + expf(-s));
      }
    }
    __syncthreads();
  }
}

extern "C" void kernel_launch(void* const* d_in, const int* in_sizes, int n_in,
                              void* d_out, int out_size, void* d_ws, size_t ws_size,
                              hipStream_t stream)
{
  const float* x    = (const float*)d_in[0];
  const int*   ei   = (const int*)  d_in[1];
  const float* ea   = (const float*)d_in[2];
  const float* l0We = (const float*)d_in[3];
  const float* l0be = (const float*)d_in[4];
  const float* l0W1 = (const float*)d_in[5];
  const float* l0b1 = (const float*)d_in[6];
  const float* l0W2 = (const float*)d_in[7];
  const float* l0b2 = (const float*)d_in[8];
  const float* l0g  = (const float*)d_in[9];
  const float* l0bt = (const float*)d_in[10];
  const float* l1We = (const float*)d_in[11];
  const float* l1be = (const float*)d_in[12];
  const float* l1W1 = (const float*)d_in[13];
  const float* l1b1 = (const float*)d_in[14];
  const float* l1W2 = (const float*)d_in[15];
  const float* l1b2 = (const float*)d_in[16];
  const float* l1g  = (const float*)d_in[17];
  const float* l1bt = (const float*)d_in[18];
  const float* hW1  = (const float*)d_in[19];
  const float* hb1  = (const float*)d_in[20];
  const float* hW2  = (const float*)d_in[21];
  const float* hb2  = (const float*)d_in[22];
  float* out = (float*)d_out;

  // workspace layout
  float*  A    = (float*)d_ws;                         // NN*128 f32 (hpre)
  float*  AGG  = A + (size_t)NN * 128;                 // NN*128 f32
  unsigned short* hb = (unsigned short*)(AGG + (size_t)NN * 128);  // NN*128 bf16
  unsigned short* xb = hb + (size_t)NN * 128;          // NN*32 bf16
  uint32* deg     = (uint32*)(xb + (size_t)NN * 32);   // NN
  uint32* cnt     = deg + NN;                          // NN
  uint32* toff    = cnt + NN;                          // NN
  uint32* eoff    = toff + NN;                         // NN
  ull*    counter = (ull*)(eoff + NN);                 // 1 (pad 4 u32)
  int*    snode   = (int*)(counter + 2);               // TMAX
  uint32* srcc    = (uint32*)(snode + TMAX);           // NE
  float*  st0     = (float*)(srcc + NE);               // 512
  float*  st1     = st0 + 512;                         // 512
  unsigned short* W1t0 = (unsigned short*)(st1 + 512); // 32*128
  unsigned short* W2t0 = W1t0 + 4096;                  // 128*128
  unsigned short* W1t1 = W2t0 + 16384;
  unsigned short* W2t1 = W1t1 + 16384;
  unsigned short* hW1t = W2t1 + 16384;
  unsigned short* Wet0 = hW1t + 16384;                 // 32*16
  unsigned short* Wet1 = Wet0 + 512;                   // 128*16
  // tail: eabc (bf16, NE*16) if it fits, else eidc (u32, NE)
  unsigned short* eabc = Wet1 + 2048;
  uint32* eidc = (uint32*)eabc;

  const size_t base_need = (size_t)((char*)(Wet1 + 2048) - (char*)d_ws);
  const size_t need_A = base_need + (size_t)NE * 16 * 2;
  const size_t need_B = base_need + (size_t)NE * 4;
  const bool EAB = (ws_size >= need_A);
  if (!EAB && ws_size < need_B) return;

  hipMemsetAsync(deg, 0, (size_t)2 * NN * 4, stream);          // deg, cnt
  hipMemsetAsync(counter, 0, 16, stream);
  hipMemsetAsync(snode, 0xFF, (size_t)TMAX * 4, stream);
  hipMemsetAsync(st0, 0, 4096, stream);                        // st0 + st1
  hipMemsetAsync(AGG, 0, (size_t)NN * 32 * 4, stream);         // layer-0 agg

  const int nChunks = (NN + 63) / 64;     // 1563

  // weight/activation converts
  wconv<<<16, 256, 0, stream>>>(l0W1, W1t0, 32, 128);
  wconv<<<64, 256, 0, stream>>>(l0W2, W2t0, 128, 128);
  wconv<<<64, 256, 0, stream>>>(l1W1, W1t1, 128, 128);
  wconv<<<64, 256, 0, stream>>>(l1W2, W2t1, 128, 128);
  wconv<<<64, 256, 0, stream>>>(hW1, hW1t, 128, 128);
  wconv<<<2, 256, 0, stream>>>(l0We, Wet0, 16, 32);
  wconv<<<8, 256, 0, stream>>>(l1We, Wet1, 16, 128);
  xconv<<<1563, 256, 0, stream>>>(x, xb);

  // CSR build
  hist_kernel<<<(NE + 255) / 256, 256, 0, stream>>>(ei, deg);
  offsets2_kernel<<<(NN + 255) / 256, 256, 0, stream>>>(deg, toff, eoff, counter);
  snode_fill<<<(NN + 255) / 256, 256, 0, stream>>>(toff, deg, snode);
  if (EAB)
    fill_kernel<true><<<(NE + 255) / 256, 256, 0, stream>>>(
        ei, eoff, cnt, srcc, eabc, eidc, ea);
  else
    fill_kernel<false><<<(NE + 255) / 256, 256, 0, stream>>>(
        ei, eoff, cnt, srcc, eabc, eidc, ea);

  // layer 0
  if (EAB)
    flat_agg<32, 2, true><<<NRANGES / 4, 256, 0, stream>>>(
        snode, toff, eoff, deg, srcc, eabc, eidc, ea, xb, Wet0, l0be, counter, AGG);
  else
    flat_agg<32, 2, false><<<NRANGES / 4, 256, 0, stream>>>(
        snode, toff, eoff, deg, srcc, eabc, eidc, ea, xb, Wet0, l0be, counter, AGG);
  mlp_mfma<32, false><<<782, 256, 0, stream>>>(x, (const unsigned short*)nullptr,
      AGG, W1t0, l0b1, W2t0, l0b2, A, st0, nChunks);
  hipMemsetAsync(AGG, 0, (size_t)NN * 128 * 4, stream);   // re-zero for layer 1
  bn_finalize<<<1, 128, 0, stream>>>(st0, l0g, l0bt);
  bn_apply_bf16<<<(NN * 32) / 256, 256, 0, stream>>>(A, st0, hb);

  // layer 1
  if (EAB)
    flat_agg<128, 4, true><<<NRANGES / 2, 256, 0, stream>>>(
        snode, toff, eoff, deg, srcc, eabc, eidc, ea, hb, Wet1, l1be, counter, AGG);
  else
    flat_agg<128, 4, false><<<NRANGES / 2, 256, 0, stream>>>(
        snode, toff, eoff, deg, srcc, eabc, eidc, ea, hb, Wet1, l1be, counter, AGG);
  mlp_mfma<128, true><<<782, 256, 0, stream>>>((const float*)nullptr, hb,
      AGG, W1t1, l1b1, W2t1, l1b2, A, st1, nChunks);
  bn_finalize<<<1, 128, 0, stream>>>(st1, l1g, l1bt);

  // fused BN-apply + head
  head_bn<<<782, 256, 0, stream>>>(A, st1, hW1t, hb1, hW2, hb2, out, nChunks);
}

// Round 8
// 543.967 us; speedup vs baseline: 2.4005x; 1.1858x over previous
//
#include <hip/hip_runtime.h>

#define NN 100000
#define NE 1600000
#define TMAX 193760           // >= sum ceil(deg/16) worst case (193750)
#define NRANGES 24220         // TMAX / 8

typedef unsigned int uint32;
typedef unsigned long long ull;
typedef __attribute__((ext_vector_type(8))) short bf16x8;
typedef __attribute__((ext_vector_type(4))) float f32x4;

__device__ __forceinline__ unsigned short f2bf(float f) {
  unsigned int u = __float_as_uint(f);
  unsigned int r = (u + 0x7fffu + ((u >> 16) & 1u)) >> 16;  // RNE
  return (unsigned short)r;
}
__device__ __forceinline__ float bf2f(unsigned short u) {
  return __uint_as_float(((unsigned int)u) << 16);
}
__device__ __forceinline__ unsigned int pack2(float a, float b) {
  return (unsigned int)f2bf(a) | ((unsigned int)f2bf(b) << 16);
}
// sum over the 16 lanes of each DPP row via row_ror adds (pure VALU, no LDS)
__device__ __forceinline__ float row16_sum(float x) {
  x += __int_as_float(__builtin_amdgcn_mov_dpp(__float_as_int(x), 0x128, 0xf, 0xf, false));
  x += __int_as_float(__builtin_amdgcn_mov_dpp(__float_as_int(x), 0x124, 0xf, 0xf, false));
  x += __int_as_float(__builtin_amdgcn_mov_dpp(__float_as_int(x), 0x122, 0xf, 0xf, false));
  x += __int_as_float(__builtin_amdgcn_mov_dpp(__float_as_int(x), 0x121, 0xf, 0xf, false));
  return x;
}

// ---------------------------------------------------------------------------
// Combined weight/activation conversion (one launch).
// ---------------------------------------------------------------------------
__device__ __forceinline__ void wconv_body(const float* __restrict__ src,
    unsigned short* __restrict__ dst, int K, int N, int b)
{
  const int i = b * 256 + threadIdx.x;
  if (i < K * N) {
    const int n = i / K, k = i - n * K;
    dst[i] = f2bf(src[k * N + n]);
  }
}

__global__ __launch_bounds__(256) void conv_all(
    const float* __restrict__ l0W1, const float* __restrict__ l0W2,
    const float* __restrict__ l1W1, const float* __restrict__ l1W2,
    const float* __restrict__ hW1,  const float* __restrict__ l0We,
    const float* __restrict__ l1We, const float* __restrict__ x,
    unsigned short* __restrict__ W1t0, unsigned short* __restrict__ W2t0,
    unsigned short* __restrict__ W1t1, unsigned short* __restrict__ W2t1,
    unsigned short* __restrict__ hW1t, unsigned short* __restrict__ Wet0,
    unsigned short* __restrict__ Wet1, unsigned short* __restrict__ xb)
{
  int b = blockIdx.x;
  if (b < 16)  { wconv_body(l0W1, W1t0, 32, 128, b); return; }  b -= 16;
  if (b < 64)  { wconv_body(l0W2, W2t0, 128, 128, b); return; } b -= 64;
  if (b < 64)  { wconv_body(l1W1, W1t1, 128, 128, b); return; } b -= 64;
  if (b < 64)  { wconv_body(l1W2, W2t1, 128, 128, b); return; } b -= 64;
  if (b < 64)  { wconv_body(hW1,  hW1t, 128, 128, b); return; } b -= 64;
  if (b < 2)   { wconv_body(l0We, Wet0, 16, 32, b); return; }   b -= 2;
  if (b < 8)   { wconv_body(l1We, Wet1, 16, 128, b); return; }  b -= 8;
  // xconv: 8 elems per thread
  const int i = b * 256 + threadIdx.x;
  if (i * 8 < NN * 32) {
    const float4 a = ((const float4*)x)[i * 2];
    const float4 d = ((const float4*)x)[i * 2 + 1];
    uint4 o;
    o.x = pack2(a.x, a.y); o.y = pack2(a.z, a.w);
    o.z = pack2(d.x, d.y); o.w = pack2(d.z, d.w);
    ((uint4*)xb)[i] = o;
  }
}

// ---------------------------------------------------------------------------
// CSR build: histogram -> dual prefix scan (tiles, edges) -> snode -> fill
// ---------------------------------------------------------------------------
__global__ __launch_bounds__(256) void hist_kernel(
    const int* __restrict__ ei, uint32* __restrict__ deg)
{
  const int e = blockIdx.x * 256 + threadIdx.x;
  if (e < NE) atomicAdd(&deg[ei[NE + e]], 1u);
}

__global__ __launch_bounds__(256) void offsets2_kernel(
    const uint32* __restrict__ deg, uint32* __restrict__ toff,
    uint32* __restrict__ eoff, ull* __restrict__ counter)
{
  __shared__ ull s[256];
  __shared__ ull base;
  const int tid = threadIdx.x;
  const int n = blockIdx.x * 256 + tid;
  const uint32 d = (n < NN) ? deg[n] : 0u;
  const uint32 tc = (d + 15u) >> 4;
  const ull v = ((ull)tc << 32) | (ull)d;
  s[tid] = v;
  __syncthreads();
#pragma unroll
  for (int st = 1; st < 256; st <<= 1) {
    ull w = (tid >= st) ? s[tid - st] : 0ull;
    __syncthreads();
    s[tid] += w;
    __syncthreads();
  }
  if (tid == 255) base = atomicAdd(counter, s[255]);
  __syncthreads();
  if (n < NN) {
    const ull t = base + (s[tid] - v);
    toff[n] = (uint32)(t >> 32);
    eoff[n] = (uint32)t;
  }
}

__global__ __launch_bounds__(256) void snode_fill(
    const uint32* __restrict__ toff, const uint32* __restrict__ deg,
    int* __restrict__ snode)
{
  const int n = blockIdx.x * 256 + threadIdx.x;
  if (n < NN) {
    const uint32 t0 = toff[n];
    const uint32 tc = (deg[n] + 15u) >> 4;
    for (uint32 i = 0; i < tc; ++i) snode[t0 + i] = n;
  }
}

template<bool EAB>
__global__ __launch_bounds__(256) void fill_kernel(
    const int* __restrict__ ei, const uint32* __restrict__ eoff,
    uint32* __restrict__ cnt, uint32* __restrict__ srcc,
    unsigned short* __restrict__ eabc, uint32* __restrict__ eidc,
    const float* __restrict__ ea)
{
  const int e = blockIdx.x * 256 + threadIdx.x;
  if (e < NE) {
    const int dst = ei[NE + e];
    const uint32 pos = eoff[dst] + atomicAdd(&cnt[dst], 1u);
    srcc[pos] = (uint32)ei[e];
    if constexpr (EAB) {
      const float4* er = (const float4*)(ea + (size_t)e * 16);
      const float4 p0 = er[0], p1 = er[1], p2 = er[2], p3 = er[3];
      uint4 lo, hi;
      lo.x = pack2(p0.x, p0.y); lo.y = pack2(p0.z, p0.w);
      lo.z = pack2(p1.x, p1.y); lo.w = pack2(p1.z, p1.w);
      hi.x = pack2(p2.x, p2.y); hi.y = pack2(p2.z, p2.w);
      hi.z = pack2(p3.x, p3.y); hi.w = pack2(p3.z, p3.w);
      *(uint4*)&eabc[(size_t)pos * 16]     = lo;
      *(uint4*)&eabc[(size_t)pos * 16 + 8] = hi;
    } else {
      eidc[pos] = (uint32)e;
    }
  }
}

// ---------------------------------------------------------------------------
// flat_agg2: padded-tile aggregate, v2.
//  - bulk srcc preload (2 coalesced loads/lane) -> per-tile src via 2 shfls
//  - permuted channel map ch = ch0 + g*(4*NCT) + ct*4 + j  -> h loads are
//    1-2 contiguous uint4 per lane; agg store coalesced
//  - DPP row_ror flush (pure VALU)
// ---------------------------------------------------------------------------
template<int D, int NCT>
__global__ __launch_bounds__(256) void flat_agg2(
    const int* __restrict__ snode, const uint32* __restrict__ toff,
    const uint32* __restrict__ eoff, const uint32* __restrict__ deg,
    const uint32* __restrict__ srcc, const unsigned short* __restrict__ eabc,
    const unsigned short* __restrict__ hsrc,
    const unsigned short* __restrict__ Wet, const float* __restrict__ be,
    const ull* __restrict__ tot, float* __restrict__ agg)
{
  const int tid = threadIdx.x;
  const int wid = tid >> 6;
  const int lane = tid & 63;
  const int c = lane & 15;
  const int g = lane >> 4;
  constexpr bool HALF = (NCT * 16 != D);
  int range, ch0;
  if (HALF) { range = blockIdx.x * 2 + (wid >> 1); ch0 = (wid & 1) * (NCT * 16); }
  else      { range = blockIdx.x * 4 + wid;        ch0 = 0; }
  const int tile0 = range * 8;
  const uint32 ntile = (uint32)((*tot) >> 32);
  if ((uint32)tile0 >= ntile) return;   // dead range

  // W fragments; A row r <-> channel ch0 + (r>>2)*(4NCT) + ct*4 + (r&3)
  bf16x8 wf[NCT];
#pragma unroll
  for (int ct = 0; ct < NCT; ++ct) {
    const int chA = ch0 + (c >> 2) * (NCT * 4) + ct * 4 + (c & 3);
    uint4 u = make_uint4(0u, 0u, 0u, 0u);
    if (g < 2) u = *(const uint4*)&Wet[chA * 16 + g * 8];
    else if (g == 2) u.x = (uint32)f2bf(be[chA]);
    union { uint4 u4; bf16x8 v; } cv; cv.u4 = u;
    wf[ct] = cv.v;
  }

  // per-tile metadata on lanes 0..7: pk = d0(7b) | rem(5b,<=16) | flags(2b)
  int sn8 = -1, pk8 = 0, p_ = 0;
  if (lane < 8) {
    sn8 = snode[tile0 + lane];
    if (sn8 >= 0) {
      const uint32 to = toff[sn8], dg = deg[sn8], eo = eoff[sn8];
      const int k = tile0 + lane - (int)to;
      p_ = (int)eo + k * 16;
      int rv = (int)dg - k * 16; if (rv > 16) rv = 16;
      const int fl = (k == 0 ? 1 : 0) |
                     ((k == (int)((dg + 15u) >> 4) - 1) ? 2 : 0);
      pk8 = (rv << 7) | (fl << 12);
    }
  }
  const int p0base = __shfl(p_, 0);   // lane 0 (tile0) is always real
  if (lane < 8 && sn8 >= 0) pk8 |= (p_ - p0base);

  // bulk srcc preload: range spans <= 128 dense slots starting at p0base
  const uint32 sl0 = srcc[(size_t)p0base + lane];
  const uint32 sl1 = srcc[(size_t)p0base + 64 + lane];

  float acc[NCT][4];
#pragma unroll
  for (int ct = 0; ct < NCT; ++ct) {
    acc[ct][0] = 0.f; acc[ct][1] = 0.f; acc[ct][2] = 0.f; acc[ct][3] = 0.f;
  }
  int openNode = -1; bool openFull = false, openClosed = false;

  auto flushOpen = [&](bool storeOK) {
#pragma unroll
    for (int ct = 0; ct < NCT; ++ct)
#pragma unroll
      for (int j = 0; j < 4; ++j)
        acc[ct][j] = row16_sum(acc[ct][j]);
    float4 sv = make_float4(0.f, 0.f, 0.f, 0.f);
#pragma unroll
    for (int ct = 0; ct < NCT; ++ct)
      if (c == ct)
        sv = make_float4(acc[ct][0], acc[ct][1], acc[ct][2], acc[ct][3]);
    if (c < NCT) {
      float* p = &agg[(size_t)openNode * D + ch0 + g * (NCT * 4) + c * 4];
      if (storeOK) {
        *(float4*)p = sv;
      } else {
        atomicAdd(p + 0, sv.x); atomicAdd(p + 1, sv.y);
        atomicAdd(p + 2, sv.z); atomicAdd(p + 3, sv.w);
      }
    }
  };

  auto issue = [&](int t, uint4& afu, uint4& h0, uint4& h1, int& n_, int& mt_) {
    n_ = __shfl(sn8, t);
    mt_ = __shfl(pk8, t);
    const int d0 = mt_ & 127;
    const int rem = (mt_ >> 7) & 31;
    const int idx = d0 + ((c < rem) ? c : 0);
    const uint32 v0 = __shfl(sl0, idx & 63);
    const uint32 v1 = __shfl(sl1, idx & 63);
    const int src = (int)((idx & 64) ? v1 : v0);
    if (g < 2) afu = *(const uint4*)&eabc[((size_t)p0base + idx) * 16 + g * 8];
    h0 = *(const uint4*)&hsrc[(size_t)src * D + ch0 + g * (NCT * 4)];
    if constexpr (NCT == 4)
      h1 = *(const uint4*)&hsrc[(size_t)src * D + ch0 + g * (NCT * 4) + 8];
  };

  auto compute = [&](const uint4 afu, const uint4 h0, const uint4 h1,
                     const int n, const int mt) {
    if (n < 0) return;
    const int rem = (mt >> 7) & 31;
    const int fl = mt >> 12;
    if (n != openNode) {
      if (openNode >= 0) {
        flushOpen(openFull);
#pragma unroll
        for (int ct = 0; ct < NCT; ++ct) {
          acc[ct][0] = 0.f; acc[ct][1] = 0.f;
          acc[ct][2] = 0.f; acc[ct][3] = 0.f;
        }
      }
      openNode = n; openFull = (fl & 1) != 0; openClosed = false;
    }
    if (fl & 2) openClosed = true;
    const float validf = (c < rem) ? 1.0f : 0.0f;
    bf16x8 afv;
    {
      uint4 u = make_uint4(0u, 0u, 0u, 0u);
      if (g < 2) u = afu;
      else if (g == 2) u.x = 0x3f80u;   // bf16(1.0) at k=16
      union { uint4 u4; bf16x8 v; } cv; cv.u4 = u; afv = cv.v;
    }
#pragma unroll
    for (int ct = 0; ct < NCT; ++ct) {
      f32x4 pre = __builtin_amdgcn_mfma_f32_16x16x32_bf16(
          wf[ct], afv, (f32x4){0.f, 0.f, 0.f, 0.f}, 0, 0, 0);
#pragma unroll
      for (int j = 0; j < 4; ++j) {
        const int ix = ct * 4 + j;
        const uint4 hu = (ix < 8) ? h0 : h1;
        uint32 wv;
        switch ((ix & 7) >> 1) {
          case 0: wv = hu.x; break;
          case 1: wv = hu.y; break;
          case 2: wv = hu.z; break;
          default: wv = hu.w; break;
        }
        const float hvv = bf2f((unsigned short)((ix & 1) ? (wv >> 16) : (wv & 0xffffu)));
        const float m = fmaxf(pre[j] + hvv, 0.f);
        acc[ct][j] = fmaf(validf, m, acc[ct][j]);
      }
    }
  };

  uint4 afA = make_uint4(0,0,0,0), h0A = make_uint4(0,0,0,0), h1A = make_uint4(0,0,0,0);
  uint4 afB = make_uint4(0,0,0,0), h0B = make_uint4(0,0,0,0), h1B = make_uint4(0,0,0,0);
  int nA = -1, mA = 0, nB = -1, mB = 0;

  issue(0, afA, h0A, h1A, nA, mA);
#pragma unroll
  for (int t = 0; t < 8; ++t) {
    if ((t & 1) == 0) {
      if (t < 7) issue(t + 1, afB, h0B, h1B, nB, mB);
      compute(afA, h0A, h1A, nA, mA);
    } else {
      if (t < 7) issue(t + 1, afA, h0A, h1A, nA, mA);
      compute(afB, h0B, h1B, nB, mB);
    }
  }
  if (openNode >= 0) flushOpen(openFull && openClosed);
}

// ---------------------------------------------------------------------------
// Fallback aggregate (EAB=false; R7 structure, ea read in-loop)
// ---------------------------------------------------------------------------
template<int D, int NCT>
__global__ __launch_bounds__(256) void flat_agg_fb(
    const int* __restrict__ snode, const uint32* __restrict__ toff,
    const uint32* __restrict__ eoff, const uint32* __restrict__ deg,
    const uint32* __restrict__ srcc, const uint32* __restrict__ eidc,
    const float* __restrict__ ea, const unsigned short* __restrict__ hsrc,
    const unsigned short* __restrict__ Wet, const float* __restrict__ be,
    const ull* __restrict__ tot, float* __restrict__ agg)
{
  const int tid = threadIdx.x;
  const int wid = tid >> 6;
  const int lane = tid & 63;
  const int c = lane & 15;
  const int g = lane >> 4;
  constexpr bool HALF = (NCT * 16 != D);
  int range, ch0;
  if (HALF) { range = blockIdx.x * 2 + (wid >> 1); ch0 = (wid & 1) * (NCT * 16); }
  else      { range = blockIdx.x * 4 + wid;        ch0 = 0; }
  const int tile0 = range * 8;
  const uint32 ntile = (uint32)((*tot) >> 32);
  if ((uint32)tile0 >= ntile) return;

  bf16x8 wf[NCT];
#pragma unroll
  for (int ct = 0; ct < NCT; ++ct) {
    uint4 u = make_uint4(0u, 0u, 0u, 0u);
    const int ch = ch0 + ct * 16 + c;
    if (g < 2) u = *(const uint4*)&Wet[ch * 16 + g * 8];
    else if (g == 2) u.x = (uint32)f2bf(be[ch]);
    union { uint4 u4; bf16x8 v; } cv; cv.u4 = u;
    wf[ct] = cv.v;
  }

  int sn8 = -1, ps8 = 0, rm8 = 0, fl8 = 0;
  if (lane < 8) {
    sn8 = snode[tile0 + lane];
    if (sn8 >= 0) {
      const uint32 to = toff[sn8], dg = deg[sn8], eo = eoff[sn8];
      const int k = tile0 + lane - (int)to;
      ps8 = (int)eo + k * 16;
      rm8 = (int)dg - k * 16;
      fl8 = (k == 0 ? 1 : 0) | ((k == (int)((dg + 15u) >> 4) - 1) ? 2 : 0);
    }
  }

  float accv[NCT][4];
#pragma unroll
  for (int ct = 0; ct < NCT; ++ct) {
    accv[ct][0] = 0.f; accv[ct][1] = 0.f; accv[ct][2] = 0.f; accv[ct][3] = 0.f;
  }
  int openNode = -1; bool openFull = false, openClosed = false;

  float4 eA0, eA1, eB0, eB1;
  uint2 hxA[NCT], hxB[NCT];
  int nA = -1, rA = 0, fA = 0, nB = -1, rB = 0, fB = 0;

  auto issue = [&](int t, float4& E0, float4& E1, uint2* hx,
                   int& n_, int& r_, int& f_) {
    n_ = __shfl(sn8, t);
    const int p0 = __shfl(ps8, t);
    r_ = __shfl(rm8, t);
    f_ = __shfl(fl8, t);
    const int idx = p0 + ((c < r_) ? c : 0);
    const int e = (int)eidc[idx];
    if (g < 2) {
      E0 = *(const float4*)&ea[(size_t)e * 16 + g * 8];
      E1 = *(const float4*)&ea[(size_t)e * 16 + g * 8 + 4];
    }
    const int sr = (int)srcc[idx];
#pragma unroll
    for (int ct = 0; ct < NCT; ++ct)
      hx[ct] = *(const uint2*)&hsrc[(size_t)sr * D + ch0 + ct * 16 + g * 4];
  };

  auto flushOpen = [&](bool storeOK) {
#pragma unroll
    for (int ct = 0; ct < NCT; ++ct)
#pragma unroll
      for (int j = 0; j < 4; ++j)
        accv[ct][j] = row16_sum(accv[ct][j]);
    float4 sv = make_float4(0.f, 0.f, 0.f, 0.f);
#pragma unroll
    for (int ct = 0; ct < NCT; ++ct)
      if (c == ct)
        sv = make_float4(accv[ct][0], accv[ct][1], accv[ct][2], accv[ct][3]);
    if (c < NCT) {
      float* p = &agg[(size_t)openNode * D + ch0 + c * 16 + g * 4];
      if (storeOK) {
        *(float4*)p = sv;
      } else {
        atomicAdd(p + 0, sv.x); atomicAdd(p + 1, sv.y);
        atomicAdd(p + 2, sv.z); atomicAdd(p + 3, sv.w);
      }
    }
  };

  auto compute = [&](const float4 E0, const float4 E1, const uint2* hx,
                     int n, int r_, int f_) {
    if (n < 0) return;
    if (n != openNode) {
      if (openNode >= 0) {
        flushOpen(openFull);
#pragma unroll
        for (int ct = 0; ct < NCT; ++ct) {
          accv[ct][0] = 0.f; accv[ct][1] = 0.f;
          accv[ct][2] = 0.f; accv[ct][3] = 0.f;
        }
      }
      openNode = n; openFull = (f_ & 1) != 0; openClosed = false;
    }
    if (f_ & 2) openClosed = true;
    const float validf = (c < r_) ? 1.0f : 0.0f;
    bf16x8 afv;
    {
      uint4 u = make_uint4(0u, 0u, 0u, 0u);
      if (g < 2) {
        u.x = pack2(E0.x, E0.y); u.y = pack2(E0.z, E0.w);
        u.z = pack2(E1.x, E1.y); u.w = pack2(E1.z, E1.w);
      } else if (g == 2) u.x = 0x3f80u;
      union { uint4 u4; bf16x8 v; } cv; cv.u4 = u; afv = cv.v;
    }
#pragma unroll
    for (int ct = 0; ct < NCT; ++ct) {
      f32x4 pre = __builtin_amdgcn_mfma_f32_16x16x32_bf16(
          wf[ct], afv, (f32x4){0.f, 0.f, 0.f, 0.f}, 0, 0, 0);
      const float m0 = fmaxf(pre[0] + bf2f((unsigned short)(hx[ct].x & 0xffffu)), 0.f);
      const float m1 = fmaxf(pre[1] + bf2f((unsigned short)(hx[ct].x >> 16)), 0.f);
      const float m2 = fmaxf(pre[2] + bf2f((unsigned short)(hx[ct].y & 0xffffu)), 0.f);
      const float m3 = fmaxf(pre[3] + bf2f((unsigned short)(hx[ct].y >> 16)), 0.f);
      accv[ct][0] = fmaf(validf, m0, accv[ct][0]);
      accv[ct][1] = fmaf(validf, m1, accv[ct][1]);
      accv[ct][2] = fmaf(validf, m2, accv[ct][2]);
      accv[ct][3] = fmaf(validf, m3, accv[ct][3]);
    }
  };

  issue(0, eA0, eA1, hxA, nA, rA, fA);
#pragma unroll
  for (int t = 0; t < 8; ++t) {
    if ((t & 1) == 0) {
      if (t < 7) issue(t + 1, eB0, eB1, hxB, nB, rB, fB);
      compute(eA0, eA1, hxA, nA, rA, fA);
    } else {
      if (t < 7) issue(t + 1, eA0, eA1, hxA, nA, rA, fA);
      compute(eB0, eB1, hxB, nB, rB, fB);
    }
  }
  if (openNode >= 0) flushOpen(openFull && openClosed);
}

// ---------------------------------------------------------------------------
// MFMA node MLP: out = relu((a+agg)@W1+b1)@W2+b2, + BN stats.
// ---------------------------------------------------------------------------
template<int DIN, bool ABF16>
__global__ __launch_bounds__(256) void mlp_mfma(
    const float* __restrict__ a32, const unsigned short* __restrict__ abf,
    const float* __restrict__ agg,
    const unsigned short* __restrict__ W1t, const float* __restrict__ b1,
    const unsigned short* __restrict__ W2t, const float* __restrict__ b2,
    float* __restrict__ outp, float* __restrict__ stats, int nChunks)
{
  constexpr int P1 = (DIN == 128) ? 136 : 40;
  constexpr int KS1 = DIN / 32;
  __shared__ __align__(16) unsigned short hin[64 * P1];
  __shared__ __align__(16) unsigned short tls[64 * 136];
  const int tid = threadIdx.x;
  const int w = tid >> 6;
  const int lane = tid & 63;
  const int c = lane & 15, g = lane >> 4;
  const int cw = w * 32;

  bf16x8 B1[2][KS1], B2[2][4];
#pragma unroll
  for (int ct = 0; ct < 2; ++ct)
#pragma unroll
    for (int kk = 0; kk < KS1; ++kk)
      B1[ct][kk] = *(const bf16x8*)&W1t[(cw + ct * 16 + c) * DIN + kk * 32 + g * 8];
#pragma unroll
  for (int ct = 0; ct < 2; ++ct)
#pragma unroll
    for (int kk = 0; kk < 4; ++kk)
      B2[ct][kk] = *(const bf16x8*)&W2t[(cw + ct * 16 + c) * 128 + kk * 32 + g * 8];
  const float b1c0 = b1[cw + c], b1c1 = b1[cw + 16 + c];
  const float b2c0 = b2[cw + c], b2c1 = b2[cw + 16 + c];
  float lsum0 = 0.f, lsum1 = 0.f, lsq0 = 0.f, lsq1 = 0.f;

  for (int chunk = blockIdx.x; chunk < nChunks; chunk += gridDim.x) {
    const int base = chunk * 64;
    if constexpr (DIN == 128) {
#pragma unroll
      for (int p = 0; p < 4; ++p) {
        const int idx = tid + 256 * p;
        const int n = idx >> 4, k8 = idx & 15;
        const int node = base + n;
        uint4 ov = make_uint4(0u, 0u, 0u, 0u);
        if (node < NN) {
          const float4 g0 = *(const float4*)&agg[node * 128 + k8 * 8];
          const float4 g1 = *(const float4*)&agg[node * 128 + k8 * 8 + 4];
          const uint4 hv = *(const uint4*)&abf[node * 128 + k8 * 8];
          ov.x = pack2(bf2f((unsigned short)(hv.x & 0xffffu)) + g0.x,
                       bf2f((unsigned short)(hv.x >> 16)) + g0.y);
          ov.y = pack2(bf2f((unsigned short)(hv.y & 0xffffu)) + g0.z,
                       bf2f((unsigned short)(hv.y >> 16)) + g0.w);
          ov.z = pack2(bf2f((unsigned short)(hv.z & 0xffffu)) + g1.x,
                       bf2f((unsigned short)(hv.z >> 16)) + g1.y);
          ov.w = pack2(bf2f((unsigned short)(hv.w & 0xffffu)) + g1.z,
                       bf2f((unsigned short)(hv.w >> 16)) + g1.w);
        }
        *(uint4*)&hin[n * P1 + k8 * 8] = ov;
      }
    } else {
      const int n = tid >> 2, k8 = tid & 3;
      const int node = base + n;
      uint4 ov = make_uint4(0u, 0u, 0u, 0u);
      if (node < NN) {
        const float4 x0 = *(const float4*)&a32[node * 32 + k8 * 8];
        const float4 x1 = *(const float4*)&a32[node * 32 + k8 * 8 + 4];
        const float4 g0 = *(const float4*)&agg[node * 32 + k8 * 8];
        const float4 g1 = *(const float4*)&agg[node * 32 + k8 * 8 + 4];
        ov.x = pack2(x0.x + g0.x, x0.y + g0.y);
        ov.y = pack2(x0.z + g0.z, x0.w + g0.w);
        ov.z = pack2(x1.x + g1.x, x1.y + g1.y);
        ov.w = pack2(x1.z + g1.z, x1.w + g1.w);
      }
      *(uint4*)&hin[n * P1 + k8 * 8] = ov;
    }
    __syncthreads();
#pragma unroll
    for (int nt = 0; nt < 4; ++nt) {
      bf16x8 af[KS1];
#pragma unroll
      for (int kk = 0; kk < KS1; ++kk)
        af[kk] = *(const bf16x8*)&hin[(nt * 16 + c) * P1 + kk * 32 + g * 8];
      f32x4 acc0 = {0.f, 0.f, 0.f, 0.f}, acc1 = {0.f, 0.f, 0.f, 0.f};
#pragma unroll
      for (int kk = 0; kk < KS1; ++kk) {
        acc0 = __builtin_amdgcn_mfma_f32_16x16x32_bf16(af[kk], B1[0][kk], acc0, 0, 0, 0);
        acc1 = __builtin_amdgcn_mfma_f32_16x16x32_bf16(af[kk], B1[1][kk], acc1, 0, 0, 0);
      }
#pragma unroll
      for (int j = 0; j < 4; ++j) {
        const int row = nt * 16 + g * 4 + j;
        tls[row * 136 + cw + c]      = f2bf(fmaxf(acc0[j] + b1c0, 0.f));
        tls[row * 136 + cw + 16 + c] = f2bf(fmaxf(acc1[j] + b1c1, 0.f));
      }
    }
    __syncthreads();
#pragma unroll
    for (int nt = 0; nt < 4; ++nt) {
      bf16x8 af[4];
#pragma unroll
      for (int kk = 0; kk < 4; ++kk)
        af[kk] = *(const bf16x8*)&tls[(nt * 16 + c) * 136 + kk * 32 + g * 8];
      f32x4 acc0 = {0.f, 0.f, 0.f, 0.f}, acc1 = {0.f, 0.f, 0.f, 0.f};
#pragma unroll
      for (int kk = 0; kk < 4; ++kk) {
        acc0 = __builtin_amdgcn_mfma_f32_16x16x32_bf16(af[kk], B2[0][kk], acc0, 0, 0, 0);
        acc1 = __builtin_amdgcn_mfma_f32_16x16x32_bf16(af[kk], B2[1][kk], acc1, 0, 0, 0);
      }
#pragma unroll
      for (int j = 0; j < 4; ++j) {
        const int node = base + nt * 16 + g * 4 + j;
        if (node < NN) {
          const float v0 = acc0[j] + b2c0;
          const float v1 = acc1[j] + b2c1;
          outp[node * 128 + cw + c] = v0;
          outp[node * 128 + cw + 16 + c] = v1;
          lsum0 += v0; lsq0 += v0 * v0;
          lsum1 += v1; lsq1 += v1 * v1;
        }
      }
    }
  }
  lsum0 += __shfl_xor(lsum0, 16); lsum0 += __shfl_xor(lsum0, 32);
  lsum1 += __shfl_xor(lsum1, 16); lsum1 += __shfl_xor(lsum1, 32);
  lsq0  += __shfl_xor(lsq0, 16);  lsq0  += __shfl_xor(lsq0, 32);
  lsq1  += __shfl_xor(lsq1, 16);  lsq1  += __shfl_xor(lsq1, 32);
  if (lane < 16) {
    atomicAdd(&stats[cw + lane], lsum0);
    atomicAdd(&stats[cw + 16 + lane], lsum1);
    atomicAdd(&stats[128 + cw + lane], lsq0);
    atomicAdd(&stats[128 + cw + 16 + lane], lsq1);
  }
}

__global__ void bn_finalize(float* __restrict__ stats,
                            const float* __restrict__ gamma,
                            const float* __restrict__ beta)
{
  const int cc = threadIdx.x;
  const float inv_n = 1.0f / (float)NN;
  const float mu = stats[cc] * inv_n;
  float var = stats[128 + cc] * inv_n - mu * mu;
  var = fmaxf(var, 0.f);
  const float rs = rsqrtf(var + 1e-5f);
  const float sc = rs * gamma[cc];
  stats[256 + cc] = sc;
  stats[384 + cc] = beta[cc] - mu * sc;
}

__global__ __launch_bounds__(256) void bn_apply_bf16(
    const float* __restrict__ h, const float* __restrict__ stats,
    unsigned short* __restrict__ hb)
{
  const int idx = blockIdx.x * 256 + threadIdx.x;
  const int c4 = (idx & 31) * 4;
  const float4 sc = *(const float4*)&stats[256 + c4];
  const float4 sh = *(const float4*)&stats[384 + c4];
  const float4 v = ((const float4*)h)[idx];
  const float r0 = fmaxf(fmaf(v.x, sc.x, sh.x), 0.f);
  const float r1 = fmaxf(fmaf(v.y, sc.y, sh.y), 0.f);
  const float r2 = fmaxf(fmaf(v.z, sc.z, sh.z), 0.f);
  const float r3 = fmaxf(fmaf(v.w, sc.w, sh.w), 0.f);
  uint2 o;
  o.x = pack2(r0, r1);
  o.y = pack2(r2, r3);
  ((uint2*)hb)[idx] = o;
}

// ---------------------------------------------------------------------------
// Fused BN-apply + head: out = sigmoid(relu(relu(hpre*sc+sh)@W1+b1)@w2 + b2)
// ---------------------------------------------------------------------------
__global__ __launch_bounds__(256) void head_bn(
    const float* __restrict__ hpre, const float* __restrict__ stats,
    const unsigned short* __restrict__ W1t, const float* __restrict__ b1,
    const float* __restrict__ w2, const float* __restrict__ b2,
    float* __restrict__ out, int nChunks)
{
  __shared__ float pl[4][64];
  const int tid = threadIdx.x;
  const int w = tid >> 6;
  const int lane = tid & 63;
  const int c = lane & 15, g = lane >> 4;
  const int cw = w * 32;

  bf16x8 B1[2][4];
#pragma unroll
  for (int ct = 0; ct < 2; ++ct)
#pragma unroll
    for (int kk = 0; kk < 4; ++kk)
      B1[ct][kk] = *(const bf16x8*)&W1t[(cw + ct * 16 + c) * 128 + kk * 32 + g * 8];
  const float b1c0 = b1[cw + c], b1c1 = b1[cw + 16 + c];
  const float w2c0 = w2[cw + c], w2c1 = w2[cw + 16 + c];
  const float b2v = b2[0];
  float4 scq[4][2], shq[4][2];
#pragma unroll
  for (int kk = 0; kk < 4; ++kk) {
    const int cb = kk * 32 + g * 8;
    scq[kk][0] = *(const float4*)&stats[256 + cb];
    scq[kk][1] = *(const float4*)&stats[256 + cb + 4];
    shq[kk][0] = *(const float4*)&stats[384 + cb];
    shq[kk][1] = *(const float4*)&stats[384 + cb + 4];
  }

  for (int chunk = blockIdx.x; chunk < nChunks; chunk += gridDim.x) {
    const int base = chunk * 64;
    float p[4][4];
#pragma unroll
    for (int nt = 0; nt < 4; ++nt) {
      const int node = base + nt * 16 + c;
      bf16x8 af[4];
#pragma unroll
      for (int kk = 0; kk < 4; ++kk) {
        uint4 u = make_uint4(0u, 0u, 0u, 0u);
        if (node < NN) {
          const float4 v0 = *(const float4*)&hpre[(size_t)node * 128 + kk * 32 + g * 8];
          const float4 v1 = *(const float4*)&hpre[(size_t)node * 128 + kk * 32 + g * 8 + 4];
          const float4 s0 = scq[kk][0], s1 = scq[kk][1];
          const float4 h0 = shq[kk][0], h1 = shq[kk][1];
          u.x = pack2(fmaxf(fmaf(v0.x, s0.x, h0.x), 0.f),
                      fmaxf(fmaf(v0.y, s0.y, h0.y), 0.f));
          u.y = pack2(fmaxf(fmaf(v0.z, s0.z, h0.z), 0.f),
                      fmaxf(fmaf(v0.w, s0.w, h0.w), 0.f));
          u.z = pack2(fmaxf(fmaf(v1.x, s1.x, h1.x), 0.f),
                      fmaxf(fmaf(v1.y, s1.y, h1.y), 0.f));
          u.w = pack2(fmaxf(fmaf(v1.z, s1.z, h1.z), 0.f),
                      fmaxf(fmaf(v1.w, s1.w, h1.w), 0.f));
        }
        union { uint4 u4; bf16x8 v; } cv; cv.u4 = u;
        af[kk] = cv.v;
      }
      f32x4 acc0 = {0.f, 0.f, 0.f, 0.f}, acc1 = {0.f, 0.f, 0.f, 0.f};
#pragma unroll
      for (int kk = 0; kk < 4; ++kk) {
        acc0 = __builtin_amdgcn_mfma_f32_16x16x32_bf16(af[kk], B1[0][kk], acc0, 0, 0, 0);
        acc1 = __builtin_amdgcn_mfma_f32_16x16x32_bf16(af[kk], B1[1][kk], acc1, 0, 0, 0);
      }
#pragma unroll
      for (int j = 0; j < 4; ++j)
        p[nt][j] = fmaxf(acc0[j] + b1c0, 0.f) * w2c0 +
                   fmaxf(acc1[j] + b1c1, 0.f) * w2c1;
    }
#pragma unroll
    for (int dd = 1; dd <= 8; dd <<= 1)
#pragma unroll
      for (int nt = 0; nt < 4; ++nt)
#pragma unroll
        for (int j = 0; j < 4; ++j)
          p[nt][j] += __shfl_xor(p[nt][j], dd);
    if (c == 0) {
#pragma unroll
      for (int nt = 0; nt < 4; ++nt)
#pragma unroll
        for (int j = 0; j < 4; ++j)
          pl[w][nt * 16 + g * 4 + j] = p[nt][j];
    }
    __syncthreads();
    if (tid < 64) {
      const int node = base + tid;
      if (node < NN) {
        const float s = pl[0][tid] + pl[1][tid] + pl[2][tid] + pl[3][tid] + b2v;
        out[node] = 1.f / (1.f + expf(-s));
      }
    }
    __syncthreads();
  }
}

extern "C" void kernel_launch(void* const* d_in, const int* in_sizes, int n_in,
                              void* d_out, int out_size, void* d_ws, size_t ws_size,
                              hipStream_t stream)
{
  const float* x    = (const float*)d_in[0];
  const int*   ei   = (const int*)  d_in[1];
  const float* ea   = (const float*)d_in[2];
  const float* l0We = (const float*)d_in[3];
  const float* l0be = (const float*)d_in[4];
  const float* l0W1 = (const float*)d_in[5];
  const float* l0b1 = (const float*)d_in[6];
  const float* l0W2 = (const float*)d_in[7];
  const float* l0b2 = (const float*)d_in[8];
  const float* l0g  = (const float*)d_in[9];
  const float* l0bt = (const float*)d_in[10];
  const float* l1We = (const float*)d_in[11];
  const float* l1be = (const float*)d_in[12];
  const float* l1W1 = (const float*)d_in[13];
  const float* l1b1 = (const float*)d_in[14];
  const float* l1W2 = (const float*)d_in[15];
  const float* l1b2 = (const float*)d_in[16];
  const float* l1g  = (const float*)d_in[17];
  const float* l1bt = (const float*)d_in[18];
  const float* hW1  = (const float*)d_in[19];
  const float* hb1  = (const float*)d_in[20];
  const float* hW2  = (const float*)d_in[21];
  const float* hb2  = (const float*)d_in[22];
  float* out = (float*)d_out;

  // workspace layout
  float*  A    = (float*)d_ws;                         // NN*128 f32 (hpre)
  float*  AGG  = A + (size_t)NN * 128;                 // NN*128 f32
  unsigned short* hb = (unsigned short*)(AGG + (size_t)NN * 128);  // NN*128 bf16
  unsigned short* xb = hb + (size_t)NN * 128;          // NN*32 bf16
  uint32* deg     = (uint32*)(xb + (size_t)NN * 32);   // NN
  uint32* cnt     = deg + NN;                          // NN
  uint32* toff    = cnt + NN;                          // NN
  uint32* eoff    = toff + NN;                         // NN
  ull*    counter = (ull*)(eoff + NN);                 // 1 (pad)
  int*    snode   = (int*)(counter + 2);               // TMAX
  uint32* srcc    = (uint32*)(snode + TMAX);           // NE (+128 slack after)
  float*  st0     = (float*)(srcc + NE) + 128;         // 512  (128 u32 pad)
  float*  st1     = st0 + 512;                         // 512
  unsigned short* W1t0 = (unsigned short*)(st1 + 512); // 32*128
  unsigned short* W2t0 = W1t0 + 4096;                  // 128*128
  unsigned short* W1t1 = W2t0 + 16384;
  unsigned short* W2t1 = W1t1 + 16384;
  unsigned short* hW1t = W2t1 + 16384;
  unsigned short* Wet0 = hW1t + 16384;                 // 32*16
  unsigned short* Wet1 = Wet0 + 512;                   // 128*16
  unsigned short* eabc = Wet1 + 2048;                  // NE*16 bf16 (if fits)
  uint32* eidc = (uint32*)eabc;

  const size_t base_need = (size_t)((char*)(Wet1 + 2048) - (char*)d_ws);
  const size_t need_A = base_need + (size_t)NE * 16 * 2;
  const size_t need_B = base_need + (size_t)NE * 4;
  const bool EAB = (ws_size >= need_A);
  if (!EAB && ws_size < need_B) return;

  hipMemsetAsync(deg, 0, (size_t)2 * NN * 4, stream);          // deg, cnt
  hipMemsetAsync(counter, 0, 16, stream);
  hipMemsetAsync(snode, 0xFF, (size_t)TMAX * 4, stream);
  hipMemsetAsync(st0, 0, 4096, stream);                        // st0 + st1
  hipMemsetAsync(AGG, 0, (size_t)NN * 32 * 4, stream);         // layer-0 agg

  const int nChunks = (NN + 63) / 64;     // 1563

  // one combined conversion launch (5 weights + 2 edge-W + x)
  conv_all<<<16 + 64 * 4 + 2 + 8 + 1563, 256, 0, stream>>>(
      l0W1, l0W2, l1W1, l1W2, hW1, l0We, l1We, x,
      W1t0, W2t0, W1t1, W2t1, hW1t, Wet0, Wet1, xb);

  // CSR build
  hist_kernel<<<(NE + 255) / 256, 256, 0, stream>>>(ei, deg);
  offsets2_kernel<<<(NN + 255) / 256, 256, 0, stream>>>(deg, toff, eoff, counter);
  snode_fill<<<(NN + 255) / 256, 256, 0, stream>>>(toff, deg, snode);
  if (EAB)
    fill_kernel<true><<<(NE + 255) / 256, 256, 0, stream>>>(
        ei, eoff, cnt, srcc, eabc, eidc, ea);
  else
    fill_kernel<false><<<(NE + 255) / 256, 256, 0, stream>>>(
        ei, eoff, cnt, srcc, eabc, eidc, ea);

  // layer 0
  if (EAB)
    flat_agg2<32, 2><<<NRANGES / 4, 256, 0, stream>>>(
        snode, toff, eoff, deg, srcc, eabc, xb, Wet0, l0be, counter, AGG);
  else
    flat_agg_fb<32, 2><<<NRANGES / 4, 256, 0, stream>>>(
        snode, toff, eoff, deg, srcc, eidc, ea, xb, Wet0, l0be, counter, AGG);
  mlp_mfma<32, false><<<782, 256, 0, stream>>>(x, (const unsigned short*)nullptr,
      AGG, W1t0, l0b1, W2t0, l0b2, A, st0, nChunks);
  hipMemsetAsync(AGG, 0, (size_t)NN * 128 * 4, stream);   // re-zero for layer 1
  bn_finalize<<<1, 128, 0, stream>>>(st0, l0g, l0bt);
  bn_apply_bf16<<<(NN * 32) / 256, 256, 0, stream>>>(A, st0, hb);

  // layer 1
  if (EAB)
    flat_agg2<128, 4><<<NRANGES / 2, 256, 0, stream>>>(
        snode, toff, eoff, deg, srcc, eabc, hb, Wet1, l1be, counter, AGG);
  else
    flat_agg_fb<128, 4><<<NRANGES / 2, 256, 0, stream>>>(
        snode, toff, eoff, deg, srcc, eidc, ea, hb, Wet1, l1be, counter, AGG);
  mlp_mfma<128, true><<<782, 256, 0, stream>>>((const float*)nullptr, hb,
      AGG, W1t1, l1b1, W2t1, l1b2, A, st1, nChunks);
  bn_finalize<<<1, 128, 0, stream>>>(st1, l1g, l1bt);

  // fused BN-apply + head
  head_bn<<<782, 256, 0, stream>>>(A, st1, hW1t, hb1, hW2, hb2, out, nChunks);
}